// Round 1
// baseline (4659.362 us; speedup 1.0000x reference)
//
#include <hip/hip_runtime.h>
#include <math.h>

#define N_NODES 100000
#define N_EDGES 1600000
#define N_B 64
#define D_IN 64
#define D_HID 128
#define D_OUT 128
#define K_ITER 16
#define LN_EPS 1e-5f

struct __align__(16) EdgeRec { int src; float w; float ea0; float ea1; };

__device__ __forceinline__ float gelu_f(float x) {
    return 0.5f * x * (1.0f + erff(0.70710678118654752440f * x));
}

// ---------------- CSR build ----------------

__global__ __launch_bounds__(256) void hist_kernel(const int* __restrict__ dst, int* __restrict__ counts) {
    int e = blockIdx.x * 256 + threadIdx.x;
    if (e < N_EDGES) atomicAdd(&counts[dst[e]], 1);
}

__global__ __launch_bounds__(256) void deg_kernel(const int* __restrict__ counts,
                                                  float* __restrict__ dis, float* __restrict__ selfw) {
    int i = blockIdx.x * 256 + threadIdx.x;
    if (i < N_NODES) {
        float d = (float)(counts[i] + 1);
        dis[i] = 1.0f / sqrtf(d);
        selfw[i] = 1.0f / d;
    }
}

__global__ __launch_bounds__(1024) void scan1(const int* __restrict__ counts, int* __restrict__ rp,
                                              int* __restrict__ bsum) {
    __shared__ int tmp[1024];
    int t = threadIdx.x;
    int idx = blockIdx.x * 1024 + t;
    int v = (idx < N_NODES) ? counts[idx] : 0;
    tmp[t] = v;
    __syncthreads();
    for (int o = 1; o < 1024; o <<= 1) {
        int add = (t >= o) ? tmp[t - o] : 0;
        __syncthreads();
        tmp[t] += add;
        __syncthreads();
    }
    if (idx < N_NODES) rp[idx] = tmp[t] - v;   // exclusive
    if (t == 1023) bsum[blockIdx.x] = tmp[t];
}

__global__ void scan2(int* bsum, int nb) {
    if (threadIdx.x == 0 && blockIdx.x == 0) {
        int acc = 0;
        for (int i = 0; i < nb; i++) { int v = bsum[i]; bsum[i] = acc; acc += v; }
    }
}

__global__ __launch_bounds__(1024) void scan3(int* __restrict__ rp, const int* __restrict__ bsum,
                                              int* __restrict__ cursor) {
    int t = threadIdx.x;
    int idx = blockIdx.x * 1024 + t;
    if (idx < N_NODES) {
        int v = rp[idx] + bsum[blockIdx.x];
        rp[idx] = v;
        cursor[idx] = v;
    }
    if (idx == 0) rp[N_NODES] = N_EDGES;
}

__global__ __launch_bounds__(256) void scatter_kernel(const int* __restrict__ src, const int* __restrict__ dst,
                                                      const float* __restrict__ ea, const float* __restrict__ dis,
                                                      int* __restrict__ cursor, EdgeRec* __restrict__ er) {
    int e = blockIdx.x * 256 + threadIdx.x;
    if (e >= N_EDGES) return;
    int s = src[e], d = dst[e];
    int pos = atomicAdd(&cursor[d], 1);
    EdgeRec r;
    r.src = s;
    r.w = dis[s] * dis[d];
    r.ea0 = ea[e * 2];
    r.ea1 = ea[e * 2 + 1];
    er[pos] = r;
}

// ---------------- GINE gathers (one wave per node) ----------------

__global__ __launch_bounds__(256) void conv1_gather(const float* __restrict__ x, const int* __restrict__ rp,
                                                    const EdgeRec* __restrict__ er,
                                                    const float* __restrict__ We1, const float* __restrict__ be1,
                                                    float* __restrict__ out) {
    int gw = (blockIdx.x * 256 + threadIdx.x) >> 6;
    if (gw >= N_NODES) return;
    int lane = threadIdx.x & 63;
    float w0 = We1[lane], w1 = We1[64 + lane], bb = be1[lane];
    float acc = x[(size_t)gw * 64 + lane];
    int s0 = rp[gw], s1 = rp[gw + 1];
    for (int j = s0; j < s1; j++) {
        EdgeRec r = er[j];
        float m = x[(size_t)r.src * 64 + lane] + r.ea0 * w0 + r.ea1 * w1 + bb;
        acc += fmaxf(m, 0.0f);
    }
    out[(size_t)gw * 64 + lane] = acc;
}

__global__ __launch_bounds__(256) void conv2_gather(const float* __restrict__ h1, const int* __restrict__ rp,
                                                    const EdgeRec* __restrict__ er,
                                                    const float* __restrict__ We2, const float* __restrict__ be2,
                                                    float* __restrict__ out) {
    int gw = (blockIdx.x * 256 + threadIdx.x) >> 6;
    if (gw >= N_NODES) return;
    int lane = threadIdx.x & 63;
    int f0 = lane * 2;
    float w00 = We2[f0], w01 = We2[f0 + 1];
    float w10 = We2[128 + f0], w11 = We2[128 + f0 + 1];
    float b0 = be2[f0], b1 = be2[f0 + 1];
    const float2* h2 = (const float2*)h1;
    float2 hc = h2[(size_t)gw * 64 + lane];
    float a0 = hc.x, a1 = hc.y;
    int s0 = rp[gw], s1 = rp[gw + 1];
    for (int j = s0; j < s1; j++) {
        EdgeRec r = er[j];
        float2 hs = h2[(size_t)r.src * 64 + lane];
        float m0 = hs.x + r.ea0 * w00 + r.ea1 * w10 + b0;
        float m1 = hs.y + r.ea0 * w01 + r.ea1 * w11 + b1;
        a0 += fmaxf(m0, 0.0f);
        a1 += fmaxf(m1, 0.0f);
    }
    out[(size_t)gw * 128 + f0] = a0;
    out[(size_t)gw * 128 + f0 + 1] = a1;
}

// ---------------- Node MLPs (one wave per node, weights in LDS) ----------------

template <int Kd>
__global__ __launch_bounds__(256) void mlp_layer1(const float* __restrict__ in, const float* __restrict__ Wa,
                                                  const float* __restrict__ ba, float* __restrict__ t) {
    __shared__ float sW[Kd * 128];
    for (int i = threadIdx.x; i < Kd * 128; i += 256) sW[i] = Wa[i];
    int lane = threadIdx.x & 63;
    int wsub = threadIdx.x >> 6;
    int f0 = lane * 2;
    float b0 = ba[f0], b1 = ba[f0 + 1];
    __syncthreads();
    const float2* sW2 = (const float2*)sW;
    for (int node = blockIdx.x * 4 + wsub; node < N_NODES; node += gridDim.x * 4) {
        const float* hrow = in + (size_t)node * Kd;
        float a0 = b0, a1 = b1;
        for (int j = 0; j < Kd; j++) {
            float hv = hrow[j];
            float2 wv = sW2[j * 64 + lane];
            a0 = fmaf(hv, wv.x, a0);
            a1 = fmaf(hv, wv.y, a1);
        }
        t[(size_t)node * 128 + f0] = gelu_f(a0);
        t[(size_t)node * 128 + f0 + 1] = gelu_f(a1);
    }
}

template <bool GELU_OUT>
__global__ __launch_bounds__(256) void mlp_layer2(const float* __restrict__ t, const float* __restrict__ Wb,
                                                  const float* __restrict__ bb, const float* __restrict__ g,
                                                  const float* __restrict__ bn, float* __restrict__ out) {
    __shared__ float sW[128 * 128];
    for (int i = threadIdx.x; i < 128 * 128; i += 256) sW[i] = Wb[i];
    int lane = threadIdx.x & 63;
    int wsub = threadIdx.x >> 6;
    int f0 = lane * 2;
    float b0 = bb[f0], b1 = bb[f0 + 1];
    float g0 = g[f0], g1v = g[f0 + 1];
    float n0 = bn[f0], n1 = bn[f0 + 1];
    __syncthreads();
    const float2* sW2 = (const float2*)sW;
    for (int node = blockIdx.x * 4 + wsub; node < N_NODES; node += gridDim.x * 4) {
        const float* trow = t + (size_t)node * 128;
        float a0 = b0, a1 = b1;
        for (int j = 0; j < 128; j++) {
            float tv = trow[j];
            float2 wv = sW2[j * 64 + lane];
            a0 = fmaf(tv, wv.x, a0);
            a1 = fmaf(tv, wv.y, a1);
        }
        if (GELU_OUT) { a0 = gelu_f(a0); a1 = gelu_f(a1); }
        float s = a0 + a1, sq = a0 * a0 + a1 * a1;
        for (int m = 32; m > 0; m >>= 1) {
            s += __shfl_xor(s, m, 64);
            sq += __shfl_xor(sq, m, 64);
        }
        float mu = s * (1.0f / 128.0f);
        float var = sq * (1.0f / 128.0f) - mu * mu;
        float rs = rsqrtf(var + LN_EPS);
        out[(size_t)node * 128 + f0] = (a0 - mu) * rs * g0 + n0;
        out[(size_t)node * 128 + f0 + 1] = (a1 - mu) * rs * g1v + n1;
    }
}

// ---------------- APPNP step ----------------

__global__ __launch_bounds__(256) void appnp_step(const float2* __restrict__ hin, const float2* __restrict__ anchor,
                                                  float2* __restrict__ hout, const int* __restrict__ rp,
                                                  const EdgeRec* __restrict__ er, const float* __restrict__ selfw) {
    int gw = (blockIdx.x * 256 + threadIdx.x) >> 6;
    if (gw >= N_NODES) return;
    int lane = threadIdx.x & 63;
    size_t idx = (size_t)gw * 64 + lane;
    float swi = selfw[gw];
    float2 hc = hin[idx];
    float ax = swi * hc.x, ay = swi * hc.y;
    int s0 = rp[gw], s1 = rp[gw + 1];
    for (int j = s0; j < s1; j++) {
        EdgeRec r = er[j];
        float2 hs = hin[(size_t)r.src * 64 + lane];
        ax = fmaf(r.w, hs.x, ax);
        ay = fmaf(r.w, hs.y, ay);
    }
    float2 anc = anchor[idx];
    float2 o;
    o.x = 0.9f * ax + 0.1f * anc.x;
    o.y = 0.9f * ay + 0.1f * anc.y;
    hout[idx] = o;
}

// ---------------- Attentional pooling ----------------

__global__ __launch_bounds__(256) void gate_kernel(const float* __restrict__ h, const float* __restrict__ Wg1,
                                                   const float* __restrict__ bg1, const float* __restrict__ Wg2,
                                                   const float* __restrict__ bg2, float* __restrict__ gate) {
    __shared__ float sW[128 * 64];
    for (int i = threadIdx.x; i < 128 * 64; i += 256) sW[i] = Wg1[i];
    int lane = threadIdx.x & 63;
    int wsub = threadIdx.x >> 6;
    float bias = bg1[lane];
    float w2 = Wg2[lane];
    float b2 = bg2[0];
    __syncthreads();
    for (int node = blockIdx.x * 4 + wsub; node < N_NODES; node += gridDim.x * 4) {
        const float* hrow = h + (size_t)node * 128;
        float a = bias;
        for (int j = 0; j < 128; j++) a = fmaf(hrow[j], sW[j * 64 + lane], a);
        a = gelu_f(a) * w2;
        for (int m = 32; m > 0; m >>= 1) a += __shfl_xor(a, m, 64);
        if (lane == 0) gate[node] = a + b2;
    }
}

__global__ void seg_begin(const int* __restrict__ batch, int* __restrict__ gbeg) {
    int b = threadIdx.x;
    if (b > N_B) return;
    if (b == N_B) { gbeg[N_B] = N_NODES; return; }
    int lo = 0, hi = N_NODES;
    while (lo < hi) {
        int mid = (lo + hi) >> 1;
        if (batch[mid] < b) lo = mid + 1; else hi = mid;
    }
    gbeg[b] = lo;
}

__global__ __launch_bounds__(256) void seg_max(const float* __restrict__ gate, const int* __restrict__ gbeg,
                                               float* __restrict__ gmax) {
    int b = blockIdx.x;
    int s = gbeg[b], e = gbeg[b + 1];
    float m = -INFINITY;
    for (int i = s + threadIdx.x; i < e; i += 256) m = fmaxf(m, gate[i]);
    for (int o = 32; o > 0; o >>= 1) m = fmaxf(m, __shfl_xor(m, o, 64));
    __shared__ float red[4];
    if ((threadIdx.x & 63) == 0) red[threadIdx.x >> 6] = m;
    __syncthreads();
    if (threadIdx.x == 0) gmax[b] = fmaxf(fmaxf(red[0], red[1]), fmaxf(red[2], red[3]));
}

__global__ __launch_bounds__(256) void seg_sum(const float* __restrict__ gate, const int* __restrict__ gbeg,
                                               const float* __restrict__ gmax, float* __restrict__ gsum) {
    int b = blockIdx.x;
    int s = gbeg[b], e = gbeg[b + 1];
    float m = gmax[b];
    float acc = 0.0f;
    for (int i = s + threadIdx.x; i < e; i += 256) acc += expf(gate[i] - m);
    for (int o = 32; o > 0; o >>= 1) acc += __shfl_xor(acc, o, 64);
    __shared__ float red[4];
    if ((threadIdx.x & 63) == 0) red[threadIdx.x >> 6] = acc;
    __syncthreads();
    if (threadIdx.x == 0) gsum[b] = red[0] + red[1] + red[2] + red[3];
}

__global__ __launch_bounds__(512) void seg_pool(const float* __restrict__ h, const float* __restrict__ gate,
                                                const int* __restrict__ gbeg, const float* __restrict__ gmax,
                                                const float* __restrict__ gsum, float* __restrict__ gout) {
    int b = blockIdx.x;
    int team = threadIdx.x >> 7;
    int f = threadIdx.x & 127;
    int s = gbeg[b], e = gbeg[b + 1];
    float m = gmax[b];
    float inv = (e > s) ? 1.0f / gsum[b] : 0.0f;
    float acc = 0.0f;
    for (int i = s + team; i < e; i += 4) {
        float a = expf(gate[i] - m) * inv;
        acc = fmaf(a, h[(size_t)i * 128 + f], acc);
    }
    __shared__ float red[4][128];
    red[team][f] = acc;
    __syncthreads();
    if (team == 0) gout[b * 128 + f] = red[0][f] + red[1][f] + red[2][f] + red[3][f];
}

// ---------------- host launch ----------------

extern "C" void kernel_launch(void* const* d_in, const int* in_sizes, int n_in,
                              void* d_out, int out_size, void* d_ws, size_t ws_size,
                              hipStream_t stream) {
    const float* x     = (const float*)d_in[0];
    const int*   ei    = (const int*)d_in[1];
    const int*   batch = (const int*)d_in[2];
    const float* ea    = (const float*)d_in[3];
    const float* We1 = (const float*)d_in[4];
    const float* be1 = (const float*)d_in[5];
    const float* W1a = (const float*)d_in[6];
    const float* b1a = (const float*)d_in[7];
    const float* W1b = (const float*)d_in[8];
    const float* b1b = (const float*)d_in[9];
    const float* g1  = (const float*)d_in[10];
    const float* bn1 = (const float*)d_in[11];
    const float* We2 = (const float*)d_in[12];
    const float* be2 = (const float*)d_in[13];
    const float* W2a = (const float*)d_in[14];
    const float* b2a = (const float*)d_in[15];
    const float* W2b = (const float*)d_in[16];
    const float* b2b = (const float*)d_in[17];
    const float* g2  = (const float*)d_in[18];
    const float* bn2 = (const float*)d_in[19];
    const float* Wg1 = (const float*)d_in[20];
    const float* bg1 = (const float*)d_in[21];
    const float* Wg2 = (const float*)d_in[22];
    const float* bg2 = (const float*)d_in[23];

    float* outH = (float*)d_out;                 // [N,128] final h
    float* outG = outH + (size_t)N_NODES * 128;  // [B,128] pooled

    char* w = (char*)d_ws;
    auto carve = [&](size_t bytes) {
        void* p = (void*)w;
        w += ((bytes + 255) / 256) * 256;
        return p;
    };
    float*   bufB   = (float*)carve((size_t)N_NODES * 128 * 4);
    float*   bufC   = (float*)carve((size_t)N_NODES * 128 * 4);
    EdgeRec* er     = (EdgeRec*)carve((size_t)N_EDGES * sizeof(EdgeRec));
    int*     counts = (int*)carve((size_t)N_NODES * 4);
    int*     rp     = (int*)carve((size_t)(N_NODES + 1) * 4);
    int*     cursor = (int*)carve((size_t)N_NODES * 4);
    float*   dis    = (float*)carve((size_t)N_NODES * 4);
    float*   selfw  = (float*)carve((size_t)N_NODES * 4);
    float*   gate   = (float*)carve((size_t)N_NODES * 4);
    int*     bsum   = (int*)carve(128 * 4);
    float*   gmax   = (float*)carve(N_B * 4);
    float*   gsum   = (float*)carve(N_B * 4);
    int*     gbeg   = (int*)carve((N_B + 1) * 4);

    const int* src = ei;
    const int* dst = ei + N_EDGES;

    const int NB_SCAN = (N_NODES + 1023) / 1024;  // 98
    const int EB = (N_EDGES + 255) / 256;
    const int NBLK = (N_NODES + 255) / 256;
    const int WBLK = (N_NODES + 3) / 4;  // one wave per node, 4 waves/block

    // CSR build
    hipMemsetAsync(counts, 0, (size_t)N_NODES * 4, stream);
    hist_kernel<<<EB, 256, 0, stream>>>(dst, counts);
    deg_kernel<<<NBLK, 256, 0, stream>>>(counts, dis, selfw);
    scan1<<<NB_SCAN, 1024, 0, stream>>>(counts, rp, bsum);
    scan2<<<1, 64, 0, stream>>>(bsum, NB_SCAN);
    scan3<<<NB_SCAN, 1024, 0, stream>>>(rp, bsum, cursor);
    scatter_kernel<<<EB, 256, 0, stream>>>(src, dst, ea, dis, cursor, er);

    // conv1: gather (x -> bufB[:,0:64]) -> mlp1 (t -> outH) -> mlp2+gelu+LN (h1 -> bufB)
    conv1_gather<<<WBLK, 256, 0, stream>>>(x, rp, er, We1, be1, bufB);
    mlp_layer1<64><<<512, 256, 0, stream>>>(bufB, W1a, b1a, outH);
    mlp_layer2<true><<<512, 256, 0, stream>>>(outH, W1b, b1b, g1, bn1, bufB);

    // conv2: gather (bufB -> bufC) -> mlp1 (t -> outH) -> mlp2+LN (anchor -> bufB)
    conv2_gather<<<WBLK, 256, 0, stream>>>(bufB, rp, er, We2, be2, bufC);
    mlp_layer1<128><<<512, 256, 0, stream>>>(bufC, W2a, b2a, outH);
    mlp_layer2<false><<<512, 256, 0, stream>>>(outH, W2b, b2b, g2, bn2, bufB);

    // APPNP: anchor = bufB; ping-pong bufC <-> outH; iter 16 (even) lands in outH
    const float2* anchor2 = (const float2*)bufB;
    float2* pa = (float2*)bufC;
    float2* pb = (float2*)outH;
    const float2* cur = (const float2*)bufB;  // h0 = anchor
    for (int k = 1; k <= K_ITER; k++) {
        float2* dstbuf = (k & 1) ? pa : pb;
        appnp_step<<<WBLK, 256, 0, stream>>>(cur, anchor2, dstbuf, rp, er, selfw);
        cur = dstbuf;
    }

    // pooling on outH
    gate_kernel<<<2048, 256, 0, stream>>>(outH, Wg1, bg1, Wg2, bg2, gate);
    seg_begin<<<1, 128, 0, stream>>>(batch, gbeg);
    seg_max<<<N_B, 256, 0, stream>>>(gate, gbeg, gmax);
    seg_sum<<<N_B, 256, 0, stream>>>(gate, gbeg, gmax, gsum);
    seg_pool<<<N_B, 512, 0, stream>>>(outH, gate, gbeg, gmax, gsum, outG);
}

// Round 2
// 3936.566 us; speedup vs baseline: 1.1836x; 1.1836x over previous
//
#include <hip/hip_runtime.h>
#include <math.h>

#define N_NODES 100000
#define N_EDGES 1600000
#define N_B 64
#define D_IN 64
#define D_HID 128
#define D_OUT 128
#define K_ITER 16
#define LN_EPS 1e-5f

__device__ __forceinline__ float gelu_f(float x) {
    return 0.5f * x * (1.0f + erff(0.70710678118654752440f * x));
}

// ---------------- CSR build ----------------

__global__ __launch_bounds__(256) void hist_kernel(const int* __restrict__ dst, int* __restrict__ counts) {
    int e = blockIdx.x * 256 + threadIdx.x;
    if (e < N_EDGES) atomicAdd(&counts[dst[e]], 1);
}

__global__ __launch_bounds__(256) void deg_kernel(const int* __restrict__ counts,
                                                  float* __restrict__ dis, float* __restrict__ selfw) {
    int i = blockIdx.x * 256 + threadIdx.x;
    if (i < N_NODES) {
        float d = (float)(counts[i] + 1);
        dis[i] = 1.0f / sqrtf(d);
        selfw[i] = 1.0f / d;
    }
}

__global__ __launch_bounds__(1024) void scan1(const int* __restrict__ counts, int* __restrict__ rp,
                                              int* __restrict__ bsum) {
    __shared__ int tmp[1024];
    int t = threadIdx.x;
    int idx = blockIdx.x * 1024 + t;
    int v = (idx < N_NODES) ? counts[idx] : 0;
    tmp[t] = v;
    __syncthreads();
    for (int o = 1; o < 1024; o <<= 1) {
        int add = (t >= o) ? tmp[t - o] : 0;
        __syncthreads();
        tmp[t] += add;
        __syncthreads();
    }
    if (idx < N_NODES) rp[idx] = tmp[t] - v;   // exclusive
    if (t == 1023) bsum[blockIdx.x] = tmp[t];
}

__global__ void scan2(int* bsum, int nb) {
    if (threadIdx.x == 0 && blockIdx.x == 0) {
        int acc = 0;
        for (int i = 0; i < nb; i++) { int v = bsum[i]; bsum[i] = acc; acc += v; }
    }
}

__global__ __launch_bounds__(1024) void scan3(int* __restrict__ rp, const int* __restrict__ bsum,
                                              int* __restrict__ cursor) {
    int t = threadIdx.x;
    int idx = blockIdx.x * 1024 + t;
    if (idx < N_NODES) {
        int v = rp[idx] + bsum[blockIdx.x];
        rp[idx] = v;
        cursor[idx] = v;
    }
    if (idx == 0) rp[N_NODES] = N_EDGES;
}

// esw = {src, w as float bits} (8B, used by appnp+convs); eea = {ea0, ea1} (8B, convs only)
__global__ __launch_bounds__(256) void scatter_kernel(const int* __restrict__ src, const int* __restrict__ dst,
                                                      const float* __restrict__ ea, const float* __restrict__ dis,
                                                      int* __restrict__ cursor, int2* __restrict__ esw,
                                                      float2* __restrict__ eea) {
    int e = blockIdx.x * 256 + threadIdx.x;
    if (e >= N_EDGES) return;
    int s = src[e], d = dst[e];
    int pos = atomicAdd(&cursor[d], 1);
    int2 sw;
    sw.x = s;
    sw.y = __float_as_int(dis[s] * dis[d]);
    esw[pos] = sw;
    float2 e2;
    e2.x = ea[e * 2];
    e2.y = ea[e * 2 + 1];
    eea[pos] = e2;
}

// ---------------- GINE gathers (one wave per node, 4x unrolled) ----------------

__global__ __launch_bounds__(256) void conv1_gather(const float* __restrict__ x, const int* __restrict__ rp,
                                                    const int2* __restrict__ esw, const float2* __restrict__ eea,
                                                    const float* __restrict__ We1, const float* __restrict__ be1,
                                                    float* __restrict__ out) {
    int gw = (blockIdx.x * 256 + threadIdx.x) >> 6;
    if (gw >= N_NODES) return;
    int lane = threadIdx.x & 63;
    float w0 = We1[lane], w1 = We1[64 + lane], bb = be1[lane];
    float acc = x[(size_t)gw * 64 + lane];
    int j = rp[gw], s1 = rp[gw + 1];
    for (; j + 4 <= s1; j += 4) {
        int2 e0 = esw[j], e1 = esw[j + 1], e2 = esw[j + 2], e3 = esw[j + 3];
        float2 a0 = eea[j], a1 = eea[j + 1], a2 = eea[j + 2], a3 = eea[j + 3];
        float v0 = x[(size_t)e0.x * 64 + lane];
        float v1 = x[(size_t)e1.x * 64 + lane];
        float v2 = x[(size_t)e2.x * 64 + lane];
        float v3 = x[(size_t)e3.x * 64 + lane];
        acc += fmaxf(v0 + a0.x * w0 + a0.y * w1 + bb, 0.0f);
        acc += fmaxf(v1 + a1.x * w0 + a1.y * w1 + bb, 0.0f);
        acc += fmaxf(v2 + a2.x * w0 + a2.y * w1 + bb, 0.0f);
        acc += fmaxf(v3 + a3.x * w0 + a3.y * w1 + bb, 0.0f);
    }
    for (; j < s1; j++) {
        int2 e = esw[j];
        float2 a = eea[j];
        float v = x[(size_t)e.x * 64 + lane];
        acc += fmaxf(v + a.x * w0 + a.y * w1 + bb, 0.0f);
    }
    out[(size_t)gw * 64 + lane] = acc;
}

__global__ __launch_bounds__(256) void conv2_gather(const float* __restrict__ h1, const int* __restrict__ rp,
                                                    const int2* __restrict__ esw, const float2* __restrict__ eea,
                                                    const float* __restrict__ We2, const float* __restrict__ be2,
                                                    float* __restrict__ out) {
    int gw = (blockIdx.x * 256 + threadIdx.x) >> 6;
    if (gw >= N_NODES) return;
    int lane = threadIdx.x & 63;
    int f0 = lane * 2;
    float w00 = We2[f0], w01 = We2[f0 + 1];
    float w10 = We2[128 + f0], w11 = We2[128 + f0 + 1];
    float b0 = be2[f0], b1 = be2[f0 + 1];
    const float2* h2 = (const float2*)h1;
    float2 hc = h2[(size_t)gw * 64 + lane];
    float a0 = hc.x, a1 = hc.y;
    int j = rp[gw], s1 = rp[gw + 1];
    for (; j + 4 <= s1; j += 4) {
        int2 e0 = esw[j], e1 = esw[j + 1], e2 = esw[j + 2], e3 = esw[j + 3];
        float2 q0 = eea[j], q1 = eea[j + 1], q2 = eea[j + 2], q3 = eea[j + 3];
        float2 v0 = h2[(size_t)e0.x * 64 + lane];
        float2 v1 = h2[(size_t)e1.x * 64 + lane];
        float2 v2 = h2[(size_t)e2.x * 64 + lane];
        float2 v3 = h2[(size_t)e3.x * 64 + lane];
        a0 += fmaxf(v0.x + q0.x * w00 + q0.y * w10 + b0, 0.0f);
        a1 += fmaxf(v0.y + q0.x * w01 + q0.y * w11 + b1, 0.0f);
        a0 += fmaxf(v1.x + q1.x * w00 + q1.y * w10 + b0, 0.0f);
        a1 += fmaxf(v1.y + q1.x * w01 + q1.y * w11 + b1, 0.0f);
        a0 += fmaxf(v2.x + q2.x * w00 + q2.y * w10 + b0, 0.0f);
        a1 += fmaxf(v2.y + q2.x * w01 + q2.y * w11 + b1, 0.0f);
        a0 += fmaxf(v3.x + q3.x * w00 + q3.y * w10 + b0, 0.0f);
        a1 += fmaxf(v3.y + q3.x * w01 + q3.y * w11 + b1, 0.0f);
    }
    for (; j < s1; j++) {
        int2 e = esw[j];
        float2 q = eea[j];
        float2 v = h2[(size_t)e.x * 64 + lane];
        a0 += fmaxf(v.x + q.x * w00 + q.y * w10 + b0, 0.0f);
        a1 += fmaxf(v.y + q.x * w01 + q.y * w11 + b1, 0.0f);
    }
    out[(size_t)gw * 128 + f0] = a0;
    out[(size_t)gw * 128 + f0 + 1] = a1;
}

// ---------------- Node MLPs: 4 nodes/wave, 8 accumulators, b128 LDS reads ----------------
// LDS weight layout: chunk c (4 k-rows), lane l (2 cols: 2l, 2l+1), 8 floats:
//   [k=4c+0: col0,col1][k=4c+1: col0,col1][k=4c+2: col0,col1][k=4c+3: col0,col1]

template <int Kd>
__global__ __launch_bounds__(512) void mlp_layer1(const float* __restrict__ in, const float* __restrict__ Wa,
                                                  const float* __restrict__ ba, float* __restrict__ t) {
    __shared__ float sW[Kd * 128];
    for (int idx = threadIdx.x; idx < Kd * 128; idx += 512) {
        int j = idx >> 7, c = idx & 127;
        sW[(((j >> 2) * 64 + (c >> 1)) << 3) + ((j & 3) << 1) + (c & 1)] = Wa[idx];
    }
    int lane = threadIdx.x & 63;
    int wsub = threadIdx.x >> 6;  // 0..7
    int f0 = lane * 2;
    float b0 = ba[f0], b1 = ba[f0 + 1];
    __syncthreads();
    const float4* sW4 = (const float4*)sW;
    const int nGroups = N_NODES / 4;
    for (int g = blockIdx.x * 8 + wsub; g < nGroups; g += gridDim.x * 8) {
        int n0 = g * 4;
        const float4* r0 = (const float4*)(in + (size_t)n0 * Kd);
        const float4* r1 = (const float4*)(in + (size_t)(n0 + 1) * Kd);
        const float4* r2 = (const float4*)(in + (size_t)(n0 + 2) * Kd);
        const float4* r3 = (const float4*)(in + (size_t)(n0 + 3) * Kd);
        float a00 = b0, a01 = b1, a10 = b0, a11 = b1, a20 = b0, a21 = b1, a30 = b0, a31 = b1;
        for (int c = 0; c < Kd / 4; c++) {
            float4 h0 = r0[c], h1 = r1[c], h2 = r2[c], h3 = r3[c];
            float4 wA = sW4[(c * 64 + lane) * 2];
            float4 wB = sW4[(c * 64 + lane) * 2 + 1];
            a00 = fmaf(h0.x, wA.x, a00); a01 = fmaf(h0.x, wA.y, a01);
            a00 = fmaf(h0.y, wA.z, a00); a01 = fmaf(h0.y, wA.w, a01);
            a00 = fmaf(h0.z, wB.x, a00); a01 = fmaf(h0.z, wB.y, a01);
            a00 = fmaf(h0.w, wB.z, a00); a01 = fmaf(h0.w, wB.w, a01);
            a10 = fmaf(h1.x, wA.x, a10); a11 = fmaf(h1.x, wA.y, a11);
            a10 = fmaf(h1.y, wA.z, a10); a11 = fmaf(h1.y, wA.w, a11);
            a10 = fmaf(h1.z, wB.x, a10); a11 = fmaf(h1.z, wB.y, a11);
            a10 = fmaf(h1.w, wB.z, a10); a11 = fmaf(h1.w, wB.w, a11);
            a20 = fmaf(h2.x, wA.x, a20); a21 = fmaf(h2.x, wA.y, a21);
            a20 = fmaf(h2.y, wA.z, a20); a21 = fmaf(h2.y, wA.w, a21);
            a20 = fmaf(h2.z, wB.x, a20); a21 = fmaf(h2.z, wB.y, a21);
            a20 = fmaf(h2.w, wB.z, a20); a21 = fmaf(h2.w, wB.w, a21);
            a30 = fmaf(h3.x, wA.x, a30); a31 = fmaf(h3.x, wA.y, a31);
            a30 = fmaf(h3.y, wA.z, a30); a31 = fmaf(h3.y, wA.w, a31);
            a30 = fmaf(h3.z, wB.x, a30); a31 = fmaf(h3.z, wB.y, a31);
            a30 = fmaf(h3.w, wB.z, a30); a31 = fmaf(h3.w, wB.w, a31);
        }
        float2* tp = (float2*)t;
        float2 o0; o0.x = gelu_f(a00); o0.y = gelu_f(a01);
        float2 o1; o1.x = gelu_f(a10); o1.y = gelu_f(a11);
        float2 o2; o2.x = gelu_f(a20); o2.y = gelu_f(a21);
        float2 o3; o3.x = gelu_f(a30); o3.y = gelu_f(a31);
        tp[(size_t)n0 * 64 + lane] = o0;
        tp[(size_t)(n0 + 1) * 64 + lane] = o1;
        tp[(size_t)(n0 + 2) * 64 + lane] = o2;
        tp[(size_t)(n0 + 3) * 64 + lane] = o3;
    }
}

template <bool GELU_OUT>
__global__ __launch_bounds__(512) void mlp_layer2(const float* __restrict__ t, const float* __restrict__ Wb,
                                                  const float* __restrict__ bb, const float* __restrict__ g,
                                                  const float* __restrict__ bn, float* __restrict__ out) {
    __shared__ float sW[128 * 128];
    for (int idx = threadIdx.x; idx < 128 * 128; idx += 512) {
        int j = idx >> 7, c = idx & 127;
        sW[(((j >> 2) * 64 + (c >> 1)) << 3) + ((j & 3) << 1) + (c & 1)] = Wb[idx];
    }
    int lane = threadIdx.x & 63;
    int wsub = threadIdx.x >> 6;
    int f0 = lane * 2;
    float b0 = bb[f0], b1 = bb[f0 + 1];
    float g0 = g[f0], g1v = g[f0 + 1];
    float n0v = bn[f0], n1v = bn[f0 + 1];
    __syncthreads();
    const float4* sW4 = (const float4*)sW;
    const int nGroups = N_NODES / 4;
    for (int grp = blockIdx.x * 8 + wsub; grp < nGroups; grp += gridDim.x * 8) {
        int n0 = grp * 4;
        const float4* r0 = (const float4*)(t + (size_t)n0 * 128);
        const float4* r1 = (const float4*)(t + (size_t)(n0 + 1) * 128);
        const float4* r2 = (const float4*)(t + (size_t)(n0 + 2) * 128);
        const float4* r3 = (const float4*)(t + (size_t)(n0 + 3) * 128);
        float a00 = b0, a01 = b1, a10 = b0, a11 = b1, a20 = b0, a21 = b1, a30 = b0, a31 = b1;
        for (int c = 0; c < 32; c++) {
            float4 h0 = r0[c], h1 = r1[c], h2 = r2[c], h3 = r3[c];
            float4 wA = sW4[(c * 64 + lane) * 2];
            float4 wB = sW4[(c * 64 + lane) * 2 + 1];
            a00 = fmaf(h0.x, wA.x, a00); a01 = fmaf(h0.x, wA.y, a01);
            a00 = fmaf(h0.y, wA.z, a00); a01 = fmaf(h0.y, wA.w, a01);
            a00 = fmaf(h0.z, wB.x, a00); a01 = fmaf(h0.z, wB.y, a01);
            a00 = fmaf(h0.w, wB.z, a00); a01 = fmaf(h0.w, wB.w, a01);
            a10 = fmaf(h1.x, wA.x, a10); a11 = fmaf(h1.x, wA.y, a11);
            a10 = fmaf(h1.y, wA.z, a10); a11 = fmaf(h1.y, wA.w, a11);
            a10 = fmaf(h1.z, wB.x, a10); a11 = fmaf(h1.z, wB.y, a11);
            a10 = fmaf(h1.w, wB.z, a10); a11 = fmaf(h1.w, wB.w, a11);
            a20 = fmaf(h2.x, wA.x, a20); a21 = fmaf(h2.x, wA.y, a21);
            a20 = fmaf(h2.y, wA.z, a20); a21 = fmaf(h2.y, wA.w, a21);
            a20 = fmaf(h2.z, wB.x, a20); a21 = fmaf(h2.z, wB.y, a21);
            a20 = fmaf(h2.w, wB.z, a20); a21 = fmaf(h2.w, wB.w, a21);
            a30 = fmaf(h3.x, wA.x, a30); a31 = fmaf(h3.x, wA.y, a31);
            a30 = fmaf(h3.y, wA.z, a30); a31 = fmaf(h3.y, wA.w, a31);
            a30 = fmaf(h3.z, wB.x, a30); a31 = fmaf(h3.z, wB.y, a31);
            a30 = fmaf(h3.w, wB.z, a30); a31 = fmaf(h3.w, wB.w, a31);
        }
        if (GELU_OUT) {
            a00 = gelu_f(a00); a01 = gelu_f(a01);
            a10 = gelu_f(a10); a11 = gelu_f(a11);
            a20 = gelu_f(a20); a21 = gelu_f(a21);
            a30 = gelu_f(a30); a31 = gelu_f(a31);
        }
        float s0 = a00 + a01, q0 = a00 * a00 + a01 * a01;
        float s1 = a10 + a11, q1 = a10 * a10 + a11 * a11;
        float s2 = a20 + a21, q2 = a20 * a20 + a21 * a21;
        float s3 = a30 + a31, q3 = a30 * a30 + a31 * a31;
        for (int m = 32; m > 0; m >>= 1) {
            s0 += __shfl_xor(s0, m, 64); q0 += __shfl_xor(q0, m, 64);
            s1 += __shfl_xor(s1, m, 64); q1 += __shfl_xor(q1, m, 64);
            s2 += __shfl_xor(s2, m, 64); q2 += __shfl_xor(q2, m, 64);
            s3 += __shfl_xor(s3, m, 64); q3 += __shfl_xor(q3, m, 64);
        }
        float2* op = (float2*)out;
        {
            float mu = s0 * (1.0f / 128.0f);
            float rs = rsqrtf(q0 * (1.0f / 128.0f) - mu * mu + LN_EPS);
            float2 o; o.x = (a00 - mu) * rs * g0 + n0v; o.y = (a01 - mu) * rs * g1v + n1v;
            op[(size_t)n0 * 64 + lane] = o;
        }
        {
            float mu = s1 * (1.0f / 128.0f);
            float rs = rsqrtf(q1 * (1.0f / 128.0f) - mu * mu + LN_EPS);
            float2 o; o.x = (a10 - mu) * rs * g0 + n0v; o.y = (a11 - mu) * rs * g1v + n1v;
            op[(size_t)(n0 + 1) * 64 + lane] = o;
        }
        {
            float mu = s2 * (1.0f / 128.0f);
            float rs = rsqrtf(q2 * (1.0f / 128.0f) - mu * mu + LN_EPS);
            float2 o; o.x = (a20 - mu) * rs * g0 + n0v; o.y = (a21 - mu) * rs * g1v + n1v;
            op[(size_t)(n0 + 2) * 64 + lane] = o;
        }
        {
            float mu = s3 * (1.0f / 128.0f);
            float rs = rsqrtf(q3 * (1.0f / 128.0f) - mu * mu + LN_EPS);
            float2 o; o.x = (a30 - mu) * rs * g0 + n0v; o.y = (a31 - mu) * rs * g1v + n1v;
            op[(size_t)(n0 + 3) * 64 + lane] = o;
        }
    }
}

// ---------------- APPNP step (4x unrolled gather) ----------------

__global__ __launch_bounds__(256) void appnp_step(const float2* __restrict__ hin, const float2* __restrict__ anchor,
                                                  float2* __restrict__ hout, const int* __restrict__ rp,
                                                  const int2* __restrict__ esw, const float* __restrict__ selfw) {
    int gw = (blockIdx.x * 256 + threadIdx.x) >> 6;
    if (gw >= N_NODES) return;
    int lane = threadIdx.x & 63;
    size_t idx = (size_t)gw * 64 + lane;
    float swi = selfw[gw];
    float2 hc = hin[idx];
    float ax = swi * hc.x, ay = swi * hc.y;
    int j = rp[gw], s1 = rp[gw + 1];
    for (; j + 4 <= s1; j += 4) {
        int2 e0 = esw[j], e1 = esw[j + 1], e2 = esw[j + 2], e3 = esw[j + 3];
        float2 v0 = hin[(size_t)e0.x * 64 + lane];
        float2 v1 = hin[(size_t)e1.x * 64 + lane];
        float2 v2 = hin[(size_t)e2.x * 64 + lane];
        float2 v3 = hin[(size_t)e3.x * 64 + lane];
        float w0 = __int_as_float(e0.y), w1 = __int_as_float(e1.y);
        float w2 = __int_as_float(e2.y), w3 = __int_as_float(e3.y);
        ax = fmaf(w0, v0.x, ax); ay = fmaf(w0, v0.y, ay);
        ax = fmaf(w1, v1.x, ax); ay = fmaf(w1, v1.y, ay);
        ax = fmaf(w2, v2.x, ax); ay = fmaf(w2, v2.y, ay);
        ax = fmaf(w3, v3.x, ax); ay = fmaf(w3, v3.y, ay);
    }
    for (; j < s1; j++) {
        int2 e = esw[j];
        float2 v = hin[(size_t)e.x * 64 + lane];
        float w = __int_as_float(e.y);
        ax = fmaf(w, v.x, ax); ay = fmaf(w, v.y, ay);
    }
    float2 anc = anchor[idx];
    float2 o;
    o.x = 0.9f * ax + 0.1f * anc.x;
    o.y = 0.9f * ay + 0.1f * anc.y;
    hout[idx] = o;
}

// ---------------- Attentional pooling ----------------

__global__ __launch_bounds__(512) void gate_kernel(const float* __restrict__ h, const float* __restrict__ Wg1,
                                                   const float* __restrict__ bg1, const float* __restrict__ Wg2,
                                                   const float* __restrict__ bg2, float* __restrict__ gate) {
    __shared__ float sW[128 * 64];  // [chunk 32][lane 64][4 k-rows]
    for (int idx = threadIdx.x; idx < 128 * 64; idx += 512) {
        int j = idx >> 6, l = idx & 63;
        sW[(((j >> 2) * 64 + l) << 2) + (j & 3)] = Wg1[idx];
    }
    int lane = threadIdx.x & 63;
    int wsub = threadIdx.x >> 6;
    float bias = bg1[lane];
    float w2 = Wg2[lane];
    float b2 = bg2[0];
    __syncthreads();
    const float4* sW4 = (const float4*)sW;
    const int nGroups = N_NODES / 4;
    for (int grp = blockIdx.x * 8 + wsub; grp < nGroups; grp += gridDim.x * 8) {
        int n0 = grp * 4;
        const float4* r0 = (const float4*)(h + (size_t)n0 * 128);
        const float4* r1 = (const float4*)(h + (size_t)(n0 + 1) * 128);
        const float4* r2 = (const float4*)(h + (size_t)(n0 + 2) * 128);
        const float4* r3 = (const float4*)(h + (size_t)(n0 + 3) * 128);
        float a0 = bias, a1 = bias, a2 = bias, a3 = bias;
        for (int c = 0; c < 32; c++) {
            float4 h0 = r0[c], h1 = r1[c], h2 = r2[c], h3 = r3[c];
            float4 wv = sW4[c * 64 + lane];
            a0 = fmaf(h0.x, wv.x, a0); a0 = fmaf(h0.y, wv.y, a0);
            a0 = fmaf(h0.z, wv.z, a0); a0 = fmaf(h0.w, wv.w, a0);
            a1 = fmaf(h1.x, wv.x, a1); a1 = fmaf(h1.y, wv.y, a1);
            a1 = fmaf(h1.z, wv.z, a1); a1 = fmaf(h1.w, wv.w, a1);
            a2 = fmaf(h2.x, wv.x, a2); a2 = fmaf(h2.y, wv.y, a2);
            a2 = fmaf(h2.z, wv.z, a2); a2 = fmaf(h2.w, wv.w, a2);
            a3 = fmaf(h3.x, wv.x, a3); a3 = fmaf(h3.y, wv.y, a3);
            a3 = fmaf(h3.z, wv.z, a3); a3 = fmaf(h3.w, wv.w, a3);
        }
        a0 = gelu_f(a0) * w2;
        a1 = gelu_f(a1) * w2;
        a2 = gelu_f(a2) * w2;
        a3 = gelu_f(a3) * w2;
        for (int m = 32; m > 0; m >>= 1) {
            a0 += __shfl_xor(a0, m, 64);
            a1 += __shfl_xor(a1, m, 64);
            a2 += __shfl_xor(a2, m, 64);
            a3 += __shfl_xor(a3, m, 64);
        }
        if (lane == 0) {
            gate[n0] = a0 + b2;
            gate[n0 + 1] = a1 + b2;
            gate[n0 + 2] = a2 + b2;
            gate[n0 + 3] = a3 + b2;
        }
    }
}

__global__ void seg_begin(const int* __restrict__ batch, int* __restrict__ gbeg) {
    int b = threadIdx.x;
    if (b > N_B) return;
    if (b == N_B) { gbeg[N_B] = N_NODES; return; }
    int lo = 0, hi = N_NODES;
    while (lo < hi) {
        int mid = (lo + hi) >> 1;
        if (batch[mid] < b) lo = mid + 1; else hi = mid;
    }
    gbeg[b] = lo;
}

__global__ __launch_bounds__(256) void seg_max(const float* __restrict__ gate, const int* __restrict__ gbeg,
                                               float* __restrict__ gmax) {
    int b = blockIdx.x;
    int s = gbeg[b], e = gbeg[b + 1];
    float m = -INFINITY;
    for (int i = s + threadIdx.x; i < e; i += 256) m = fmaxf(m, gate[i]);
    for (int o = 32; o > 0; o >>= 1) m = fmaxf(m, __shfl_xor(m, o, 64));
    __shared__ float red[4];
    if ((threadIdx.x & 63) == 0) red[threadIdx.x >> 6] = m;
    __syncthreads();
    if (threadIdx.x == 0) gmax[b] = fmaxf(fmaxf(red[0], red[1]), fmaxf(red[2], red[3]));
}

__global__ __launch_bounds__(256) void seg_sum(const float* __restrict__ gate, const int* __restrict__ gbeg,
                                               const float* __restrict__ gmax, float* __restrict__ gsum) {
    int b = blockIdx.x;
    int s = gbeg[b], e = gbeg[b + 1];
    float m = gmax[b];
    float acc = 0.0f;
    for (int i = s + threadIdx.x; i < e; i += 256) acc += expf(gate[i] - m);
    for (int o = 32; o > 0; o >>= 1) acc += __shfl_xor(acc, o, 64);
    __shared__ float red[4];
    if ((threadIdx.x & 63) == 0) red[threadIdx.x >> 6] = acc;
    __syncthreads();
    if (threadIdx.x == 0) gsum[b] = red[0] + red[1] + red[2] + red[3];
}

__global__ __launch_bounds__(512) void seg_pool(const float* __restrict__ h, const float* __restrict__ gate,
                                                const int* __restrict__ gbeg, const float* __restrict__ gmax,
                                                const float* __restrict__ gsum, float* __restrict__ gout) {
    int b = blockIdx.x;
    int team = threadIdx.x >> 7;
    int f = threadIdx.x & 127;
    int s = gbeg[b], e = gbeg[b + 1];
    float m = gmax[b];
    float inv = (e > s) ? 1.0f / gsum[b] : 0.0f;
    float acc = 0.0f;
    for (int i = s + team; i < e; i += 4) {
        float a = expf(gate[i] - m) * inv;
        acc = fmaf(a, h[(size_t)i * 128 + f], acc);
    }
    __shared__ float red[4][128];
    red[team][f] = acc;
    __syncthreads();
    if (team == 0) gout[b * 128 + f] = red[0][f] + red[1][f] + red[2][f] + red[3][f];
}

// ---------------- host launch ----------------

extern "C" void kernel_launch(void* const* d_in, const int* in_sizes, int n_in,
                              void* d_out, int out_size, void* d_ws, size_t ws_size,
                              hipStream_t stream) {
    const float* x     = (const float*)d_in[0];
    const int*   ei    = (const int*)d_in[1];
    const int*   batch = (const int*)d_in[2];
    const float* ea    = (const float*)d_in[3];
    const float* We1 = (const float*)d_in[4];
    const float* be1 = (const float*)d_in[5];
    const float* W1a = (const float*)d_in[6];
    const float* b1a = (const float*)d_in[7];
    const float* W1b = (const float*)d_in[8];
    const float* b1b = (const float*)d_in[9];
    const float* g1  = (const float*)d_in[10];
    const float* bn1 = (const float*)d_in[11];
    const float* We2 = (const float*)d_in[12];
    const float* be2 = (const float*)d_in[13];
    const float* W2a = (const float*)d_in[14];
    const float* b2a = (const float*)d_in[15];
    const float* W2b = (const float*)d_in[16];
    const float* b2b = (const float*)d_in[17];
    const float* g2  = (const float*)d_in[18];
    const float* bn2 = (const float*)d_in[19];
    const float* Wg1 = (const float*)d_in[20];
    const float* bg1 = (const float*)d_in[21];
    const float* Wg2 = (const float*)d_in[22];
    const float* bg2 = (const float*)d_in[23];

    float* outH = (float*)d_out;                 // [N,128] final h
    float* outG = outH + (size_t)N_NODES * 128;  // [B,128] pooled

    char* w = (char*)d_ws;
    auto carve = [&](size_t bytes) {
        void* p = (void*)w;
        w += ((bytes + 255) / 256) * 256;
        return p;
    };
    float*  bufB   = (float*)carve((size_t)N_NODES * 128 * 4);
    float*  bufC   = (float*)carve((size_t)N_NODES * 128 * 4);
    int2*   esw    = (int2*)carve((size_t)N_EDGES * 8);
    float2* eea    = (float2*)carve((size_t)N_EDGES * 8);
    int*    counts = (int*)carve((size_t)N_NODES * 4);
    int*    rp     = (int*)carve((size_t)(N_NODES + 1) * 4);
    int*    cursor = (int*)carve((size_t)N_NODES * 4);
    float*  dis    = (float*)carve((size_t)N_NODES * 4);
    float*  selfw  = (float*)carve((size_t)N_NODES * 4);
    float*  gate   = (float*)carve((size_t)N_NODES * 4);
    int*    bsum   = (int*)carve(128 * 4);
    float*  gmax   = (float*)carve(N_B * 4);
    float*  gsum   = (float*)carve(N_B * 4);
    int*    gbeg   = (int*)carve((N_B + 1) * 4);

    const int* src = ei;
    const int* dst = ei + N_EDGES;

    const int NB_SCAN = (N_NODES + 1023) / 1024;  // 98
    const int EB = (N_EDGES + 255) / 256;
    const int NBLK = (N_NODES + 255) / 256;
    const int WBLK = (N_NODES + 3) / 4;  // one wave per node, 4 waves/block

    // CSR build
    hipMemsetAsync(counts, 0, (size_t)N_NODES * 4, stream);
    hist_kernel<<<EB, 256, 0, stream>>>(dst, counts);
    deg_kernel<<<NBLK, 256, 0, stream>>>(counts, dis, selfw);
    scan1<<<NB_SCAN, 1024, 0, stream>>>(counts, rp, bsum);
    scan2<<<1, 64, 0, stream>>>(bsum, NB_SCAN);
    scan3<<<NB_SCAN, 1024, 0, stream>>>(rp, bsum, cursor);
    scatter_kernel<<<EB, 256, 0, stream>>>(src, dst, ea, dis, cursor, esw, eea);

    // conv1: gather (x -> bufB[:,0:64]) -> mlp1 (t -> outH) -> mlp2+gelu+LN (h1 -> bufB)
    conv1_gather<<<WBLK, 256, 0, stream>>>(x, rp, esw, eea, We1, be1, bufB);
    mlp_layer1<64><<<256, 512, 0, stream>>>(bufB, W1a, b1a, outH);
    mlp_layer2<true><<<256, 512, 0, stream>>>(outH, W1b, b1b, g1, bn1, bufB);

    // conv2: gather (bufB -> bufC) -> mlp1 (t -> outH) -> mlp2+LN (anchor -> bufB)
    conv2_gather<<<WBLK, 256, 0, stream>>>(bufB, rp, esw, eea, We2, be2, bufC);
    mlp_layer1<128><<<256, 512, 0, stream>>>(bufC, W2a, b2a, outH);
    mlp_layer2<false><<<256, 512, 0, stream>>>(outH, W2b, b2b, g2, bn2, bufB);

    // APPNP: anchor = bufB; ping-pong bufC <-> outH; iter 16 (even) lands in outH
    const float2* anchor2 = (const float2*)bufB;
    float2* pa = (float2*)bufC;
    float2* pb = (float2*)outH;
    const float2* cur = (const float2*)bufB;  // h0 = anchor
    for (int k = 1; k <= K_ITER; k++) {
        float2* dstbuf = (k & 1) ? pa : pb;
        appnp_step<<<WBLK, 256, 0, stream>>>(cur, anchor2, dstbuf, rp, esw, selfw);
        cur = dstbuf;
    }

    // pooling on outH
    gate_kernel<<<256, 512, 0, stream>>>(outH, Wg1, bg1, Wg2, bg2, gate);
    seg_begin<<<1, 128, 0, stream>>>(batch, gbeg);
    seg_max<<<N_B, 256, 0, stream>>>(gate, gbeg, gmax);
    seg_sum<<<N_B, 256, 0, stream>>>(gate, gbeg, gmax, gsum);
    seg_pool<<<N_B, 512, 0, stream>>>(outH, gate, gbeg, gmax, gsum, outG);
}

// Round 3
// 3454.860 us; speedup vs baseline: 1.3486x; 1.1394x over previous
//
#include <hip/hip_runtime.h>
#include <math.h>

#define N_NODES 100000
#define N_EDGES 1600000
#define N_B 64
#define D_IN 64
#define D_HID 128
#define D_OUT 128
#define K_ITER 16
#define LN_EPS 1e-5f

__device__ __forceinline__ float gelu_f(float x) {
    return 0.5f * x * (1.0f + erff(0.70710678118654752440f * x));
}

// ---------------- CSR build ----------------

__global__ __launch_bounds__(256) void hist_kernel(const int* __restrict__ dst, int* __restrict__ counts) {
    int e = blockIdx.x * 256 + threadIdx.x;
    if (e < N_EDGES) atomicAdd(&counts[dst[e]], 1);
}

__global__ __launch_bounds__(256) void deg_kernel(const int* __restrict__ counts,
                                                  float* __restrict__ dis, float* __restrict__ selfw) {
    int i = blockIdx.x * 256 + threadIdx.x;
    if (i < N_NODES) {
        float d = (float)(counts[i] + 1);
        dis[i] = 1.0f / sqrtf(d);
        selfw[i] = 1.0f / d;
    }
}

__global__ __launch_bounds__(1024) void scan1(const int* __restrict__ counts, int* __restrict__ rp,
                                              int* __restrict__ bsum) {
    __shared__ int tmp[1024];
    int t = threadIdx.x;
    int idx = blockIdx.x * 1024 + t;
    int v = (idx < N_NODES) ? counts[idx] : 0;
    tmp[t] = v;
    __syncthreads();
    for (int o = 1; o < 1024; o <<= 1) {
        int add = (t >= o) ? tmp[t - o] : 0;
        __syncthreads();
        tmp[t] += add;
        __syncthreads();
    }
    if (idx < N_NODES) rp[idx] = tmp[t] - v;   // exclusive
    if (t == 1023) bsum[blockIdx.x] = tmp[t];
}

__global__ void scan2(int* bsum, int nb) {
    if (threadIdx.x == 0 && blockIdx.x == 0) {
        int acc = 0;
        for (int i = 0; i < nb; i++) { int v = bsum[i]; bsum[i] = acc; acc += v; }
    }
}

__global__ __launch_bounds__(1024) void scan3(int* __restrict__ rp, const int* __restrict__ bsum,
                                              int* __restrict__ cursor) {
    int t = threadIdx.x;
    int idx = blockIdx.x * 1024 + t;
    if (idx < N_NODES) {
        int v = rp[idx] + bsum[blockIdx.x];
        rp[idx] = v;
        cursor[idx] = v;
    }
    if (idx == 0) rp[N_NODES] = N_EDGES;
}

// esw = {src, w as float bits} (8B, used by appnp+convs); eea = {ea0, ea1} (8B, convs only)
__global__ __launch_bounds__(256) void scatter_kernel(const int* __restrict__ src, const int* __restrict__ dst,
                                                      const float* __restrict__ ea, const float* __restrict__ dis,
                                                      int* __restrict__ cursor, int2* __restrict__ esw,
                                                      float2* __restrict__ eea) {
    int e = blockIdx.x * 256 + threadIdx.x;
    if (e >= N_EDGES) return;
    int s = src[e], d = dst[e];
    int pos = atomicAdd(&cursor[d], 1);
    int2 sw;
    sw.x = s;
    sw.y = __float_as_int(dis[s] * dis[d]);
    esw[pos] = sw;
    float2 e2;
    e2.x = ea[e * 2];
    e2.y = ea[e * 2 + 1];
    eea[pos] = e2;
}

// ---------------- GINE gathers (one wave per node, 4x unrolled) ----------------

__global__ __launch_bounds__(256) void conv1_gather(const float* __restrict__ x, const int* __restrict__ rp,
                                                    const int2* __restrict__ esw, const float2* __restrict__ eea,
                                                    const float* __restrict__ We1, const float* __restrict__ be1,
                                                    float* __restrict__ out) {
    int gw = (blockIdx.x * 256 + threadIdx.x) >> 6;
    if (gw >= N_NODES) return;
    int lane = threadIdx.x & 63;
    float w0 = We1[lane], w1 = We1[64 + lane], bb = be1[lane];
    float acc = x[(size_t)gw * 64 + lane];
    int j = rp[gw], s1 = rp[gw + 1];
    for (; j + 4 <= s1; j += 4) {
        int2 e0 = esw[j], e1 = esw[j + 1], e2 = esw[j + 2], e3 = esw[j + 3];
        float2 a0 = eea[j], a1 = eea[j + 1], a2 = eea[j + 2], a3 = eea[j + 3];
        float v0 = x[(size_t)e0.x * 64 + lane];
        float v1 = x[(size_t)e1.x * 64 + lane];
        float v2 = x[(size_t)e2.x * 64 + lane];
        float v3 = x[(size_t)e3.x * 64 + lane];
        acc += fmaxf(v0 + a0.x * w0 + a0.y * w1 + bb, 0.0f);
        acc += fmaxf(v1 + a1.x * w0 + a1.y * w1 + bb, 0.0f);
        acc += fmaxf(v2 + a2.x * w0 + a2.y * w1 + bb, 0.0f);
        acc += fmaxf(v3 + a3.x * w0 + a3.y * w1 + bb, 0.0f);
    }
    for (; j < s1; j++) {
        int2 e = esw[j];
        float2 a = eea[j];
        float v = x[(size_t)e.x * 64 + lane];
        acc += fmaxf(v + a.x * w0 + a.y * w1 + bb, 0.0f);
    }
    out[(size_t)gw * 64 + lane] = acc;
}

__global__ __launch_bounds__(256) void conv2_gather(const float* __restrict__ h1, const int* __restrict__ rp,
                                                    const int2* __restrict__ esw, const float2* __restrict__ eea,
                                                    const float* __restrict__ We2, const float* __restrict__ be2,
                                                    float* __restrict__ out) {
    int gw = (blockIdx.x * 256 + threadIdx.x) >> 6;
    if (gw >= N_NODES) return;
    int lane = threadIdx.x & 63;
    int f0 = lane * 2;
    float w00 = We2[f0], w01 = We2[f0 + 1];
    float w10 = We2[128 + f0], w11 = We2[128 + f0 + 1];
    float b0 = be2[f0], b1 = be2[f0 + 1];
    const float2* h2 = (const float2*)h1;
    float2 hc = h2[(size_t)gw * 64 + lane];
    float a0 = hc.x, a1 = hc.y;
    int j = rp[gw], s1 = rp[gw + 1];
    for (; j + 4 <= s1; j += 4) {
        int2 e0 = esw[j], e1 = esw[j + 1], e2 = esw[j + 2], e3 = esw[j + 3];
        float2 q0 = eea[j], q1 = eea[j + 1], q2 = eea[j + 2], q3 = eea[j + 3];
        float2 v0 = h2[(size_t)e0.x * 64 + lane];
        float2 v1 = h2[(size_t)e1.x * 64 + lane];
        float2 v2 = h2[(size_t)e2.x * 64 + lane];
        float2 v3 = h2[(size_t)e3.x * 64 + lane];
        a0 += fmaxf(v0.x + q0.x * w00 + q0.y * w10 + b0, 0.0f);
        a1 += fmaxf(v0.y + q0.x * w01 + q0.y * w11 + b1, 0.0f);
        a0 += fmaxf(v1.x + q1.x * w00 + q1.y * w10 + b0, 0.0f);
        a1 += fmaxf(v1.y + q1.x * w01 + q1.y * w11 + b1, 0.0f);
        a0 += fmaxf(v2.x + q2.x * w00 + q2.y * w10 + b0, 0.0f);
        a1 += fmaxf(v2.y + q2.x * w01 + q2.y * w11 + b1, 0.0f);
        a0 += fmaxf(v3.x + q3.x * w00 + q3.y * w10 + b0, 0.0f);
        a1 += fmaxf(v3.y + q3.x * w01 + q3.y * w11 + b1, 0.0f);
    }
    for (; j < s1; j++) {
        int2 e = esw[j];
        float2 q = eea[j];
        float2 v = h2[(size_t)e.x * 64 + lane];
        a0 += fmaxf(v.x + q.x * w00 + q.y * w10 + b0, 0.0f);
        a1 += fmaxf(v.y + q.x * w01 + q.y * w11 + b1, 0.0f);
    }
    out[(size_t)gw * 128 + f0] = a0;
    out[(size_t)gw * 128 + f0 + 1] = a1;
}

// ---------------- Node MLPs: 4 nodes/wave, 8 accumulators, b128 LDS reads ----------------

template <int Kd>
__global__ __launch_bounds__(512) void mlp_layer1(const float* __restrict__ in, const float* __restrict__ Wa,
                                                  const float* __restrict__ ba, float* __restrict__ t) {
    __shared__ float sW[Kd * 128];
    for (int idx = threadIdx.x; idx < Kd * 128; idx += 512) {
        int j = idx >> 7, c = idx & 127;
        sW[(((j >> 2) * 64 + (c >> 1)) << 3) + ((j & 3) << 1) + (c & 1)] = Wa[idx];
    }
    int lane = threadIdx.x & 63;
    int wsub = threadIdx.x >> 6;  // 0..7
    int f0 = lane * 2;
    float b0 = ba[f0], b1 = ba[f0 + 1];
    __syncthreads();
    const float4* sW4 = (const float4*)sW;
    const int nGroups = N_NODES / 4;
    for (int g = blockIdx.x * 8 + wsub; g < nGroups; g += gridDim.x * 8) {
        int n0 = g * 4;
        const float4* r0 = (const float4*)(in + (size_t)n0 * Kd);
        const float4* r1 = (const float4*)(in + (size_t)(n0 + 1) * Kd);
        const float4* r2 = (const float4*)(in + (size_t)(n0 + 2) * Kd);
        const float4* r3 = (const float4*)(in + (size_t)(n0 + 3) * Kd);
        float a00 = b0, a01 = b1, a10 = b0, a11 = b1, a20 = b0, a21 = b1, a30 = b0, a31 = b1;
        for (int c = 0; c < Kd / 4; c++) {
            float4 h0 = r0[c], h1 = r1[c], h2 = r2[c], h3 = r3[c];
            float4 wA = sW4[(c * 64 + lane) * 2];
            float4 wB = sW4[(c * 64 + lane) * 2 + 1];
            a00 = fmaf(h0.x, wA.x, a00); a01 = fmaf(h0.x, wA.y, a01);
            a00 = fmaf(h0.y, wA.z, a00); a01 = fmaf(h0.y, wA.w, a01);
            a00 = fmaf(h0.z, wB.x, a00); a01 = fmaf(h0.z, wB.y, a01);
            a00 = fmaf(h0.w, wB.z, a00); a01 = fmaf(h0.w, wB.w, a01);
            a10 = fmaf(h1.x, wA.x, a10); a11 = fmaf(h1.x, wA.y, a11);
            a10 = fmaf(h1.y, wA.z, a10); a11 = fmaf(h1.y, wA.w, a11);
            a10 = fmaf(h1.z, wB.x, a10); a11 = fmaf(h1.z, wB.y, a11);
            a10 = fmaf(h1.w, wB.z, a10); a11 = fmaf(h1.w, wB.w, a11);
            a20 = fmaf(h2.x, wA.x, a20); a21 = fmaf(h2.x, wA.y, a21);
            a20 = fmaf(h2.y, wA.z, a20); a21 = fmaf(h2.y, wA.w, a21);
            a20 = fmaf(h2.z, wB.x, a20); a21 = fmaf(h2.z, wB.y, a21);
            a20 = fmaf(h2.w, wB.z, a20); a21 = fmaf(h2.w, wB.w, a21);
            a30 = fmaf(h3.x, wA.x, a30); a31 = fmaf(h3.x, wA.y, a31);
            a30 = fmaf(h3.y, wA.z, a30); a31 = fmaf(h3.y, wA.w, a31);
            a30 = fmaf(h3.z, wB.x, a30); a31 = fmaf(h3.z, wB.y, a31);
            a30 = fmaf(h3.w, wB.z, a30); a31 = fmaf(h3.w, wB.w, a31);
        }
        float2* tp = (float2*)t;
        float2 o0; o0.x = gelu_f(a00); o0.y = gelu_f(a01);
        float2 o1; o1.x = gelu_f(a10); o1.y = gelu_f(a11);
        float2 o2; o2.x = gelu_f(a20); o2.y = gelu_f(a21);
        float2 o3; o3.x = gelu_f(a30); o3.y = gelu_f(a31);
        tp[(size_t)n0 * 64 + lane] = o0;
        tp[(size_t)(n0 + 1) * 64 + lane] = o1;
        tp[(size_t)(n0 + 2) * 64 + lane] = o2;
        tp[(size_t)(n0 + 3) * 64 + lane] = o3;
    }
}

template <bool GELU_OUT>
__global__ __launch_bounds__(512) void mlp_layer2(const float* __restrict__ t, const float* __restrict__ Wb,
                                                  const float* __restrict__ bb, const float* __restrict__ g,
                                                  const float* __restrict__ bn, float* __restrict__ out) {
    __shared__ float sW[128 * 128];
    for (int idx = threadIdx.x; idx < 128 * 128; idx += 512) {
        int j = idx >> 7, c = idx & 127;
        sW[(((j >> 2) * 64 + (c >> 1)) << 3) + ((j & 3) << 1) + (c & 1)] = Wb[idx];
    }
    int lane = threadIdx.x & 63;
    int wsub = threadIdx.x >> 6;
    int f0 = lane * 2;
    float b0 = bb[f0], b1 = bb[f0 + 1];
    float g0 = g[f0], g1v = g[f0 + 1];
    float n0v = bn[f0], n1v = bn[f0 + 1];
    __syncthreads();
    const float4* sW4 = (const float4*)sW;
    const int nGroups = N_NODES / 4;
    for (int grp = blockIdx.x * 8 + wsub; grp < nGroups; grp += gridDim.x * 8) {
        int n0 = grp * 4;
        const float4* r0 = (const float4*)(t + (size_t)n0 * 128);
        const float4* r1 = (const float4*)(t + (size_t)(n0 + 1) * 128);
        const float4* r2 = (const float4*)(t + (size_t)(n0 + 2) * 128);
        const float4* r3 = (const float4*)(t + (size_t)(n0 + 3) * 128);
        float a00 = b0, a01 = b1, a10 = b0, a11 = b1, a20 = b0, a21 = b1, a30 = b0, a31 = b1;
        for (int c = 0; c < 32; c++) {
            float4 h0 = r0[c], h1 = r1[c], h2 = r2[c], h3 = r3[c];
            float4 wA = sW4[(c * 64 + lane) * 2];
            float4 wB = sW4[(c * 64 + lane) * 2 + 1];
            a00 = fmaf(h0.x, wA.x, a00); a01 = fmaf(h0.x, wA.y, a01);
            a00 = fmaf(h0.y, wA.z, a00); a01 = fmaf(h0.y, wA.w, a01);
            a00 = fmaf(h0.z, wB.x, a00); a01 = fmaf(h0.z, wB.y, a01);
            a00 = fmaf(h0.w, wB.z, a00); a01 = fmaf(h0.w, wB.w, a01);
            a10 = fmaf(h1.x, wA.x, a10); a11 = fmaf(h1.x, wA.y, a11);
            a10 = fmaf(h1.y, wA.z, a10); a11 = fmaf(h1.y, wA.w, a11);
            a10 = fmaf(h1.z, wB.x, a10); a11 = fmaf(h1.z, wB.y, a11);
            a10 = fmaf(h1.w, wB.z, a10); a11 = fmaf(h1.w, wB.w, a11);
            a20 = fmaf(h2.x, wA.x, a20); a21 = fmaf(h2.x, wA.y, a21);
            a20 = fmaf(h2.y, wA.z, a20); a21 = fmaf(h2.y, wA.w, a21);
            a20 = fmaf(h2.z, wB.x, a20); a21 = fmaf(h2.z, wB.y, a21);
            a20 = fmaf(h2.w, wB.z, a20); a21 = fmaf(h2.w, wB.w, a21);
            a30 = fmaf(h3.x, wA.x, a30); a31 = fmaf(h3.x, wA.y, a31);
            a30 = fmaf(h3.y, wA.z, a30); a31 = fmaf(h3.y, wA.w, a31);
            a30 = fmaf(h3.z, wB.x, a30); a31 = fmaf(h3.z, wB.y, a31);
            a30 = fmaf(h3.w, wB.z, a30); a31 = fmaf(h3.w, wB.w, a31);
        }
        if (GELU_OUT) {
            a00 = gelu_f(a00); a01 = gelu_f(a01);
            a10 = gelu_f(a10); a11 = gelu_f(a11);
            a20 = gelu_f(a20); a21 = gelu_f(a21);
            a30 = gelu_f(a30); a31 = gelu_f(a31);
        }
        float s0 = a00 + a01, q0 = a00 * a00 + a01 * a01;
        float s1 = a10 + a11, q1 = a10 * a10 + a11 * a11;
        float s2 = a20 + a21, q2 = a20 * a20 + a21 * a21;
        float s3 = a30 + a31, q3 = a30 * a30 + a31 * a31;
        for (int m = 32; m > 0; m >>= 1) {
            s0 += __shfl_xor(s0, m, 64); q0 += __shfl_xor(q0, m, 64);
            s1 += __shfl_xor(s1, m, 64); q1 += __shfl_xor(q1, m, 64);
            s2 += __shfl_xor(s2, m, 64); q2 += __shfl_xor(q2, m, 64);
            s3 += __shfl_xor(s3, m, 64); q3 += __shfl_xor(q3, m, 64);
        }
        float2* op = (float2*)out;
        {
            float mu = s0 * (1.0f / 128.0f);
            float rs = rsqrtf(q0 * (1.0f / 128.0f) - mu * mu + LN_EPS);
            float2 o; o.x = (a00 - mu) * rs * g0 + n0v; o.y = (a01 - mu) * rs * g1v + n1v;
            op[(size_t)n0 * 64 + lane] = o;
        }
        {
            float mu = s1 * (1.0f / 128.0f);
            float rs = rsqrtf(q1 * (1.0f / 128.0f) - mu * mu + LN_EPS);
            float2 o; o.x = (a10 - mu) * rs * g0 + n0v; o.y = (a11 - mu) * rs * g1v + n1v;
            op[(size_t)(n0 + 1) * 64 + lane] = o;
        }
        {
            float mu = s2 * (1.0f / 128.0f);
            float rs = rsqrtf(q2 * (1.0f / 128.0f) - mu * mu + LN_EPS);
            float2 o; o.x = (a20 - mu) * rs * g0 + n0v; o.y = (a21 - mu) * rs * g1v + n1v;
            op[(size_t)(n0 + 2) * 64 + lane] = o;
        }
        {
            float mu = s3 * (1.0f / 128.0f);
            float rs = rsqrtf(q3 * (1.0f / 128.0f) - mu * mu + LN_EPS);
            float2 o; o.x = (a30 - mu) * rs * g0 + n0v; o.y = (a31 - mu) * rs * g1v + n1v;
            op[(size_t)(n0 + 3) * 64 + lane] = o;
        }
    }
}

// ---------------- APPNP step (4x unrolled gather) ----------------

__global__ __launch_bounds__(256) void appnp_step(const float2* __restrict__ hin, const float2* __restrict__ anchor,
                                                  float2* __restrict__ hout, const int* __restrict__ rp,
                                                  const int2* __restrict__ esw, const float* __restrict__ selfw) {
    int gw = (blockIdx.x * 256 + threadIdx.x) >> 6;
    if (gw >= N_NODES) return;
    int lane = threadIdx.x & 63;
    size_t idx = (size_t)gw * 64 + lane;
    float swi = selfw[gw];
    float2 hc = hin[idx];
    float ax = swi * hc.x, ay = swi * hc.y;
    int j = rp[gw], s1 = rp[gw + 1];
    for (; j + 4 <= s1; j += 4) {
        int2 e0 = esw[j], e1 = esw[j + 1], e2 = esw[j + 2], e3 = esw[j + 3];
        float2 v0 = hin[(size_t)e0.x * 64 + lane];
        float2 v1 = hin[(size_t)e1.x * 64 + lane];
        float2 v2 = hin[(size_t)e2.x * 64 + lane];
        float2 v3 = hin[(size_t)e3.x * 64 + lane];
        float w0 = __int_as_float(e0.y), w1 = __int_as_float(e1.y);
        float w2 = __int_as_float(e2.y), w3 = __int_as_float(e3.y);
        ax = fmaf(w0, v0.x, ax); ay = fmaf(w0, v0.y, ay);
        ax = fmaf(w1, v1.x, ax); ay = fmaf(w1, v1.y, ay);
        ax = fmaf(w2, v2.x, ax); ay = fmaf(w2, v2.y, ay);
        ax = fmaf(w3, v3.x, ax); ay = fmaf(w3, v3.y, ay);
    }
    for (; j < s1; j++) {
        int2 e = esw[j];
        float2 v = hin[(size_t)e.x * 64 + lane];
        float w = __int_as_float(e.y);
        ax = fmaf(w, v.x, ax); ay = fmaf(w, v.y, ay);
    }
    float2 anc = anchor[idx];
    float2 o;
    o.x = 0.9f * ax + 0.1f * anc.x;
    o.y = 0.9f * ay + 0.1f * anc.y;
    hout[idx] = o;
}

// ---------------- Attentional pooling ----------------
// Coalesced-cooperative gate: one wave = 16 nodes; lane = nodeInWave*4 + quarter.
// Each lane loads 128B contiguous (its node's feature quarter), accumulates all 64
// output cols from LDS weights (17-float4 slot pad -> quarter-lanes on disjoint bank
// groups), shfl-reduce over quarters, redundant gelu-dot, store from quarter 0.

__global__ __launch_bounds__(256) void gate_kernel(const float* __restrict__ h, const float* __restrict__ Wg1,
                                                   const float* __restrict__ bg1, const float* __restrict__ Wg2,
                                                   const float* __restrict__ bg2, float* __restrict__ gate) {
    __shared__ float sW[128 * 68];  // slot (jj*4+sub), 17 float4 per slot
    __shared__ float sB[64], sV[64];
    for (int idx = threadIdx.x; idx < 128 * 64; idx += 256) {
        int j = idx >> 6, c = idx & 63;
        int slot = (j & 31) * 4 + (j >> 5);
        sW[slot * 68 + c] = Wg1[idx];
    }
    if (threadIdx.x < 64) { sB[threadIdx.x] = bg1[threadIdx.x]; sV[threadIdx.x] = Wg2[threadIdx.x]; }
    float b2 = bg2[0];
    __syncthreads();
    int wave = threadIdx.x >> 6;
    int lane = threadIdx.x & 63;
    int nIw = lane >> 2, sub = lane & 3;
    const float4* sW4 = (const float4*)sW;
    const int nTiles = N_NODES / 16;  // 6250, exact
    for (int tile = blockIdx.x * 4 + wave; tile < nTiles; tile += gridDim.x * 4) {
        int n = tile * 16 + nIw;
        const float4* hp = (const float4*)(h + (size_t)n * 128 + sub * 32);
        float4 hq[8];
        #pragma unroll
        for (int i = 0; i < 8; i++) hq[i] = hp[i];
        float4 acc[16];
        #pragma unroll
        for (int i = 0; i < 16; i++) { acc[i].x = 0.f; acc[i].y = 0.f; acc[i].z = 0.f; acc[i].w = 0.f; }
        #pragma unroll
        for (int i = 0; i < 8; i++) {
            float hv0 = hq[i].x, hv1 = hq[i].y, hv2 = hq[i].z, hv3 = hq[i].w;
            const float4* w0 = sW4 + (size_t)((i * 4 + 0) * 4 + sub) * 17;
            const float4* w1 = sW4 + (size_t)((i * 4 + 1) * 4 + sub) * 17;
            const float4* w2 = sW4 + (size_t)((i * 4 + 2) * 4 + sub) * 17;
            const float4* w3 = sW4 + (size_t)((i * 4 + 3) * 4 + sub) * 17;
            #pragma unroll
            for (int cq = 0; cq < 16; cq++) {
                float4 a = w0[cq], b = w1[cq], c = w2[cq], d = w3[cq];
                acc[cq].x = fmaf(hv0, a.x, acc[cq].x); acc[cq].y = fmaf(hv0, a.y, acc[cq].y);
                acc[cq].z = fmaf(hv0, a.z, acc[cq].z); acc[cq].w = fmaf(hv0, a.w, acc[cq].w);
                acc[cq].x = fmaf(hv1, b.x, acc[cq].x); acc[cq].y = fmaf(hv1, b.y, acc[cq].y);
                acc[cq].z = fmaf(hv1, b.z, acc[cq].z); acc[cq].w = fmaf(hv1, b.w, acc[cq].w);
                acc[cq].x = fmaf(hv2, c.x, acc[cq].x); acc[cq].y = fmaf(hv2, c.y, acc[cq].y);
                acc[cq].z = fmaf(hv2, c.z, acc[cq].z); acc[cq].w = fmaf(hv2, c.w, acc[cq].w);
                acc[cq].x = fmaf(hv3, d.x, acc[cq].x); acc[cq].y = fmaf(hv3, d.y, acc[cq].y);
                acc[cq].z = fmaf(hv3, d.z, acc[cq].z); acc[cq].w = fmaf(hv3, d.w, acc[cq].w);
            }
        }
        #pragma unroll
        for (int cq = 0; cq < 16; cq++) {
            acc[cq].x += __shfl_xor(acc[cq].x, 1, 64);
            acc[cq].y += __shfl_xor(acc[cq].y, 1, 64);
            acc[cq].z += __shfl_xor(acc[cq].z, 1, 64);
            acc[cq].w += __shfl_xor(acc[cq].w, 1, 64);
            acc[cq].x += __shfl_xor(acc[cq].x, 2, 64);
            acc[cq].y += __shfl_xor(acc[cq].y, 2, 64);
            acc[cq].z += __shfl_xor(acc[cq].z, 2, 64);
            acc[cq].w += __shfl_xor(acc[cq].w, 2, 64);
        }
        float part = 0.0f;
        #pragma unroll
        for (int cq = 0; cq < 16; cq++) {
            part += gelu_f(acc[cq].x + sB[cq * 4 + 0]) * sV[cq * 4 + 0];
            part += gelu_f(acc[cq].y + sB[cq * 4 + 1]) * sV[cq * 4 + 1];
            part += gelu_f(acc[cq].z + sB[cq * 4 + 2]) * sV[cq * 4 + 2];
            part += gelu_f(acc[cq].w + sB[cq * 4 + 3]) * sV[cq * 4 + 3];
        }
        if (sub == 0) gate[n] = part + b2;
    }
}

__global__ void seg_begin(const int* __restrict__ batch, int* __restrict__ gbeg) {
    int b = threadIdx.x;
    if (b > N_B) return;
    if (b == N_B) { gbeg[N_B] = N_NODES; return; }
    int lo = 0, hi = N_NODES;
    while (lo < hi) {
        int mid = (lo + hi) >> 1;
        if (batch[mid] < b) lo = mid + 1; else hi = mid;
    }
    gbeg[b] = lo;
}

__global__ __launch_bounds__(256) void seg_max(const float* __restrict__ gate, const int* __restrict__ gbeg,
                                               float* __restrict__ gmax) {
    int b = blockIdx.x;
    int s = gbeg[b], e = gbeg[b + 1];
    float m = -INFINITY;
    for (int i = s + threadIdx.x; i < e; i += 256) m = fmaxf(m, gate[i]);
    for (int o = 32; o > 0; o >>= 1) m = fmaxf(m, __shfl_xor(m, o, 64));
    __shared__ float red[4];
    if ((threadIdx.x & 63) == 0) red[threadIdx.x >> 6] = m;
    __syncthreads();
    if (threadIdx.x == 0) gmax[b] = fmaxf(fmaxf(red[0], red[1]), fmaxf(red[2], red[3]));
}

__global__ __launch_bounds__(256) void seg_sum(const float* __restrict__ gate, const int* __restrict__ gbeg,
                                               const float* __restrict__ gmax, float* __restrict__ gsum) {
    int b = blockIdx.x;
    int s = gbeg[b], e = gbeg[b + 1];
    float m = gmax[b];
    float acc = 0.0f;
    for (int i = s + threadIdx.x; i < e; i += 256) acc += expf(gate[i] - m);
    for (int o = 32; o > 0; o >>= 1) acc += __shfl_xor(acc, o, 64);
    __shared__ float red[4];
    if ((threadIdx.x & 63) == 0) red[threadIdx.x >> 6] = acc;
    __syncthreads();
    if (threadIdx.x == 0) gsum[b] = red[0] + red[1] + red[2] + red[3];
}

__global__ __launch_bounds__(512) void seg_pool(const float* __restrict__ h, const float* __restrict__ gate,
                                                const int* __restrict__ gbeg, const float* __restrict__ gmax,
                                                const float* __restrict__ gsum, float* __restrict__ gout) {
    int b = blockIdx.x;
    int team = threadIdx.x >> 7;
    int f = threadIdx.x & 127;
    int s = gbeg[b], e = gbeg[b + 1];
    float m = gmax[b];
    float inv = (e > s) ? 1.0f / gsum[b] : 0.0f;
    float acc = 0.0f;
    for (int i = s + team; i < e; i += 4) {
        float a = expf(gate[i] - m) * inv;
        acc = fmaf(a, h[(size_t)i * 128 + f], acc);
    }
    __shared__ float red[4][128];
    red[team][f] = acc;
    __syncthreads();
    if (team == 0) gout[b * 128 + f] = red[0][f] + red[1][f] + red[2][f] + red[3][f];
}

// ---------------- host launch ----------------

extern "C" void kernel_launch(void* const* d_in, const int* in_sizes, int n_in,
                              void* d_out, int out_size, void* d_ws, size_t ws_size,
                              hipStream_t stream) {
    const float* x     = (const float*)d_in[0];
    const int*   ei    = (const int*)d_in[1];
    const int*   batch = (const int*)d_in[2];
    const float* ea    = (const float*)d_in[3];
    const float* We1 = (const float*)d_in[4];
    const float* be1 = (const float*)d_in[5];
    const float* W1a = (const float*)d_in[6];
    const float* b1a = (const float*)d_in[7];
    const float* W1b = (const float*)d_in[8];
    const float* b1b = (const float*)d_in[9];
    const float* g1  = (const float*)d_in[10];
    const float* bn1 = (const float*)d_in[11];
    const float* We2 = (const float*)d_in[12];
    const float* be2 = (const float*)d_in[13];
    const float* W2a = (const float*)d_in[14];
    const float* b2a = (const float*)d_in[15];
    const float* W2b = (const float*)d_in[16];
    const float* b2b = (const float*)d_in[17];
    const float* g2  = (const float*)d_in[18];
    const float* bn2 = (const float*)d_in[19];
    const float* Wg1 = (const float*)d_in[20];
    const float* bg1 = (const float*)d_in[21];
    const float* Wg2 = (const float*)d_in[22];
    const float* bg2 = (const float*)d_in[23];

    float* outH = (float*)d_out;                 // [N,128] final h
    float* outG = outH + (size_t)N_NODES * 128;  // [B,128] pooled

    char* w = (char*)d_ws;
    auto carve = [&](size_t bytes) {
        void* p = (void*)w;
        w += ((bytes + 255) / 256) * 256;
        return p;
    };
    float*  bufB   = (float*)carve((size_t)N_NODES * 128 * 4);
    float*  bufC   = (float*)carve((size_t)N_NODES * 128 * 4);
    int2*   esw    = (int2*)carve((size_t)N_EDGES * 8);
    float2* eea    = (float2*)carve((size_t)N_EDGES * 8);
    int*    counts = (int*)carve((size_t)N_NODES * 4);
    int*    rp     = (int*)carve((size_t)(N_NODES + 1) * 4);
    int*    cursor = (int*)carve((size_t)N_NODES * 4);
    float*  dis    = (float*)carve((size_t)N_NODES * 4);
    float*  selfw  = (float*)carve((size_t)N_NODES * 4);
    float*  gate   = (float*)carve((size_t)N_NODES * 4);
    int*    bsum   = (int*)carve(128 * 4);
    float*  gmax   = (float*)carve(N_B * 4);
    float*  gsum   = (float*)carve(N_B * 4);
    int*    gbeg   = (int*)carve((N_B + 1) * 4);

    const int* src = ei;
    const int* dst = ei + N_EDGES;

    const int NB_SCAN = (N_NODES + 1023) / 1024;  // 98
    const int EB = (N_EDGES + 255) / 256;
    const int NBLK = (N_NODES + 255) / 256;
    const int WBLK = (N_NODES + 3) / 4;  // one wave per node, 4 waves/block

    // CSR build
    hipMemsetAsync(counts, 0, (size_t)N_NODES * 4, stream);
    hist_kernel<<<EB, 256, 0, stream>>>(dst, counts);
    deg_kernel<<<NBLK, 256, 0, stream>>>(counts, dis, selfw);
    scan1<<<NB_SCAN, 1024, 0, stream>>>(counts, rp, bsum);
    scan2<<<1, 64, 0, stream>>>(bsum, NB_SCAN);
    scan3<<<NB_SCAN, 1024, 0, stream>>>(rp, bsum, cursor);
    scatter_kernel<<<EB, 256, 0, stream>>>(src, dst, ea, dis, cursor, esw, eea);

    // conv1: gather (x -> bufB[:,0:64]) -> mlp1 (t -> outH) -> mlp2+gelu+LN (h1 -> bufB)
    conv1_gather<<<WBLK, 256, 0, stream>>>(x, rp, esw, eea, We1, be1, bufB);
    mlp_layer1<64><<<1024, 512, 0, stream>>>(bufB, W1a, b1a, outH);
    mlp_layer2<true><<<512, 512, 0, stream>>>(outH, W1b, b1b, g1, bn1, bufB);

    // conv2: gather (bufB -> bufC) -> mlp1 (t -> outH) -> mlp2+LN (anchor -> bufB)
    conv2_gather<<<WBLK, 256, 0, stream>>>(bufB, rp, esw, eea, We2, be2, bufC);
    mlp_layer1<128><<<512, 512, 0, stream>>>(bufC, W2a, b2a, outH);
    mlp_layer2<false><<<512, 512, 0, stream>>>(outH, W2b, b2b, g2, bn2, bufB);

    // APPNP: anchor = bufB; ping-pong bufC <-> outH; iter 16 (even) lands in outH
    const float2* anchor2 = (const float2*)bufB;
    float2* pa = (float2*)bufC;
    float2* pb = (float2*)outH;
    const float2* cur = (const float2*)bufB;  // h0 = anchor
    for (int k = 1; k <= K_ITER; k++) {
        float2* dstbuf = (k & 1) ? pa : pb;
        appnp_step<<<WBLK, 256, 0, stream>>>(cur, anchor2, dstbuf, rp, esw, selfw);
        cur = dstbuf;
    }

    // pooling on outH
    gate_kernel<<<1024, 256, 0, stream>>>(outH, Wg1, bg1, Wg2, bg2, gate);
    seg_begin<<<1, 128, 0, stream>>>(batch, gbeg);
    seg_max<<<N_B, 256, 0, stream>>>(gate, gbeg, gmax);
    seg_sum<<<N_B, 256, 0, stream>>>(gate, gbeg, gmax, gsum);
    seg_pool<<<N_B, 512, 0, stream>>>(outH, gate, gbeg, gmax, gsum, outG);
}

// Round 4
// 2719.496 us; speedup vs baseline: 1.7133x; 1.2704x over previous
//
#include <hip/hip_runtime.h>
#include <math.h>

#define N_NODES 100000
#define N_EDGES 1600000
#define N_B 64
#define D_IN 64
#define D_HID 128
#define D_OUT 128
#define K_ITER 16
#define LN_EPS 1e-5f

__device__ __forceinline__ float gelu_f(float x) {
    return 0.5f * x * (1.0f + erff(0.70710678118654752440f * x));
}

__device__ __forceinline__ unsigned pack_bf2(float a, float b) {
    unsigned ua = __float_as_uint(a), ub = __float_as_uint(b);
    ua += 0x7fffu + ((ua >> 16) & 1u);
    ub += 0x7fffu + ((ub >> 16) & 1u);
    return (ua >> 16) | (ub & 0xffff0000u);
}
__device__ __forceinline__ float ubx(unsigned u) { return __uint_as_float(u << 16); }
__device__ __forceinline__ float uby(unsigned u) { return __uint_as_float(u & 0xffff0000u); }

// ---------------- CSR build ----------------

__global__ __launch_bounds__(256) void hist_kernel(const int* __restrict__ dst, int* __restrict__ counts) {
    int e = blockIdx.x * 256 + threadIdx.x;
    if (e < N_EDGES) atomicAdd(&counts[dst[e]], 1);
}

__global__ __launch_bounds__(256) void deg_kernel(const int* __restrict__ counts,
                                                  float* __restrict__ dis, float* __restrict__ selfw) {
    int i = blockIdx.x * 256 + threadIdx.x;
    if (i < N_NODES) {
        float d = (float)(counts[i] + 1);
        dis[i] = 1.0f / sqrtf(d);
        selfw[i] = 1.0f / d;
    }
}

__global__ __launch_bounds__(1024) void scan1(const int* __restrict__ counts, int* __restrict__ rp,
                                              int* __restrict__ bsum) {
    __shared__ int tmp[1024];
    int t = threadIdx.x;
    int idx = blockIdx.x * 1024 + t;
    int v = (idx < N_NODES) ? counts[idx] : 0;
    tmp[t] = v;
    __syncthreads();
    for (int o = 1; o < 1024; o <<= 1) {
        int add = (t >= o) ? tmp[t - o] : 0;
        __syncthreads();
        tmp[t] += add;
        __syncthreads();
    }
    if (idx < N_NODES) rp[idx] = tmp[t] - v;   // exclusive
    if (t == 1023) bsum[blockIdx.x] = tmp[t];
}

__global__ void scan2(int* bsum, int nb) {
    if (threadIdx.x == 0 && blockIdx.x == 0) {
        int acc = 0;
        for (int i = 0; i < nb; i++) { int v = bsum[i]; bsum[i] = acc; acc += v; }
    }
}

__global__ __launch_bounds__(1024) void scan3(int* __restrict__ rp, const int* __restrict__ bsum,
                                              int* __restrict__ cursor) {
    int t = threadIdx.x;
    int idx = blockIdx.x * 1024 + t;
    if (idx < N_NODES) {
        int v = rp[idx] + bsum[blockIdx.x];
        rp[idx] = v;
        cursor[idx] = v;
    }
    if (idx == 0) rp[N_NODES] = N_EDGES;
}

__global__ __launch_bounds__(256) void scatter_kernel(const int* __restrict__ src, const int* __restrict__ dst,
                                                      const float* __restrict__ ea, const float* __restrict__ dis,
                                                      int* __restrict__ cursor, int2* __restrict__ esw,
                                                      float2* __restrict__ eea) {
    int e = blockIdx.x * 256 + threadIdx.x;
    if (e >= N_EDGES) return;
    int s = src[e], d = dst[e];
    int pos = atomicAdd(&cursor[d], 1);
    int2 sw;
    sw.x = s;
    sw.y = __float_as_int(dis[s] * dis[d]);
    esw[pos] = sw;
    float2 e2;
    e2.x = ea[e * 2];
    e2.y = ea[e * 2 + 1];
    eea[pos] = e2;
}

// ---------------- GINE gathers (one wave per node, 4x unrolled) ----------------

__global__ __launch_bounds__(256) void conv1_gather(const float* __restrict__ x, const int* __restrict__ rp,
                                                    const int2* __restrict__ esw, const float2* __restrict__ eea,
                                                    const float* __restrict__ We1, const float* __restrict__ be1,
                                                    float* __restrict__ out) {
    int gw = (blockIdx.x * 256 + threadIdx.x) >> 6;
    if (gw >= N_NODES) return;
    int lane = threadIdx.x & 63;
    float w0 = We1[lane], w1 = We1[64 + lane], bb = be1[lane];
    float acc = x[(size_t)gw * 64 + lane];
    int j = rp[gw], s1 = rp[gw + 1];
    for (; j + 4 <= s1; j += 4) {
        int2 e0 = esw[j], e1 = esw[j + 1], e2 = esw[j + 2], e3 = esw[j + 3];
        float2 a0 = eea[j], a1 = eea[j + 1], a2 = eea[j + 2], a3 = eea[j + 3];
        float v0 = x[(size_t)e0.x * 64 + lane];
        float v1 = x[(size_t)e1.x * 64 + lane];
        float v2 = x[(size_t)e2.x * 64 + lane];
        float v3 = x[(size_t)e3.x * 64 + lane];
        acc += fmaxf(v0 + a0.x * w0 + a0.y * w1 + bb, 0.0f);
        acc += fmaxf(v1 + a1.x * w0 + a1.y * w1 + bb, 0.0f);
        acc += fmaxf(v2 + a2.x * w0 + a2.y * w1 + bb, 0.0f);
        acc += fmaxf(v3 + a3.x * w0 + a3.y * w1 + bb, 0.0f);
    }
    for (; j < s1; j++) {
        int2 e = esw[j];
        float2 a = eea[j];
        float v = x[(size_t)e.x * 64 + lane];
        acc += fmaxf(v + a.x * w0 + a.y * w1 + bb, 0.0f);
    }
    out[(size_t)gw * 64 + lane] = acc;
}

__global__ __launch_bounds__(256) void conv2_gather(const float* __restrict__ h1, const int* __restrict__ rp,
                                                    const int2* __restrict__ esw, const float2* __restrict__ eea,
                                                    const float* __restrict__ We2, const float* __restrict__ be2,
                                                    float* __restrict__ out) {
    int gw = (blockIdx.x * 256 + threadIdx.x) >> 6;
    if (gw >= N_NODES) return;
    int lane = threadIdx.x & 63;
    int f0 = lane * 2;
    float w00 = We2[f0], w01 = We2[f0 + 1];
    float w10 = We2[128 + f0], w11 = We2[128 + f0 + 1];
    float b0 = be2[f0], b1 = be2[f0 + 1];
    const float2* h2 = (const float2*)h1;
    float2 hc = h2[(size_t)gw * 64 + lane];
    float a0 = hc.x, a1 = hc.y;
    int j = rp[gw], s1 = rp[gw + 1];
    for (; j + 4 <= s1; j += 4) {
        int2 e0 = esw[j], e1 = esw[j + 1], e2 = esw[j + 2], e3 = esw[j + 3];
        float2 q0 = eea[j], q1 = eea[j + 1], q2 = eea[j + 2], q3 = eea[j + 3];
        float2 v0 = h2[(size_t)e0.x * 64 + lane];
        float2 v1 = h2[(size_t)e1.x * 64 + lane];
        float2 v2 = h2[(size_t)e2.x * 64 + lane];
        float2 v3 = h2[(size_t)e3.x * 64 + lane];
        a0 += fmaxf(v0.x + q0.x * w00 + q0.y * w10 + b0, 0.0f);
        a1 += fmaxf(v0.y + q0.x * w01 + q0.y * w11 + b1, 0.0f);
        a0 += fmaxf(v1.x + q1.x * w00 + q1.y * w10 + b0, 0.0f);
        a1 += fmaxf(v1.y + q1.x * w01 + q1.y * w11 + b1, 0.0f);
        a0 += fmaxf(v2.x + q2.x * w00 + q2.y * w10 + b0, 0.0f);
        a1 += fmaxf(v2.y + q2.x * w01 + q2.y * w11 + b1, 0.0f);
        a0 += fmaxf(v3.x + q3.x * w00 + q3.y * w10 + b0, 0.0f);
        a1 += fmaxf(v3.y + q3.x * w01 + q3.y * w11 + b1, 0.0f);
    }
    for (; j < s1; j++) {
        int2 e = esw[j];
        float2 q = eea[j];
        float2 v = h2[(size_t)e.x * 64 + lane];
        a0 += fmaxf(v.x + q.x * w00 + q.y * w10 + b0, 0.0f);
        a1 += fmaxf(v.y + q.x * w01 + q.y * w11 + b1, 0.0f);
    }
    out[(size_t)gw * 128 + f0] = a0;
    out[(size_t)gw * 128 + f0 + 1] = a1;
}

// ---------------- Node MLPs: 4 nodes/wave, 8 accumulators ----------------
// LDS: two lane-contiguous float4 arrays (16B lane stride = conflict-free b128).
// sWA[c*64+l] = {W[4c][2l],W[4c][2l+1],W[4c+1][2l],W[4c+1][2l+1]}
// sWB[c*64+l] = {W[4c+2][2l],W[4c+2][2l+1],W[4c+3][2l],W[4c+3][2l+1]}

template <int Kd>
__global__ __launch_bounds__(512) void mlp_layer1(const float* __restrict__ in, const float* __restrict__ Wa,
                                                  const float* __restrict__ ba, float* __restrict__ t) {
    __shared__ float sWA[Kd * 64];
    __shared__ float sWB[Kd * 64];
    for (int idx = threadIdx.x; idx < Kd * 128; idx += 512) {
        int j = idx >> 7, c = idx & 127;
        int chunk = j >> 2, within = j & 3, ln = c >> 1, cp = c & 1;
        float v = Wa[idx];
        if (within < 2) sWA[(chunk * 64 + ln) * 4 + within * 2 + cp] = v;
        else            sWB[(chunk * 64 + ln) * 4 + (within - 2) * 2 + cp] = v;
    }
    int lane = threadIdx.x & 63;
    int wsub = threadIdx.x >> 6;  // 0..7
    int f0 = lane * 2;
    float b0 = ba[f0], b1 = ba[f0 + 1];
    __syncthreads();
    const float4* sWA4 = (const float4*)sWA;
    const float4* sWB4 = (const float4*)sWB;
    const int nGroups = N_NODES / 4;
    for (int g = blockIdx.x * 8 + wsub; g < nGroups; g += gridDim.x * 8) {
        int n0 = g * 4;
        const float4* r0 = (const float4*)(in + (size_t)n0 * Kd);
        const float4* r1 = (const float4*)(in + (size_t)(n0 + 1) * Kd);
        const float4* r2 = (const float4*)(in + (size_t)(n0 + 2) * Kd);
        const float4* r3 = (const float4*)(in + (size_t)(n0 + 3) * Kd);
        float a00 = b0, a01 = b1, a10 = b0, a11 = b1, a20 = b0, a21 = b1, a30 = b0, a31 = b1;
        for (int c = 0; c < Kd / 4; c++) {
            float4 h0 = r0[c], h1 = r1[c], h2 = r2[c], h3 = r3[c];
            float4 wA = sWA4[c * 64 + lane];
            float4 wB = sWB4[c * 64 + lane];
            a00 = fmaf(h0.x, wA.x, a00); a01 = fmaf(h0.x, wA.y, a01);
            a00 = fmaf(h0.y, wA.z, a00); a01 = fmaf(h0.y, wA.w, a01);
            a00 = fmaf(h0.z, wB.x, a00); a01 = fmaf(h0.z, wB.y, a01);
            a00 = fmaf(h0.w, wB.z, a00); a01 = fmaf(h0.w, wB.w, a01);
            a10 = fmaf(h1.x, wA.x, a10); a11 = fmaf(h1.x, wA.y, a11);
            a10 = fmaf(h1.y, wA.z, a10); a11 = fmaf(h1.y, wA.w, a11);
            a10 = fmaf(h1.z, wB.x, a10); a11 = fmaf(h1.z, wB.y, a11);
            a10 = fmaf(h1.w, wB.z, a10); a11 = fmaf(h1.w, wB.w, a11);
            a20 = fmaf(h2.x, wA.x, a20); a21 = fmaf(h2.x, wA.y, a21);
            a20 = fmaf(h2.y, wA.z, a20); a21 = fmaf(h2.y, wA.w, a21);
            a20 = fmaf(h2.z, wB.x, a20); a21 = fmaf(h2.z, wB.y, a21);
            a20 = fmaf(h2.w, wB.z, a20); a21 = fmaf(h2.w, wB.w, a21);
            a30 = fmaf(h3.x, wA.x, a30); a31 = fmaf(h3.x, wA.y, a31);
            a30 = fmaf(h3.y, wA.z, a30); a31 = fmaf(h3.y, wA.w, a31);
            a30 = fmaf(h3.z, wB.x, a30); a31 = fmaf(h3.z, wB.y, a31);
            a30 = fmaf(h3.w, wB.z, a30); a31 = fmaf(h3.w, wB.w, a31);
        }
        float2* tp = (float2*)t;
        float2 o0; o0.x = gelu_f(a00); o0.y = gelu_f(a01);
        float2 o1; o1.x = gelu_f(a10); o1.y = gelu_f(a11);
        float2 o2; o2.x = gelu_f(a20); o2.y = gelu_f(a21);
        float2 o3; o3.x = gelu_f(a30); o3.y = gelu_f(a31);
        tp[(size_t)n0 * 64 + lane] = o0;
        tp[(size_t)(n0 + 1) * 64 + lane] = o1;
        tp[(size_t)(n0 + 2) * 64 + lane] = o2;
        tp[(size_t)(n0 + 3) * 64 + lane] = o3;
    }
}

template <bool GELU_OUT>
__global__ __launch_bounds__(512) void mlp_layer2(const float* __restrict__ t, const float* __restrict__ Wb,
                                                  const float* __restrict__ bb, const float* __restrict__ g,
                                                  const float* __restrict__ bn, float* __restrict__ out) {
    __shared__ float sWA[128 * 64];
    __shared__ float sWB[128 * 64];
    for (int idx = threadIdx.x; idx < 128 * 128; idx += 512) {
        int j = idx >> 7, c = idx & 127;
        int chunk = j >> 2, within = j & 3, ln = c >> 1, cp = c & 1;
        float v = Wb[idx];
        if (within < 2) sWA[(chunk * 64 + ln) * 4 + within * 2 + cp] = v;
        else            sWB[(chunk * 64 + ln) * 4 + (within - 2) * 2 + cp] = v;
    }
    int lane = threadIdx.x & 63;
    int wsub = threadIdx.x >> 6;
    int f0 = lane * 2;
    float b0 = bb[f0], b1 = bb[f0 + 1];
    float g0 = g[f0], g1v = g[f0 + 1];
    float n0v = bn[f0], n1v = bn[f0 + 1];
    __syncthreads();
    const float4* sWA4 = (const float4*)sWA;
    const float4* sWB4 = (const float4*)sWB;
    const int nGroups = N_NODES / 4;
    for (int grp = blockIdx.x * 8 + wsub; grp < nGroups; grp += gridDim.x * 8) {
        int n0 = grp * 4;
        const float4* r0 = (const float4*)(t + (size_t)n0 * 128);
        const float4* r1 = (const float4*)(t + (size_t)(n0 + 1) * 128);
        const float4* r2 = (const float4*)(t + (size_t)(n0 + 2) * 128);
        const float4* r3 = (const float4*)(t + (size_t)(n0 + 3) * 128);
        float a00 = b0, a01 = b1, a10 = b0, a11 = b1, a20 = b0, a21 = b1, a30 = b0, a31 = b1;
        for (int c = 0; c < 32; c++) {
            float4 h0 = r0[c], h1 = r1[c], h2 = r2[c], h3 = r3[c];
            float4 wA = sWA4[c * 64 + lane];
            float4 wB = sWB4[c * 64 + lane];
            a00 = fmaf(h0.x, wA.x, a00); a01 = fmaf(h0.x, wA.y, a01);
            a00 = fmaf(h0.y, wA.z, a00); a01 = fmaf(h0.y, wA.w, a01);
            a00 = fmaf(h0.z, wB.x, a00); a01 = fmaf(h0.z, wB.y, a01);
            a00 = fmaf(h0.w, wB.z, a00); a01 = fmaf(h0.w, wB.w, a01);
            a10 = fmaf(h1.x, wA.x, a10); a11 = fmaf(h1.x, wA.y, a11);
            a10 = fmaf(h1.y, wA.z, a10); a11 = fmaf(h1.y, wA.w, a11);
            a10 = fmaf(h1.z, wB.x, a10); a11 = fmaf(h1.z, wB.y, a11);
            a10 = fmaf(h1.w, wB.z, a10); a11 = fmaf(h1.w, wB.w, a11);
            a20 = fmaf(h2.x, wA.x, a20); a21 = fmaf(h2.x, wA.y, a21);
            a20 = fmaf(h2.y, wA.z, a20); a21 = fmaf(h2.y, wA.w, a21);
            a20 = fmaf(h2.z, wB.x, a20); a21 = fmaf(h2.z, wB.y, a21);
            a20 = fmaf(h2.w, wB.z, a20); a21 = fmaf(h2.w, wB.w, a21);
            a30 = fmaf(h3.x, wA.x, a30); a31 = fmaf(h3.x, wA.y, a31);
            a30 = fmaf(h3.y, wA.z, a30); a31 = fmaf(h3.y, wA.w, a31);
            a30 = fmaf(h3.z, wB.x, a30); a31 = fmaf(h3.z, wB.y, a31);
            a30 = fmaf(h3.w, wB.z, a30); a31 = fmaf(h3.w, wB.w, a31);
        }
        if (GELU_OUT) {
            a00 = gelu_f(a00); a01 = gelu_f(a01);
            a10 = gelu_f(a10); a11 = gelu_f(a11);
            a20 = gelu_f(a20); a21 = gelu_f(a21);
            a30 = gelu_f(a30); a31 = gelu_f(a31);
        }
        float s0 = a00 + a01, q0 = a00 * a00 + a01 * a01;
        float s1 = a10 + a11, q1 = a10 * a10 + a11 * a11;
        float s2 = a20 + a21, q2 = a20 * a20 + a21 * a21;
        float s3 = a30 + a31, q3 = a30 * a30 + a31 * a31;
        for (int m = 32; m > 0; m >>= 1) {
            s0 += __shfl_xor(s0, m, 64); q0 += __shfl_xor(q0, m, 64);
            s1 += __shfl_xor(s1, m, 64); q1 += __shfl_xor(q1, m, 64);
            s2 += __shfl_xor(s2, m, 64); q2 += __shfl_xor(q2, m, 64);
            s3 += __shfl_xor(s3, m, 64); q3 += __shfl_xor(q3, m, 64);
        }
        float2* op = (float2*)out;
        {
            float mu = s0 * (1.0f / 128.0f);
            float rs = rsqrtf(q0 * (1.0f / 128.0f) - mu * mu + LN_EPS);
            float2 o; o.x = (a00 - mu) * rs * g0 + n0v; o.y = (a01 - mu) * rs * g1v + n1v;
            op[(size_t)n0 * 64 + lane] = o;
        }
        {
            float mu = s1 * (1.0f / 128.0f);
            float rs = rsqrtf(q1 * (1.0f / 128.0f) - mu * mu + LN_EPS);
            float2 o; o.x = (a10 - mu) * rs * g0 + n0v; o.y = (a11 - mu) * rs * g1v + n1v;
            op[(size_t)(n0 + 1) * 64 + lane] = o;
        }
        {
            float mu = s2 * (1.0f / 128.0f);
            float rs = rsqrtf(q2 * (1.0f / 128.0f) - mu * mu + LN_EPS);
            float2 o; o.x = (a20 - mu) * rs * g0 + n0v; o.y = (a21 - mu) * rs * g1v + n1v;
            op[(size_t)(n0 + 2) * 64 + lane] = o;
        }
        {
            float mu = s3 * (1.0f / 128.0f);
            float rs = rsqrtf(q3 * (1.0f / 128.0f) - mu * mu + LN_EPS);
            float2 o; o.x = (a30 - mu) * rs * g0 + n0v; o.y = (a31 - mu) * rs * g1v + n1v;
            op[(size_t)(n0 + 3) * 64 + lane] = o;
        }
    }
}

// ---------------- APPNP (bf16 propagated state, f32 accumulation) ----------------

__global__ __launch_bounds__(256) void f32_to_bf2(const float2* __restrict__ in, unsigned* __restrict__ out) {
    int i = blockIdx.x * 256 + threadIdx.x;
    if (i < N_NODES * 64) { float2 v = in[i]; out[i] = pack_bf2(v.x, v.y); }
}

template <bool LAST>
__global__ __launch_bounds__(256) void appnp_step_bf(const unsigned* __restrict__ hin,
                                                     const float2* __restrict__ anchor,
                                                     unsigned* __restrict__ hout, float2* __restrict__ houtf,
                                                     const int* __restrict__ rp, const int2* __restrict__ esw,
                                                     const float* __restrict__ selfw) {
    int gw = (blockIdx.x * 256 + threadIdx.x) >> 6;
    if (gw >= N_NODES) return;
    int lane = threadIdx.x & 63;
    size_t idx = (size_t)gw * 64 + lane;
    float swi = selfw[gw];
    unsigned hcp = hin[idx];
    float ax = swi * ubx(hcp), ay = swi * uby(hcp);
    int j = rp[gw], s1 = rp[gw + 1];
    for (; j + 4 <= s1; j += 4) {
        int2 e0 = esw[j], e1 = esw[j + 1], e2 = esw[j + 2], e3 = esw[j + 3];
        unsigned v0 = hin[(size_t)e0.x * 64 + lane];
        unsigned v1 = hin[(size_t)e1.x * 64 + lane];
        unsigned v2 = hin[(size_t)e2.x * 64 + lane];
        unsigned v3 = hin[(size_t)e3.x * 64 + lane];
        float w0 = __int_as_float(e0.y), w1 = __int_as_float(e1.y);
        float w2 = __int_as_float(e2.y), w3 = __int_as_float(e3.y);
        ax = fmaf(w0, ubx(v0), ax); ay = fmaf(w0, uby(v0), ay);
        ax = fmaf(w1, ubx(v1), ax); ay = fmaf(w1, uby(v1), ay);
        ax = fmaf(w2, ubx(v2), ax); ay = fmaf(w2, uby(v2), ay);
        ax = fmaf(w3, ubx(v3), ax); ay = fmaf(w3, uby(v3), ay);
    }
    for (; j < s1; j++) {
        int2 e = esw[j];
        unsigned v = hin[(size_t)e.x * 64 + lane];
        float w = __int_as_float(e.y);
        ax = fmaf(w, ubx(v), ax); ay = fmaf(w, uby(v), ay);
    }
    float2 anc = anchor[idx];
    float ox = 0.9f * ax + 0.1f * anc.x;
    float oy = 0.9f * ay + 0.1f * anc.y;
    if (LAST) {
        float2 o; o.x = ox; o.y = oy;
        houtf[idx] = o;
    } else {
        hout[idx] = pack_bf2(ox, oy);
    }
}

// ---------------- Attentional pooling ----------------

__global__ __launch_bounds__(256) void gate_kernel(const float* __restrict__ h, const float* __restrict__ Wg1,
                                                   const float* __restrict__ bg1, const float* __restrict__ Wg2,
                                                   const float* __restrict__ bg2, float* __restrict__ gate) {
    __shared__ float sW[128 * 68];  // slot (jj*4+sub), 17 float4 per slot
    __shared__ float sB[64], sV[64];
    for (int idx = threadIdx.x; idx < 128 * 64; idx += 256) {
        int j = idx >> 6, c = idx & 63;
        int slot = (j & 31) * 4 + (j >> 5);
        sW[slot * 68 + c] = Wg1[idx];
    }
    if (threadIdx.x < 64) { sB[threadIdx.x] = bg1[threadIdx.x]; sV[threadIdx.x] = Wg2[threadIdx.x]; }
    float b2 = bg2[0];
    __syncthreads();
    int wave = threadIdx.x >> 6;
    int lane = threadIdx.x & 63;
    int nIw = lane >> 2, sub = lane & 3;
    const float4* sW4 = (const float4*)sW;
    const int nTiles = N_NODES / 16;  // 6250, exact
    for (int tile = blockIdx.x * 4 + wave; tile < nTiles; tile += gridDim.x * 4) {
        int n = tile * 16 + nIw;
        const float4* hp = (const float4*)(h + (size_t)n * 128 + sub * 32);
        float4 hq[8];
        #pragma unroll
        for (int i = 0; i < 8; i++) hq[i] = hp[i];
        float4 acc[16];
        #pragma unroll
        for (int i = 0; i < 16; i++) { acc[i].x = 0.f; acc[i].y = 0.f; acc[i].z = 0.f; acc[i].w = 0.f; }
        #pragma unroll
        for (int i = 0; i < 8; i++) {
            float hv0 = hq[i].x, hv1 = hq[i].y, hv2 = hq[i].z, hv3 = hq[i].w;
            const float4* w0 = sW4 + (size_t)((i * 4 + 0) * 4 + sub) * 17;
            const float4* w1 = sW4 + (size_t)((i * 4 + 1) * 4 + sub) * 17;
            const float4* w2 = sW4 + (size_t)((i * 4 + 2) * 4 + sub) * 17;
            const float4* w3 = sW4 + (size_t)((i * 4 + 3) * 4 + sub) * 17;
            #pragma unroll
            for (int cq = 0; cq < 16; cq++) {
                float4 a = w0[cq], b = w1[cq], c = w2[cq], d = w3[cq];
                acc[cq].x = fmaf(hv0, a.x, acc[cq].x); acc[cq].y = fmaf(hv0, a.y, acc[cq].y);
                acc[cq].z = fmaf(hv0, a.z, acc[cq].z); acc[cq].w = fmaf(hv0, a.w, acc[cq].w);
                acc[cq].x = fmaf(hv1, b.x, acc[cq].x); acc[cq].y = fmaf(hv1, b.y, acc[cq].y);
                acc[cq].z = fmaf(hv1, b.z, acc[cq].z); acc[cq].w = fmaf(hv1, b.w, acc[cq].w);
                acc[cq].x = fmaf(hv2, c.x, acc[cq].x); acc[cq].y = fmaf(hv2, c.y, acc[cq].y);
                acc[cq].z = fmaf(hv2, c.z, acc[cq].z); acc[cq].w = fmaf(hv2, c.w, acc[cq].w);
                acc[cq].x = fmaf(hv3, d.x, acc[cq].x); acc[cq].y = fmaf(hv3, d.y, acc[cq].y);
                acc[cq].z = fmaf(hv3, d.z, acc[cq].z); acc[cq].w = fmaf(hv3, d.w, acc[cq].w);
            }
        }
        #pragma unroll
        for (int cq = 0; cq < 16; cq++) {
            acc[cq].x += __shfl_xor(acc[cq].x, 1, 64);
            acc[cq].y += __shfl_xor(acc[cq].y, 1, 64);
            acc[cq].z += __shfl_xor(acc[cq].z, 1, 64);
            acc[cq].w += __shfl_xor(acc[cq].w, 1, 64);
            acc[cq].x += __shfl_xor(acc[cq].x, 2, 64);
            acc[cq].y += __shfl_xor(acc[cq].y, 2, 64);
            acc[cq].z += __shfl_xor(acc[cq].z, 2, 64);
            acc[cq].w += __shfl_xor(acc[cq].w, 2, 64);
        }
        float part = 0.0f;
        #pragma unroll
        for (int cq = 0; cq < 16; cq++) {
            part += gelu_f(acc[cq].x + sB[cq * 4 + 0]) * sV[cq * 4 + 0];
            part += gelu_f(acc[cq].y + sB[cq * 4 + 1]) * sV[cq * 4 + 1];
            part += gelu_f(acc[cq].z + sB[cq * 4 + 2]) * sV[cq * 4 + 2];
            part += gelu_f(acc[cq].w + sB[cq * 4 + 3]) * sV[cq * 4 + 3];
        }
        if (sub == 0) gate[n] = part + b2;
    }
}

__global__ void seg_begin(const int* __restrict__ batch, int* __restrict__ gbeg) {
    int b = threadIdx.x;
    if (b > N_B) return;
    if (b == N_B) { gbeg[N_B] = N_NODES; return; }
    int lo = 0, hi = N_NODES;
    while (lo < hi) {
        int mid = (lo + hi) >> 1;
        if (batch[mid] < b) lo = mid + 1; else hi = mid;
    }
    gbeg[b] = lo;
}

__global__ __launch_bounds__(256) void seg_max(const float* __restrict__ gate, const int* __restrict__ gbeg,
                                               float* __restrict__ gmax) {
    int b = blockIdx.x;
    int s = gbeg[b], e = gbeg[b + 1];
    float m = -INFINITY;
    for (int i = s + threadIdx.x; i < e; i += 256) m = fmaxf(m, gate[i]);
    for (int o = 32; o > 0; o >>= 1) m = fmaxf(m, __shfl_xor(m, o, 64));
    __shared__ float red[4];
    if ((threadIdx.x & 63) == 0) red[threadIdx.x >> 6] = m;
    __syncthreads();
    if (threadIdx.x == 0) gmax[b] = fmaxf(fmaxf(red[0], red[1]), fmaxf(red[2], red[3]));
}

__global__ __launch_bounds__(256) void seg_sum(const float* __restrict__ gate, const int* __restrict__ gbeg,
                                               const float* __restrict__ gmax, float* __restrict__ gsum) {
    int b = blockIdx.x;
    int s = gbeg[b], e = gbeg[b + 1];
    float m = gmax[b];
    float acc = 0.0f;
    for (int i = s + threadIdx.x; i < e; i += 256) acc += expf(gate[i] - m);
    for (int o = 32; o > 0; o >>= 1) acc += __shfl_xor(acc, o, 64);
    __shared__ float red[4];
    if ((threadIdx.x & 63) == 0) red[threadIdx.x >> 6] = acc;
    __syncthreads();
    if (threadIdx.x == 0) gsum[b] = red[0] + red[1] + red[2] + red[3];
}

__global__ __launch_bounds__(512) void seg_pool(const float* __restrict__ h, const float* __restrict__ gate,
                                                const int* __restrict__ gbeg, const float* __restrict__ gmax,
                                                const float* __restrict__ gsum, float* __restrict__ gout) {
    int b = blockIdx.x;
    int team = threadIdx.x >> 7;
    int f = threadIdx.x & 127;
    int s = gbeg[b], e = gbeg[b + 1];
    float m = gmax[b];
    float inv = (e > s) ? 1.0f / gsum[b] : 0.0f;
    float acc = 0.0f;
    for (int i = s + team; i < e; i += 4) {
        float a = expf(gate[i] - m) * inv;
        acc = fmaf(a, h[(size_t)i * 128 + f], acc);
    }
    __shared__ float red[4][128];
    red[team][f] = acc;
    __syncthreads();
    if (team == 0) gout[b * 128 + f] = red[0][f] + red[1][f] + red[2][f] + red[3][f];
}

// ---------------- host launch ----------------

extern "C" void kernel_launch(void* const* d_in, const int* in_sizes, int n_in,
                              void* d_out, int out_size, void* d_ws, size_t ws_size,
                              hipStream_t stream) {
    const float* x     = (const float*)d_in[0];
    const int*   ei    = (const int*)d_in[1];
    const int*   batch = (const int*)d_in[2];
    const float* ea    = (const float*)d_in[3];
    const float* We1 = (const float*)d_in[4];
    const float* be1 = (const float*)d_in[5];
    const float* W1a = (const float*)d_in[6];
    const float* b1a = (const float*)d_in[7];
    const float* W1b = (const float*)d_in[8];
    const float* b1b = (const float*)d_in[9];
    const float* g1  = (const float*)d_in[10];
    const float* bn1 = (const float*)d_in[11];
    const float* We2 = (const float*)d_in[12];
    const float* be2 = (const float*)d_in[13];
    const float* W2a = (const float*)d_in[14];
    const float* b2a = (const float*)d_in[15];
    const float* W2b = (const float*)d_in[16];
    const float* b2b = (const float*)d_in[17];
    const float* g2  = (const float*)d_in[18];
    const float* bn2 = (const float*)d_in[19];
    const float* Wg1 = (const float*)d_in[20];
    const float* bg1 = (const float*)d_in[21];
    const float* Wg2 = (const float*)d_in[22];
    const float* bg2 = (const float*)d_in[23];

    float* outH = (float*)d_out;                 // [N,128] final h
    float* outG = outH + (size_t)N_NODES * 128;  // [B,128] pooled

    char* w = (char*)d_ws;
    auto carve = [&](size_t bytes) {
        void* p = (void*)w;
        w += ((bytes + 255) / 256) * 256;
        return p;
    };
    float*  bufB   = (float*)carve((size_t)N_NODES * 128 * 4);
    float*  bufC   = (float*)carve((size_t)N_NODES * 128 * 4);
    int2*   esw    = (int2*)carve((size_t)N_EDGES * 8);
    float2* eea    = (float2*)carve((size_t)N_EDGES * 8);
    int*    counts = (int*)carve((size_t)N_NODES * 4);
    int*    rp     = (int*)carve((size_t)(N_NODES + 1) * 4);
    int*    cursor = (int*)carve((size_t)N_NODES * 4);
    float*  dis    = (float*)carve((size_t)N_NODES * 4);
    float*  selfw  = (float*)carve((size_t)N_NODES * 4);
    float*  gate   = (float*)carve((size_t)N_NODES * 4);
    int*    bsum   = (int*)carve(128 * 4);
    float*  gmax   = (float*)carve(N_B * 4);
    float*  gsum   = (float*)carve(N_B * 4);
    int*    gbeg   = (int*)carve((N_B + 1) * 4);

    const int* src = ei;
    const int* dst = ei + N_EDGES;

    const int NB_SCAN = (N_NODES + 1023) / 1024;  // 98
    const int EB = (N_EDGES + 255) / 256;
    const int NBLK = (N_NODES + 255) / 256;
    const int WBLK = (N_NODES + 3) / 4;  // one wave per node, 4 waves/block

    // CSR build
    hipMemsetAsync(counts, 0, (size_t)N_NODES * 4, stream);
    hist_kernel<<<EB, 256, 0, stream>>>(dst, counts);
    deg_kernel<<<NBLK, 256, 0, stream>>>(counts, dis, selfw);
    scan1<<<NB_SCAN, 1024, 0, stream>>>(counts, rp, bsum);
    scan2<<<1, 64, 0, stream>>>(bsum, NB_SCAN);
    scan3<<<NB_SCAN, 1024, 0, stream>>>(rp, bsum, cursor);
    scatter_kernel<<<EB, 256, 0, stream>>>(src, dst, ea, dis, cursor, esw, eea);

    // conv1: gather (x -> bufB[:,0:64]) -> mlp1 (t -> outH) -> mlp2+gelu+LN (h1 -> bufB)
    conv1_gather<<<WBLK, 256, 0, stream>>>(x, rp, esw, eea, We1, be1, bufB);
    mlp_layer1<64><<<512, 512, 0, stream>>>(bufB, W1a, b1a, outH);
    mlp_layer2<true><<<512, 512, 0, stream>>>(outH, W1b, b1b, g1, bn1, bufB);

    // conv2: gather (bufB -> bufC) -> mlp1 (t -> outH) -> mlp2+LN (anchor -> bufB)
    conv2_gather<<<WBLK, 256, 0, stream>>>(bufB, rp, esw, eea, We2, be2, bufC);
    mlp_layer1<128><<<512, 512, 0, stream>>>(bufC, W2a, b2a, outH);
    mlp_layer2<false><<<512, 512, 0, stream>>>(outH, W2b, b2b, g2, bn2, bufB);

    // APPNP: anchor = bufB (f32). bf16 ping-pong buffers live inside bufC
    // (2 x 25.6 MB <= 51.2 MB). Steps 1..15 write bf16; step 16 writes f32 outH.
    unsigned* bfA = (unsigned*)bufC;
    unsigned* bfB2 = bfA + (size_t)N_NODES * 64;
    const float2* anchor2 = (const float2*)bufB;
    f32_to_bf2<<<(N_NODES * 64 + 255) / 256, 256, 0, stream>>>(anchor2, bfA);
    const unsigned* cur = bfA;
    for (int k = 1; k <= K_ITER - 1; k++) {
        unsigned* dstbuf = (k & 1) ? bfB2 : bfA;
        appnp_step_bf<false><<<WBLK, 256, 0, stream>>>(cur, anchor2, dstbuf, nullptr, rp, esw, selfw);
        cur = dstbuf;
    }
    appnp_step_bf<true><<<WBLK, 256, 0, stream>>>(cur, anchor2, nullptr, (float2*)outH, rp, esw, selfw);

    // pooling on outH
    gate_kernel<<<1024, 256, 0, stream>>>(outH, Wg1, bg1, Wg2, bg2, gate);
    seg_begin<<<1, 128, 0, stream>>>(batch, gbeg);
    seg_max<<<N_B, 256, 0, stream>>>(gate, gbeg, gmax);
    seg_sum<<<N_B, 256, 0, stream>>>(gate, gbeg, gmax, gsum);
    seg_pool<<<N_B, 512, 0, stream>>>(outH, gate, gbeg, gmax, gsum, outG);
}

// Round 5
// 2288.546 us; speedup vs baseline: 2.0359x; 1.1883x over previous
//
#include <hip/hip_runtime.h>
#include <math.h>

#define N_NODES 100000
#define N_EDGES 1600000
#define N_B 64
#define D_IN 64
#define D_HID 128
#define D_OUT 128
#define K_ITER 16
#define LN_EPS 1e-5f

typedef short s8v __attribute__((ext_vector_type(8)));
typedef float f4v __attribute__((ext_vector_type(4)));

__device__ __forceinline__ float gelu_f(float x) {
    return 0.5f * x * (1.0f + erff(0.70710678118654752440f * x));
}

__device__ __forceinline__ unsigned pack_bf2(float a, float b) {
    unsigned ua = __float_as_uint(a), ub = __float_as_uint(b);
    ua += 0x7fffu + ((ua >> 16) & 1u);
    ub += 0x7fffu + ((ub >> 16) & 1u);
    return (ua >> 16) | (ub & 0xffff0000u);
}
__device__ __forceinline__ float ubx(unsigned u) { return __uint_as_float(u << 16); }
__device__ __forceinline__ float uby(unsigned u) { return __uint_as_float(u & 0xffff0000u); }

__device__ __forceinline__ unsigned short bf_rne(float x) {
    unsigned u = __float_as_uint(x);
    u += 0x7fffu + ((u >> 16) & 1u);
    return (unsigned short)(u >> 16);
}
__device__ __forceinline__ float bf_f(unsigned short s) {
    return __uint_as_float(((unsigned)s) << 16);
}

// ---------------- CSR build ----------------

__global__ __launch_bounds__(256) void hist_kernel(const int* __restrict__ dst, int* __restrict__ counts) {
    int e = blockIdx.x * 256 + threadIdx.x;
    if (e < N_EDGES) atomicAdd(&counts[dst[e]], 1);
}

__global__ __launch_bounds__(256) void deg_kernel(const int* __restrict__ counts,
                                                  float* __restrict__ dis, float* __restrict__ selfw) {
    int i = blockIdx.x * 256 + threadIdx.x;
    if (i < N_NODES) {
        float d = (float)(counts[i] + 1);
        dis[i] = 1.0f / sqrtf(d);
        selfw[i] = 1.0f / d;
    }
}

__global__ __launch_bounds__(1024) void scan1(const int* __restrict__ counts, int* __restrict__ rp,
                                              int* __restrict__ bsum) {
    __shared__ int tmp[1024];
    int t = threadIdx.x;
    int idx = blockIdx.x * 1024 + t;
    int v = (idx < N_NODES) ? counts[idx] : 0;
    tmp[t] = v;
    __syncthreads();
    for (int o = 1; o < 1024; o <<= 1) {
        int add = (t >= o) ? tmp[t - o] : 0;
        __syncthreads();
        tmp[t] += add;
        __syncthreads();
    }
    if (idx < N_NODES) rp[idx] = tmp[t] - v;   // exclusive
    if (t == 1023) bsum[blockIdx.x] = tmp[t];
}

__global__ void scan2(int* bsum, int nb) {
    if (threadIdx.x == 0 && blockIdx.x == 0) {
        int acc = 0;
        for (int i = 0; i < nb; i++) { int v = bsum[i]; bsum[i] = acc; acc += v; }
    }
}

__global__ __launch_bounds__(1024) void scan3(int* __restrict__ rp, const int* __restrict__ bsum,
                                              int* __restrict__ cursor) {
    int t = threadIdx.x;
    int idx = blockIdx.x * 1024 + t;
    if (idx < N_NODES) {
        int v = rp[idx] + bsum[blockIdx.x];
        rp[idx] = v;
        cursor[idx] = v;
    }
    if (idx == 0) rp[N_NODES] = N_EDGES;
}

__global__ __launch_bounds__(256) void scatter_kernel(const int* __restrict__ src, const int* __restrict__ dst,
                                                      const float* __restrict__ ea, const float* __restrict__ dis,
                                                      int* __restrict__ cursor, int2* __restrict__ esw,
                                                      float2* __restrict__ eea) {
    int e = blockIdx.x * 256 + threadIdx.x;
    if (e >= N_EDGES) return;
    int s = src[e], d = dst[e];
    int pos = atomicAdd(&cursor[d], 1);
    int2 sw;
    sw.x = s;
    sw.y = __float_as_int(dis[s] * dis[d]);
    esw[pos] = sw;
    float2 e2;
    e2.x = ea[e * 2];
    e2.y = ea[e * 2 + 1];
    eea[pos] = e2;
}

// ---------------- GINE gathers (one wave per node, 4x unrolled) ----------------

__global__ __launch_bounds__(256) void conv1_gather(const float* __restrict__ x, const int* __restrict__ rp,
                                                    const int2* __restrict__ esw, const float2* __restrict__ eea,
                                                    const float* __restrict__ We1, const float* __restrict__ be1,
                                                    float* __restrict__ out) {
    int gw = (blockIdx.x * 256 + threadIdx.x) >> 6;
    if (gw >= N_NODES) return;
    int lane = threadIdx.x & 63;
    float w0 = We1[lane], w1 = We1[64 + lane], bb = be1[lane];
    float acc = x[(size_t)gw * 64 + lane];
    int j = rp[gw], s1 = rp[gw + 1];
    for (; j + 4 <= s1; j += 4) {
        int2 e0 = esw[j], e1 = esw[j + 1], e2 = esw[j + 2], e3 = esw[j + 3];
        float2 a0 = eea[j], a1 = eea[j + 1], a2 = eea[j + 2], a3 = eea[j + 3];
        float v0 = x[(size_t)e0.x * 64 + lane];
        float v1 = x[(size_t)e1.x * 64 + lane];
        float v2 = x[(size_t)e2.x * 64 + lane];
        float v3 = x[(size_t)e3.x * 64 + lane];
        acc += fmaxf(v0 + a0.x * w0 + a0.y * w1 + bb, 0.0f);
        acc += fmaxf(v1 + a1.x * w0 + a1.y * w1 + bb, 0.0f);
        acc += fmaxf(v2 + a2.x * w0 + a2.y * w1 + bb, 0.0f);
        acc += fmaxf(v3 + a3.x * w0 + a3.y * w1 + bb, 0.0f);
    }
    for (; j < s1; j++) {
        int2 e = esw[j];
        float2 a = eea[j];
        float v = x[(size_t)e.x * 64 + lane];
        acc += fmaxf(v + a.x * w0 + a.y * w1 + bb, 0.0f);
    }
    out[(size_t)gw * 64 + lane] = acc;
}

__global__ __launch_bounds__(256) void conv2_gather(const float* __restrict__ h1, const int* __restrict__ rp,
                                                    const int2* __restrict__ esw, const float2* __restrict__ eea,
                                                    const float* __restrict__ We2, const float* __restrict__ be2,
                                                    float* __restrict__ out) {
    int gw = (blockIdx.x * 256 + threadIdx.x) >> 6;
    if (gw >= N_NODES) return;
    int lane = threadIdx.x & 63;
    int f0 = lane * 2;
    float w00 = We2[f0], w01 = We2[f0 + 1];
    float w10 = We2[128 + f0], w11 = We2[128 + f0 + 1];
    float b0 = be2[f0], b1 = be2[f0 + 1];
    const float2* h2 = (const float2*)h1;
    float2 hc = h2[(size_t)gw * 64 + lane];
    float a0 = hc.x, a1 = hc.y;
    int j = rp[gw], s1 = rp[gw + 1];
    for (; j + 4 <= s1; j += 4) {
        int2 e0 = esw[j], e1 = esw[j + 1], e2 = esw[j + 2], e3 = esw[j + 3];
        float2 q0 = eea[j], q1 = eea[j + 1], q2 = eea[j + 2], q3 = eea[j + 3];
        float2 v0 = h2[(size_t)e0.x * 64 + lane];
        float2 v1 = h2[(size_t)e1.x * 64 + lane];
        float2 v2 = h2[(size_t)e2.x * 64 + lane];
        float2 v3 = h2[(size_t)e3.x * 64 + lane];
        a0 += fmaxf(v0.x + q0.x * w00 + q0.y * w10 + b0, 0.0f);
        a1 += fmaxf(v0.y + q0.x * w01 + q0.y * w11 + b1, 0.0f);
        a0 += fmaxf(v1.x + q1.x * w00 + q1.y * w10 + b0, 0.0f);
        a1 += fmaxf(v1.y + q1.x * w01 + q1.y * w11 + b1, 0.0f);
        a0 += fmaxf(v2.x + q2.x * w00 + q2.y * w10 + b0, 0.0f);
        a1 += fmaxf(v2.y + q2.x * w01 + q2.y * w11 + b1, 0.0f);
        a0 += fmaxf(v3.x + q3.x * w00 + q3.y * w10 + b0, 0.0f);
        a1 += fmaxf(v3.y + q3.x * w01 + q3.y * w11 + b1, 0.0f);
    }
    for (; j < s1; j++) {
        int2 e = esw[j];
        float2 q = eea[j];
        float2 v = h2[(size_t)e.x * 64 + lane];
        a0 += fmaxf(v.x + q.x * w00 + q.y * w10 + b0, 0.0f);
        a1 += fmaxf(v.y + q.x * w01 + q.y * w11 + b1, 0.0f);
    }
    out[(size_t)gw * 128 + f0] = a0;
    out[(size_t)gw * 128 + f0 + 1] = a1;
}

// ---------------- MLP layers via MFMA (split-bf16: Ahi*Whi + Ahi*Wlo + Alo*Whi) ----------------
// C[N x 128] = A[N x Kd] * W[Kd x 128]; block = 64 rows, 4 waves x 16 rows, 8 col-tiles.
// mfma_f32_16x16x32_bf16: A-frag A[m=lane&15][k=quad*8+j]; B-frag B[k=quad*8+j][n=lane&15];
// D: row = quad*4+reg, col = lane&15  (learn_hip m89/m120 verified layouts).

template <int Kd, bool GELU, bool LN>
__global__ __launch_bounds__(256) void mlp_mfma(const float* __restrict__ A, const float* __restrict__ W,
                                                const float* __restrict__ bias, const float* __restrict__ g,
                                                const float* __restrict__ bn, float* __restrict__ out) {
    __shared__ unsigned short sHi[8192];   // 64 k-rows x 128 cols, swizzled
    __shared__ unsigned short sLo[8192];
    int wave = threadIdx.x >> 6, lane = threadIdx.x & 63;
    int quad = lane >> 4, n = lane & 15;
    int rowA = blockIdx.x * 64 + wave * 16 + n;
    int rowAc = (rowA < N_NODES) ? rowA : 0;

    f4v acc[8];
    #pragma unroll
    for (int t = 0; t < 8; t++) acc[t] = (f4v){0.f, 0.f, 0.f, 0.f};

    for (int ph = 0; ph < Kd / 64; ph++) {
        __syncthreads();
        for (int idx = threadIdx.x; idx < 8192; idx += 256) {
            int k = idx >> 7, c = idx & 127;
            float v = W[(size_t)(ph * 64 + k) * 128 + c];
            unsigned short hi = bf_rne(v);
            unsigned short lo = bf_rne(v - bf_f(hi));
            int kk = k >> 5, q = (k >> 3) & 3, j = k & 7, t = c >> 4, nn = c & 15;
            int lidx = ((((kk * 4 + q) * 8 + t) * 16 + nn) << 3) + j;
            sHi[lidx] = hi;
            sLo[lidx] = lo;
        }
        __syncthreads();
        #pragma unroll
        for (int kk = 0; kk < 2; kk++) {
            int k0 = ph * 64 + kk * 32 + quad * 8;
            const float4* ap = (const float4*)(A + (size_t)rowAc * Kd + k0);
            float4 a0 = ap[0], a1 = ap[1];
            float av[8] = {a0.x, a0.y, a0.z, a0.w, a1.x, a1.y, a1.z, a1.w};
            s8v ahi, alo;
            #pragma unroll
            for (int j = 0; j < 8; j++) {
                unsigned short h = bf_rne(av[j]);
                ahi[j] = (short)h;
                alo[j] = (short)bf_rne(av[j] - bf_f(h));
            }
            int base = ((kk * 4 + quad) * 8) * 128;  // *16*8
            #pragma unroll
            for (int t = 0; t < 8; t++) {
                s8v bhi = *(const s8v*)&sHi[base + ((t * 16 + n) << 3)];
                s8v blo = *(const s8v*)&sLo[base + ((t * 16 + n) << 3)];
                acc[t] = __builtin_amdgcn_mfma_f32_16x16x32_bf16(ahi, bhi, acc[t], 0, 0, 0);
                acc[t] = __builtin_amdgcn_mfma_f32_16x16x32_bf16(ahi, blo, acc[t], 0, 0, 0);
                acc[t] = __builtin_amdgcn_mfma_f32_16x16x32_bf16(alo, bhi, acc[t], 0, 0, 0);
            }
        }
    }

    // epilogue
    float bcol[8], gcol[8], bncol[8];
    #pragma unroll
    for (int t = 0; t < 8; t++) {
        bcol[t] = bias[t * 16 + n];
        if (LN) { gcol[t] = g[t * 16 + n]; bncol[t] = bn[t * 16 + n]; }
    }
    #pragma unroll
    for (int r = 0; r < 4; r++) {
        int row = blockIdx.x * 64 + wave * 16 + quad * 4 + r;
        float v[8];
        #pragma unroll
        for (int t = 0; t < 8; t++) {
            float x = acc[t][r] + bcol[t];
            v[t] = GELU ? gelu_f(x) : x;
        }
        if (LN) {
            float s = 0.f, q2 = 0.f;
            #pragma unroll
            for (int t = 0; t < 8; t++) { s += v[t]; q2 += v[t] * v[t]; }
            #pragma unroll
            for (int m = 1; m <= 8; m <<= 1) {
                s += __shfl_xor(s, m, 64);
                q2 += __shfl_xor(q2, m, 64);
            }
            float mu = s * (1.0f / 128.0f);
            float rs = rsqrtf(q2 * (1.0f / 128.0f) - mu * mu + LN_EPS);
            #pragma unroll
            for (int t = 0; t < 8; t++) v[t] = (v[t] - mu) * rs * gcol[t] + bncol[t];
        }
        if (row < N_NODES) {
            #pragma unroll
            for (int t = 0; t < 8; t++) out[(size_t)row * 128 + t * 16 + n] = v[t];
        }
    }
}

// ---------------- APPNP (bf16 propagated state, f32 accumulation) ----------------

__global__ __launch_bounds__(256) void f32_to_bf2(const float2* __restrict__ in, unsigned* __restrict__ out) {
    int i = blockIdx.x * 256 + threadIdx.x;
    if (i < N_NODES * 64) { float2 v = in[i]; out[i] = pack_bf2(v.x, v.y); }
}

template <bool LAST>
__global__ __launch_bounds__(256) void appnp_step_bf(const unsigned* __restrict__ hin,
                                                     const float2* __restrict__ anchor,
                                                     unsigned* __restrict__ hout, float2* __restrict__ houtf,
                                                     const int* __restrict__ rp, const int2* __restrict__ esw,
                                                     const float* __restrict__ selfw) {
    int gw = (blockIdx.x * 256 + threadIdx.x) >> 6;
    if (gw >= N_NODES) return;
    int lane = threadIdx.x & 63;
    size_t idx = (size_t)gw * 64 + lane;
    float swi = selfw[gw];
    unsigned hcp = hin[idx];
    float ax = swi * ubx(hcp), ay = swi * uby(hcp);
    int j = rp[gw], s1 = rp[gw + 1];
    for (; j + 4 <= s1; j += 4) {
        int2 e0 = esw[j], e1 = esw[j + 1], e2 = esw[j + 2], e3 = esw[j + 3];
        unsigned v0 = hin[(size_t)e0.x * 64 + lane];
        unsigned v1 = hin[(size_t)e1.x * 64 + lane];
        unsigned v2 = hin[(size_t)e2.x * 64 + lane];
        unsigned v3 = hin[(size_t)e3.x * 64 + lane];
        float w0 = __int_as_float(e0.y), w1 = __int_as_float(e1.y);
        float w2 = __int_as_float(e2.y), w3 = __int_as_float(e3.y);
        ax = fmaf(w0, ubx(v0), ax); ay = fmaf(w0, uby(v0), ay);
        ax = fmaf(w1, ubx(v1), ax); ay = fmaf(w1, uby(v1), ay);
        ax = fmaf(w2, ubx(v2), ax); ay = fmaf(w2, uby(v2), ay);
        ax = fmaf(w3, ubx(v3), ax); ay = fmaf(w3, uby(v3), ay);
    }
    for (; j < s1; j++) {
        int2 e = esw[j];
        unsigned v = hin[(size_t)e.x * 64 + lane];
        float w = __int_as_float(e.y);
        ax = fmaf(w, ubx(v), ax); ay = fmaf(w, uby(v), ay);
    }
    float2 anc = anchor[idx];
    float ox = 0.9f * ax + 0.1f * anc.x;
    float oy = 0.9f * ay + 0.1f * anc.y;
    if (LAST) {
        float2 o; o.x = ox; o.y = oy;
        houtf[idx] = o;
    } else {
        hout[idx] = pack_bf2(ox, oy);
    }
}

// ---------------- Attentional pooling ----------------

__global__ __launch_bounds__(256) void gate_kernel(const float* __restrict__ h, const float* __restrict__ Wg1,
                                                   const float* __restrict__ bg1, const float* __restrict__ Wg2,
                                                   const float* __restrict__ bg2, float* __restrict__ gate) {
    __shared__ float sW[128 * 68];  // slot (jj*4+sub), 17 float4 per slot
    __shared__ float sB[64], sV[64];
    for (int idx = threadIdx.x; idx < 128 * 64; idx += 256) {
        int j = idx >> 6, c = idx & 63;
        int slot = (j & 31) * 4 + (j >> 5);
        sW[slot * 68 + c] = Wg1[idx];
    }
    if (threadIdx.x < 64) { sB[threadIdx.x] = bg1[threadIdx.x]; sV[threadIdx.x] = Wg2[threadIdx.x]; }
    float b2 = bg2[0];
    __syncthreads();
    int wave = threadIdx.x >> 6;
    int lane = threadIdx.x & 63;
    int nIw = lane >> 2, sub = lane & 3;
    const float4* sW4 = (const float4*)sW;
    const int nTiles = N_NODES / 16;  // 6250, exact
    for (int tile = blockIdx.x * 4 + wave; tile < nTiles; tile += gridDim.x * 4) {
        int n = tile * 16 + nIw;
        const float4* hp = (const float4*)(h + (size_t)n * 128 + sub * 32);
        float4 hq[8];
        #pragma unroll
        for (int i = 0; i < 8; i++) hq[i] = hp[i];
        float4 acc[16];
        #pragma unroll
        for (int i = 0; i < 16; i++) { acc[i].x = 0.f; acc[i].y = 0.f; acc[i].z = 0.f; acc[i].w = 0.f; }
        #pragma unroll
        for (int i = 0; i < 8; i++) {
            float hv0 = hq[i].x, hv1 = hq[i].y, hv2 = hq[i].z, hv3 = hq[i].w;
            const float4* w0 = sW4 + (size_t)((i * 4 + 0) * 4 + sub) * 17;
            const float4* w1 = sW4 + (size_t)((i * 4 + 1) * 4 + sub) * 17;
            const float4* w2 = sW4 + (size_t)((i * 4 + 2) * 4 + sub) * 17;
            const float4* w3 = sW4 + (size_t)((i * 4 + 3) * 4 + sub) * 17;
            #pragma unroll
            for (int cq = 0; cq < 16; cq++) {
                float4 a = w0[cq], b = w1[cq], c = w2[cq], d = w3[cq];
                acc[cq].x = fmaf(hv0, a.x, acc[cq].x); acc[cq].y = fmaf(hv0, a.y, acc[cq].y);
                acc[cq].z = fmaf(hv0, a.z, acc[cq].z); acc[cq].w = fmaf(hv0, a.w, acc[cq].w);
                acc[cq].x = fmaf(hv1, b.x, acc[cq].x); acc[cq].y = fmaf(hv1, b.y, acc[cq].y);
                acc[cq].z = fmaf(hv1, b.z, acc[cq].z); acc[cq].w = fmaf(hv1, b.w, acc[cq].w);
                acc[cq].x = fmaf(hv2, c.x, acc[cq].x); acc[cq].y = fmaf(hv2, c.y, acc[cq].y);
                acc[cq].z = fmaf(hv2, c.z, acc[cq].z); acc[cq].w = fmaf(hv2, c.w, acc[cq].w);
                acc[cq].x = fmaf(hv3, d.x, acc[cq].x); acc[cq].y = fmaf(hv3, d.y, acc[cq].y);
                acc[cq].z = fmaf(hv3, d.z, acc[cq].z); acc[cq].w = fmaf(hv3, d.w, acc[cq].w);
            }
        }
        #pragma unroll
        for (int cq = 0; cq < 16; cq++) {
            acc[cq].x += __shfl_xor(acc[cq].x, 1, 64);
            acc[cq].y += __shfl_xor(acc[cq].y, 1, 64);
            acc[cq].z += __shfl_xor(acc[cq].z, 1, 64);
            acc[cq].w += __shfl_xor(acc[cq].w, 1, 64);
            acc[cq].x += __shfl_xor(acc[cq].x, 2, 64);
            acc[cq].y += __shfl_xor(acc[cq].y, 2, 64);
            acc[cq].z += __shfl_xor(acc[cq].z, 2, 64);
            acc[cq].w += __shfl_xor(acc[cq].w, 2, 64);
        }
        float part = 0.0f;
        #pragma unroll
        for (int cq = 0; cq < 16; cq++) {
            part += gelu_f(acc[cq].x + sB[cq * 4 + 0]) * sV[cq * 4 + 0];
            part += gelu_f(acc[cq].y + sB[cq * 4 + 1]) * sV[cq * 4 + 1];
            part += gelu_f(acc[cq].z + sB[cq * 4 + 2]) * sV[cq * 4 + 2];
            part += gelu_f(acc[cq].w + sB[cq * 4 + 3]) * sV[cq * 4 + 3];
        }
        if (sub == 0) gate[n] = part + b2;
    }
}

__global__ void seg_begin(const int* __restrict__ batch, int* __restrict__ gbeg) {
    int b = threadIdx.x;
    if (b > N_B) return;
    if (b == N_B) { gbeg[N_B] = N_NODES; return; }
    int lo = 0, hi = N_NODES;
    while (lo < hi) {
        int mid = (lo + hi) >> 1;
        if (batch[mid] < b) lo = mid + 1; else hi = mid;
    }
    gbeg[b] = lo;
}

__global__ __launch_bounds__(256) void seg_max(const float* __restrict__ gate, const int* __restrict__ gbeg,
                                               float* __restrict__ gmax) {
    int b = blockIdx.x;
    int s = gbeg[b], e = gbeg[b + 1];
    float m = -INFINITY;
    for (int i = s + threadIdx.x; i < e; i += 256) m = fmaxf(m, gate[i]);
    for (int o = 32; o > 0; o >>= 1) m = fmaxf(m, __shfl_xor(m, o, 64));
    __shared__ float red[4];
    if ((threadIdx.x & 63) == 0) red[threadIdx.x >> 6] = m;
    __syncthreads();
    if (threadIdx.x == 0) gmax[b] = fmaxf(fmaxf(red[0], red[1]), fmaxf(red[2], red[3]));
}

__global__ __launch_bounds__(256) void seg_sum(const float* __restrict__ gate, const int* __restrict__ gbeg,
                                               const float* __restrict__ gmax, float* __restrict__ gsum) {
    int b = blockIdx.x;
    int s = gbeg[b], e = gbeg[b + 1];
    float m = gmax[b];
    float acc = 0.0f;
    for (int i = s + threadIdx.x; i < e; i += 256) acc += expf(gate[i] - m);
    for (int o = 32; o > 0; o >>= 1) acc += __shfl_xor(acc, o, 64);
    __shared__ float red[4];
    if ((threadIdx.x & 63) == 0) red[threadIdx.x >> 6] = acc;
    __syncthreads();
    if (threadIdx.x == 0) gsum[b] = red[0] + red[1] + red[2] + red[3];
}

__global__ __launch_bounds__(512) void seg_pool(const float* __restrict__ h, const float* __restrict__ gate,
                                                const int* __restrict__ gbeg, const float* __restrict__ gmax,
                                                const float* __restrict__ gsum, float* __restrict__ gout) {
    int b = blockIdx.x;
    int team = threadIdx.x >> 7;
    int f = threadIdx.x & 127;
    int s = gbeg[b], e = gbeg[b + 1];
    float m = gmax[b];
    float inv = (e > s) ? 1.0f / gsum[b] : 0.0f;
    float acc = 0.0f;
    for (int i = s + team; i < e; i += 4) {
        float a = expf(gate[i] - m) * inv;
        acc = fmaf(a, h[(size_t)i * 128 + f], acc);
    }
    __shared__ float red[4][128];
    red[team][f] = acc;
    __syncthreads();
    if (team == 0) gout[b * 128 + f] = red[0][f] + red[1][f] + red[2][f] + red[3][f];
}

// ---------------- host launch ----------------

extern "C" void kernel_launch(void* const* d_in, const int* in_sizes, int n_in,
                              void* d_out, int out_size, void* d_ws, size_t ws_size,
                              hipStream_t stream) {
    const float* x     = (const float*)d_in[0];
    const int*   ei    = (const int*)d_in[1];
    const int*   batch = (const int*)d_in[2];
    const float* ea    = (const float*)d_in[3];
    const float* We1 = (const float*)d_in[4];
    const float* be1 = (const float*)d_in[5];
    const float* W1a = (const float*)d_in[6];
    const float* b1a = (const float*)d_in[7];
    const float* W1b = (const float*)d_in[8];
    const float* b1b = (const float*)d_in[9];
    const float* g1  = (const float*)d_in[10];
    const float* bn1 = (const float*)d_in[11];
    const float* We2 = (const float*)d_in[12];
    const float* be2 = (const float*)d_in[13];
    const float* W2a = (const float*)d_in[14];
    const float* b2a = (const float*)d_in[15];
    const float* W2b = (const float*)d_in[16];
    const float* b2b = (const float*)d_in[17];
    const float* g2  = (const float*)d_in[18];
    const float* bn2 = (const float*)d_in[19];
    const float* Wg1 = (const float*)d_in[20];
    const float* bg1 = (const float*)d_in[21];
    const float* Wg2 = (const float*)d_in[22];
    const float* bg2 = (const float*)d_in[23];

    float* outH = (float*)d_out;                 // [N,128] final h
    float* outG = outH + (size_t)N_NODES * 128;  // [B,128] pooled

    char* w = (char*)d_ws;
    auto carve = [&](size_t bytes) {
        void* p = (void*)w;
        w += ((bytes + 255) / 256) * 256;
        return p;
    };
    float*  bufB   = (float*)carve((size_t)N_NODES * 128 * 4);
    float*  bufC   = (float*)carve((size_t)N_NODES * 128 * 4);
    int2*   esw    = (int2*)carve((size_t)N_EDGES * 8);
    float2* eea    = (float2*)carve((size_t)N_EDGES * 8);
    int*    counts = (int*)carve((size_t)N_NODES * 4);
    int*    rp     = (int*)carve((size_t)(N_NODES + 1) * 4);
    int*    cursor = (int*)carve((size_t)N_NODES * 4);
    float*  dis    = (float*)carve((size_t)N_NODES * 4);
    float*  selfw  = (float*)carve((size_t)N_NODES * 4);
    float*  gate   = (float*)carve((size_t)N_NODES * 4);
    int*    bsum   = (int*)carve(128 * 4);
    float*  gmax   = (float*)carve(N_B * 4);
    float*  gsum   = (float*)carve(N_B * 4);
    int*    gbeg   = (int*)carve((N_B + 1) * 4);

    const int* src = ei;
    const int* dst = ei + N_EDGES;

    const int NB_SCAN = (N_NODES + 1023) / 1024;  // 98
    const int EB = (N_EDGES + 255) / 256;
    const int NBLK = (N_NODES + 255) / 256;
    const int WBLK = (N_NODES + 3) / 4;    // one wave per node, 4 waves/block
    const int MBLK = (N_NODES + 63) / 64;  // 1563 blocks for mlp_mfma

    // CSR build
    hipMemsetAsync(counts, 0, (size_t)N_NODES * 4, stream);
    hist_kernel<<<EB, 256, 0, stream>>>(dst, counts);
    deg_kernel<<<NBLK, 256, 0, stream>>>(counts, dis, selfw);
    scan1<<<NB_SCAN, 1024, 0, stream>>>(counts, rp, bsum);
    scan2<<<1, 64, 0, stream>>>(bsum, NB_SCAN);
    scan3<<<NB_SCAN, 1024, 0, stream>>>(rp, bsum, cursor);
    scatter_kernel<<<EB, 256, 0, stream>>>(src, dst, ea, dis, cursor, esw, eea);

    // conv1: gather (x -> bufB[:,0:64]) -> mfma mlp1 (t -> outH) -> mfma mlp2+gelu+LN (-> bufB)
    conv1_gather<<<WBLK, 256, 0, stream>>>(x, rp, esw, eea, We1, be1, bufB);
    mlp_mfma<64, true, false><<<MBLK, 256, 0, stream>>>(bufB, W1a, b1a, nullptr, nullptr, outH);
    mlp_mfma<128, true, true><<<MBLK, 256, 0, stream>>>(outH, W1b, b1b, g1, bn1, bufB);

    // conv2: gather (bufB -> bufC) -> mfma mlp1 (t -> outH) -> mfma mlp2+LN (anchor -> bufB)
    conv2_gather<<<WBLK, 256, 0, stream>>>(bufB, rp, esw, eea, We2, be2, bufC);
    mlp_mfma<128, true, false><<<MBLK, 256, 0, stream>>>(bufC, W2a, b2a, nullptr, nullptr, outH);
    mlp_mfma<128, false, true><<<MBLK, 256, 0, stream>>>(outH, W2b, b2b, g2, bn2, bufB);

    // APPNP: anchor = bufB (f32). bf16 ping-pong buffers live inside bufC.
    unsigned* bfA = (unsigned*)bufC;
    unsigned* bfB2 = bfA + (size_t)N_NODES * 64;
    const float2* anchor2 = (const float2*)bufB;
    f32_to_bf2<<<(N_NODES * 64 + 255) / 256, 256, 0, stream>>>(anchor2, bfA);
    const unsigned* cur = bfA;
    for (int k = 1; k <= K_ITER - 1; k++) {
        unsigned* dstbuf = (k & 1) ? bfB2 : bfA;
        appnp_step_bf<false><<<WBLK, 256, 0, stream>>>(cur, anchor2, dstbuf, nullptr, rp, esw, selfw);
        cur = dstbuf;
    }
    appnp_step_bf<true><<<WBLK, 256, 0, stream>>>(cur, anchor2, nullptr, (float2*)outH, rp, esw, selfw);

    // pooling on outH
    gate_kernel<<<1024, 256, 0, stream>>>(outH, Wg1, bg1, Wg2, bg2, gate);
    seg_begin<<<1, 128, 0, stream>>>(batch, gbeg);
    seg_max<<<N_B, 256, 0, stream>>>(gate, gbeg, gmax);
    seg_sum<<<N_B, 256, 0, stream>>>(gate, gbeg, gmax, gsum);
    seg_pool<<<N_B, 512, 0, stream>>>(outH, gate, gbeg, gmax, gsum, outG);
}

// Round 6
// 1981.365 us; speedup vs baseline: 2.3516x; 1.1550x over previous
//
#include <hip/hip_runtime.h>
#include <math.h>

#define N_NODES 100000
#define N_EDGES 1600000
#define N_B 64
#define D_IN 64
#define D_HID 128
#define D_OUT 128
#define K_ITER 16
#define LN_EPS 1e-5f

typedef short s8v __attribute__((ext_vector_type(8)));
typedef float f4v __attribute__((ext_vector_type(4)));

__device__ __forceinline__ float gelu_f(float x) {
    return 0.5f * x * (1.0f + erff(0.70710678118654752440f * x));
}

__device__ __forceinline__ unsigned pack_bf2(float a, float b) {
    unsigned ua = __float_as_uint(a), ub = __float_as_uint(b);
    ua += 0x7fffu + ((ua >> 16) & 1u);
    ub += 0x7fffu + ((ub >> 16) & 1u);
    return (ua >> 16) | (ub & 0xffff0000u);
}
__device__ __forceinline__ float ubx(unsigned u) { return __uint_as_float(u << 16); }
__device__ __forceinline__ float uby(unsigned u) { return __uint_as_float(u & 0xffff0000u); }

__device__ __forceinline__ unsigned short bf_rne(float x) {
    unsigned u = __float_as_uint(x);
    u += 0x7fffu + ((u >> 16) & 1u);
    return (unsigned short)(u >> 16);
}
__device__ __forceinline__ float bf_f(unsigned short s) {
    return __uint_as_float(((unsigned)s) << 16);
}

// ---------------- CSR build ----------------

__global__ __launch_bounds__(256) void hist_kernel(const int* __restrict__ dst, int* __restrict__ counts) {
    int e = blockIdx.x * 256 + threadIdx.x;
    if (e < N_EDGES) atomicAdd(&counts[dst[e]], 1);
}

__global__ __launch_bounds__(256) void deg_kernel(const int* __restrict__ counts,
                                                  float* __restrict__ dis, float* __restrict__ selfw) {
    int i = blockIdx.x * 256 + threadIdx.x;
    if (i < N_NODES) {
        float d = (float)(counts[i] + 1);
        dis[i] = 1.0f / sqrtf(d);
        selfw[i] = 1.0f / d;
    }
}

__global__ __launch_bounds__(1024) void scan1(const int* __restrict__ counts, int* __restrict__ rp,
                                              int* __restrict__ bsum) {
    __shared__ int tmp[1024];
    int t = threadIdx.x;
    int idx = blockIdx.x * 1024 + t;
    int v = (idx < N_NODES) ? counts[idx] : 0;
    tmp[t] = v;
    __syncthreads();
    for (int o = 1; o < 1024; o <<= 1) {
        int add = (t >= o) ? tmp[t - o] : 0;
        __syncthreads();
        tmp[t] += add;
        __syncthreads();
    }
    if (idx < N_NODES) rp[idx] = tmp[t] - v;   // exclusive
    if (t == 1023) bsum[blockIdx.x] = tmp[t];
}

__global__ void scan2(int* bsum, int nb) {
    if (threadIdx.x == 0 && blockIdx.x == 0) {
        int acc = 0;
        for (int i = 0; i < nb; i++) { int v = bsum[i]; bsum[i] = acc; acc += v; }
    }
}

__global__ __launch_bounds__(1024) void scan3(int* __restrict__ rp, const int* __restrict__ bsum,
                                              int* __restrict__ cursor) {
    int t = threadIdx.x;
    int idx = blockIdx.x * 1024 + t;
    if (idx < N_NODES) {
        int v = rp[idx] + bsum[blockIdx.x];
        rp[idx] = v;
        cursor[idx] = v;
    }
    if (idx == 0) rp[N_NODES] = N_EDGES;
}

__global__ __launch_bounds__(256) void scatter_kernel(const int* __restrict__ src, const int* __restrict__ dst,
                                                      const float* __restrict__ ea, const float* __restrict__ dis,
                                                      int* __restrict__ cursor, int2* __restrict__ esw,
                                                      float2* __restrict__ eea) {
    int e = blockIdx.x * 256 + threadIdx.x;
    if (e >= N_EDGES) return;
    int s = src[e], d = dst[e];
    int pos = atomicAdd(&cursor[d], 1);
    int2 sw;
    sw.x = s;
    sw.y = __float_as_int(dis[s] * dis[d]);
    esw[pos] = sw;
    float2 e2;
    e2.x = ea[e * 2];
    e2.y = ea[e * 2 + 1];
    eea[pos] = e2;
}

// ---------------- GINE gathers ----------------

__global__ __launch_bounds__(256) void conv1_gather(const float* __restrict__ x, const int* __restrict__ rp,
                                                    const int2* __restrict__ esw, const float2* __restrict__ eea,
                                                    const float* __restrict__ We1, const float* __restrict__ be1,
                                                    float* __restrict__ out) {
    int gw = (blockIdx.x * 256 + threadIdx.x) >> 6;
    if (gw >= N_NODES) return;
    int lane = threadIdx.x & 63;
    float w0 = We1[lane], w1 = We1[64 + lane], bb = be1[lane];
    float acc = x[(size_t)gw * 64 + lane];
    int j = rp[gw], s1 = rp[gw + 1];
    for (; j + 4 <= s1; j += 4) {
        int2 e0 = esw[j], e1 = esw[j + 1], e2 = esw[j + 2], e3 = esw[j + 3];
        float2 a0 = eea[j], a1 = eea[j + 1], a2 = eea[j + 2], a3 = eea[j + 3];
        float v0 = x[(size_t)e0.x * 64 + lane];
        float v1 = x[(size_t)e1.x * 64 + lane];
        float v2 = x[(size_t)e2.x * 64 + lane];
        float v3 = x[(size_t)e3.x * 64 + lane];
        acc += fmaxf(v0 + a0.x * w0 + a0.y * w1 + bb, 0.0f);
        acc += fmaxf(v1 + a1.x * w0 + a1.y * w1 + bb, 0.0f);
        acc += fmaxf(v2 + a2.x * w0 + a2.y * w1 + bb, 0.0f);
        acc += fmaxf(v3 + a3.x * w0 + a3.y * w1 + bb, 0.0f);
    }
    for (; j < s1; j++) {
        int2 e = esw[j];
        float2 a = eea[j];
        float v = x[(size_t)e.x * 64 + lane];
        acc += fmaxf(v + a.x * w0 + a.y * w1 + bb, 0.0f);
    }
    out[(size_t)gw * 64 + lane] = acc;
}

__global__ __launch_bounds__(256) void conv2_gather(const float* __restrict__ h1, const int* __restrict__ rp,
                                                    const int2* __restrict__ esw, const float2* __restrict__ eea,
                                                    const float* __restrict__ We2, const float* __restrict__ be2,
                                                    float* __restrict__ out) {
    int gw = (blockIdx.x * 256 + threadIdx.x) >> 6;
    if (gw >= N_NODES) return;
    int lane = threadIdx.x & 63;
    int f0 = lane * 2;
    float w00 = We2[f0], w01 = We2[f0 + 1];
    float w10 = We2[128 + f0], w11 = We2[128 + f0 + 1];
    float b0 = be2[f0], b1 = be2[f0 + 1];
    const float2* h2 = (const float2*)h1;
    float2 hc = h2[(size_t)gw * 64 + lane];
    float a0 = hc.x, a1 = hc.y;
    int j = rp[gw], s1 = rp[gw + 1];
    for (; j + 8 <= s1; j += 8) {
        int2 e0 = esw[j], e1 = esw[j + 1], e2 = esw[j + 2], e3 = esw[j + 3];
        int2 e4 = esw[j + 4], e5 = esw[j + 5], e6 = esw[j + 6], e7 = esw[j + 7];
        float2 q0 = eea[j], q1 = eea[j + 1], q2 = eea[j + 2], q3 = eea[j + 3];
        float2 q4 = eea[j + 4], q5 = eea[j + 5], q6 = eea[j + 6], q7 = eea[j + 7];
        float2 v0 = h2[(size_t)e0.x * 64 + lane];
        float2 v1 = h2[(size_t)e1.x * 64 + lane];
        float2 v2 = h2[(size_t)e2.x * 64 + lane];
        float2 v3 = h2[(size_t)e3.x * 64 + lane];
        float2 v4 = h2[(size_t)e4.x * 64 + lane];
        float2 v5 = h2[(size_t)e5.x * 64 + lane];
        float2 v6 = h2[(size_t)e6.x * 64 + lane];
        float2 v7 = h2[(size_t)e7.x * 64 + lane];
        a0 += fmaxf(v0.x + q0.x * w00 + q0.y * w10 + b0, 0.0f);
        a1 += fmaxf(v0.y + q0.x * w01 + q0.y * w11 + b1, 0.0f);
        a0 += fmaxf(v1.x + q1.x * w00 + q1.y * w10 + b0, 0.0f);
        a1 += fmaxf(v1.y + q1.x * w01 + q1.y * w11 + b1, 0.0f);
        a0 += fmaxf(v2.x + q2.x * w00 + q2.y * w10 + b0, 0.0f);
        a1 += fmaxf(v2.y + q2.x * w01 + q2.y * w11 + b1, 0.0f);
        a0 += fmaxf(v3.x + q3.x * w00 + q3.y * w10 + b0, 0.0f);
        a1 += fmaxf(v3.y + q3.x * w01 + q3.y * w11 + b1, 0.0f);
        a0 += fmaxf(v4.x + q4.x * w00 + q4.y * w10 + b0, 0.0f);
        a1 += fmaxf(v4.y + q4.x * w01 + q4.y * w11 + b1, 0.0f);
        a0 += fmaxf(v5.x + q5.x * w00 + q5.y * w10 + b0, 0.0f);
        a1 += fmaxf(v5.y + q5.x * w01 + q5.y * w11 + b1, 0.0f);
        a0 += fmaxf(v6.x + q6.x * w00 + q6.y * w10 + b0, 0.0f);
        a1 += fmaxf(v6.y + q6.x * w01 + q6.y * w11 + b1, 0.0f);
        a0 += fmaxf(v7.x + q7.x * w00 + q7.y * w10 + b0, 0.0f);
        a1 += fmaxf(v7.y + q7.x * w01 + q7.y * w11 + b1, 0.0f);
    }
    for (; j < s1; j++) {
        int2 e = esw[j];
        float2 q = eea[j];
        float2 v = h2[(size_t)e.x * 64 + lane];
        a0 += fmaxf(v.x + q.x * w00 + q.y * w10 + b0, 0.0f);
        a1 += fmaxf(v.y + q.x * w01 + q.y * w11 + b1, 0.0f);
    }
    out[(size_t)gw * 128 + f0] = a0;
    out[(size_t)gw * 128 + f0 + 1] = a1;
}

// ---------------- MLP layers via MFMA (split-bf16: Ahi*Whi + Ahi*Wlo + Alo*Whi) ----------------

template <int Kd, bool GELU, bool LN>
__global__ __launch_bounds__(256) void mlp_mfma(const float* __restrict__ A, const float* __restrict__ W,
                                                const float* __restrict__ bias, const float* __restrict__ g,
                                                const float* __restrict__ bn, float* __restrict__ out) {
    __shared__ unsigned short sHi[8192];   // 64 k-rows x 128 cols, swizzled
    __shared__ unsigned short sLo[8192];
    int wave = threadIdx.x >> 6, lane = threadIdx.x & 63;
    int quad = lane >> 4, n = lane & 15;
    int rowA = blockIdx.x * 64 + wave * 16 + n;
    int rowAc = (rowA < N_NODES) ? rowA : 0;

    f4v acc[8];
    #pragma unroll
    for (int t = 0; t < 8; t++) acc[t] = (f4v){0.f, 0.f, 0.f, 0.f};

    for (int ph = 0; ph < Kd / 64; ph++) {
        __syncthreads();
        for (int idx = threadIdx.x; idx < 8192; idx += 256) {
            int k = idx >> 7, c = idx & 127;
            float v = W[(size_t)(ph * 64 + k) * 128 + c];
            unsigned short hi = bf_rne(v);
            unsigned short lo = bf_rne(v - bf_f(hi));
            int kk = k >> 5, q = (k >> 3) & 3, j = k & 7, t = c >> 4, nn = c & 15;
            int lidx = ((((kk * 4 + q) * 8 + t) * 16 + nn) << 3) + j;
            sHi[lidx] = hi;
            sLo[lidx] = lo;
        }
        __syncthreads();
        #pragma unroll
        for (int kk = 0; kk < 2; kk++) {
            int k0 = ph * 64 + kk * 32 + quad * 8;
            const float4* ap = (const float4*)(A + (size_t)rowAc * Kd + k0);
            float4 a0 = ap[0], a1 = ap[1];
            float av[8] = {a0.x, a0.y, a0.z, a0.w, a1.x, a1.y, a1.z, a1.w};
            s8v ahi, alo;
            #pragma unroll
            for (int j = 0; j < 8; j++) {
                unsigned short h = bf_rne(av[j]);
                ahi[j] = (short)h;
                alo[j] = (short)bf_rne(av[j] - bf_f(h));
            }
            int base = ((kk * 4 + quad) * 8) * 128;
            #pragma unroll
            for (int t = 0; t < 8; t++) {
                s8v bhi = *(const s8v*)&sHi[base + ((t * 16 + n) << 3)];
                s8v blo = *(const s8v*)&sLo[base + ((t * 16 + n) << 3)];
                acc[t] = __builtin_amdgcn_mfma_f32_16x16x32_bf16(ahi, bhi, acc[t], 0, 0, 0);
                acc[t] = __builtin_amdgcn_mfma_f32_16x16x32_bf16(ahi, blo, acc[t], 0, 0, 0);
                acc[t] = __builtin_amdgcn_mfma_f32_16x16x32_bf16(alo, bhi, acc[t], 0, 0, 0);
            }
        }
    }

    float bcol[8], gcol[8], bncol[8];
    #pragma unroll
    for (int t = 0; t < 8; t++) {
        bcol[t] = bias[t * 16 + n];
        if (LN) { gcol[t] = g[t * 16 + n]; bncol[t] = bn[t * 16 + n]; }
    }
    #pragma unroll
    for (int r = 0; r < 4; r++) {
        int row = blockIdx.x * 64 + wave * 16 + quad * 4 + r;
        float v[8];
        #pragma unroll
        for (int t = 0; t < 8; t++) {
            float x = acc[t][r] + bcol[t];
            v[t] = GELU ? gelu_f(x) : x;
        }
        if (LN) {
            float s = 0.f, q2 = 0.f;
            #pragma unroll
            for (int t = 0; t < 8; t++) { s += v[t]; q2 += v[t] * v[t]; }
            #pragma unroll
            for (int m = 1; m <= 8; m <<= 1) {
                s += __shfl_xor(s, m, 64);
                q2 += __shfl_xor(q2, m, 64);
            }
            float mu = s * (1.0f / 128.0f);
            float rs = rsqrtf(q2 * (1.0f / 128.0f) - mu * mu + LN_EPS);
            #pragma unroll
            for (int t = 0; t < 8; t++) v[t] = (v[t] - mu) * rs * gcol[t] + bncol[t];
        }
        if (row < N_NODES) {
            #pragma unroll
            for (int t = 0; t < 8; t++) out[(size_t)row * 128 + t * 16 + n] = v[t];
        }
    }
}

// ---------------- Gate via MFMA: gate = gelu(h@Wg1+bg1)@Wg2 + bg2 ----------------

__global__ __launch_bounds__(256) void gate_mfma(const float* __restrict__ h, const float* __restrict__ Wg1,
                                                 const float* __restrict__ bg1, const float* __restrict__ Wg2,
                                                 const float* __restrict__ bg2, float* __restrict__ gate) {
    __shared__ unsigned short sHi[8192];  // 128 k x 64 cols, swizzled
    __shared__ unsigned short sLo[8192];
    int wave = threadIdx.x >> 6, lane = threadIdx.x & 63;
    int quad = lane >> 4, n = lane & 15;
    for (int idx = threadIdx.x; idx < 8192; idx += 256) {
        int k = idx >> 6, c = idx & 63;
        float v = Wg1[k * 64 + c];
        unsigned short hi = bf_rne(v);
        unsigned short lo = bf_rne(v - bf_f(hi));
        int kk = k >> 5, q = (k >> 3) & 3, j = k & 7, t = c >> 4, nn = c & 15;
        int lidx = ((((kk * 4 + q) * 4 + t) * 16 + nn) << 3) + j;
        sHi[lidx] = hi;
        sLo[lidx] = lo;
    }
    __syncthreads();
    int rowA = blockIdx.x * 64 + wave * 16 + n;
    int rowAc = (rowA < N_NODES) ? rowA : 0;
    f4v acc[4];
    #pragma unroll
    for (int t = 0; t < 4; t++) acc[t] = (f4v){0.f, 0.f, 0.f, 0.f};
    #pragma unroll
    for (int kk = 0; kk < 4; kk++) {
        const float4* ap = (const float4*)(h + (size_t)rowAc * 128 + kk * 32 + quad * 8);
        float4 a0 = ap[0], a1 = ap[1];
        float av[8] = {a0.x, a0.y, a0.z, a0.w, a1.x, a1.y, a1.z, a1.w};
        s8v ahi, alo;
        #pragma unroll
        for (int j = 0; j < 8; j++) {
            unsigned short hh = bf_rne(av[j]);
            ahi[j] = (short)hh;
            alo[j] = (short)bf_rne(av[j] - bf_f(hh));
        }
        int base = ((kk * 4 + quad) * 4) * 128;
        #pragma unroll
        for (int t = 0; t < 4; t++) {
            s8v bhi = *(const s8v*)&sHi[base + ((t * 16 + n) << 3)];
            s8v blo = *(const s8v*)&sLo[base + ((t * 16 + n) << 3)];
            acc[t] = __builtin_amdgcn_mfma_f32_16x16x32_bf16(ahi, bhi, acc[t], 0, 0, 0);
            acc[t] = __builtin_amdgcn_mfma_f32_16x16x32_bf16(ahi, blo, acc[t], 0, 0, 0);
            acc[t] = __builtin_amdgcn_mfma_f32_16x16x32_bf16(alo, bhi, acc[t], 0, 0, 0);
        }
    }
    float b2 = bg2[0];
    float bb[4], vv[4];
    #pragma unroll
    for (int t = 0; t < 4; t++) { bb[t] = bg1[t * 16 + n]; vv[t] = Wg2[t * 16 + n]; }
    #pragma unroll
    for (int r = 0; r < 4; r++) {
        int row = blockIdx.x * 64 + wave * 16 + quad * 4 + r;
        float val = 0.f;
        #pragma unroll
        for (int t = 0; t < 4; t++) val += gelu_f(acc[t][r] + bb[t]) * vv[t];
        #pragma unroll
        for (int m = 1; m <= 8; m <<= 1) val += __shfl_xor(val, m, 64);
        if (n == 0 && row < N_NODES) gate[row] = val + b2;
    }
}

// ---------------- APPNP (bf16 propagated state, f32 accumulation, 8x unroll) ----------------

__global__ __launch_bounds__(256) void f32_to_bf2(const float2* __restrict__ in, unsigned* __restrict__ out) {
    int i = blockIdx.x * 256 + threadIdx.x;
    if (i < N_NODES * 64) { float2 v = in[i]; out[i] = pack_bf2(v.x, v.y); }
}

template <bool LAST>
__global__ __launch_bounds__(256) void appnp_step_bf(const unsigned* __restrict__ hin,
                                                     const float2* __restrict__ anchor,
                                                     unsigned* __restrict__ hout, float2* __restrict__ houtf,
                                                     const int* __restrict__ rp, const int2* __restrict__ esw,
                                                     const float* __restrict__ selfw) {
    int gw = (blockIdx.x * 256 + threadIdx.x) >> 6;
    if (gw >= N_NODES) return;
    int lane = threadIdx.x & 63;
    size_t idx = (size_t)gw * 64 + lane;
    float swi = selfw[gw];
    unsigned hcp = hin[idx];
    float ax = swi * ubx(hcp), ay = swi * uby(hcp);
    int j = rp[gw], s1 = rp[gw + 1];
    for (; j + 8 <= s1; j += 8) {
        int2 e0 = esw[j], e1 = esw[j + 1], e2 = esw[j + 2], e3 = esw[j + 3];
        int2 e4 = esw[j + 4], e5 = esw[j + 5], e6 = esw[j + 6], e7 = esw[j + 7];
        unsigned v0 = hin[(size_t)e0.x * 64 + lane];
        unsigned v1 = hin[(size_t)e1.x * 64 + lane];
        unsigned v2 = hin[(size_t)e2.x * 64 + lane];
        unsigned v3 = hin[(size_t)e3.x * 64 + lane];
        unsigned v4 = hin[(size_t)e4.x * 64 + lane];
        unsigned v5 = hin[(size_t)e5.x * 64 + lane];
        unsigned v6 = hin[(size_t)e6.x * 64 + lane];
        unsigned v7 = hin[(size_t)e7.x * 64 + lane];
        float w0 = __int_as_float(e0.y), w1 = __int_as_float(e1.y);
        float w2 = __int_as_float(e2.y), w3 = __int_as_float(e3.y);
        float w4 = __int_as_float(e4.y), w5 = __int_as_float(e5.y);
        float w6 = __int_as_float(e6.y), w7 = __int_as_float(e7.y);
        ax = fmaf(w0, ubx(v0), ax); ay = fmaf(w0, uby(v0), ay);
        ax = fmaf(w1, ubx(v1), ax); ay = fmaf(w1, uby(v1), ay);
        ax = fmaf(w2, ubx(v2), ax); ay = fmaf(w2, uby(v2), ay);
        ax = fmaf(w3, ubx(v3), ax); ay = fmaf(w3, uby(v3), ay);
        ax = fmaf(w4, ubx(v4), ax); ay = fmaf(w4, uby(v4), ay);
        ax = fmaf(w5, ubx(v5), ax); ay = fmaf(w5, uby(v5), ay);
        ax = fmaf(w6, ubx(v6), ax); ay = fmaf(w6, uby(v6), ay);
        ax = fmaf(w7, ubx(v7), ax); ay = fmaf(w7, uby(v7), ay);
    }
    for (; j + 4 <= s1; j += 4) {
        int2 e0 = esw[j], e1 = esw[j + 1], e2 = esw[j + 2], e3 = esw[j + 3];
        unsigned v0 = hin[(size_t)e0.x * 64 + lane];
        unsigned v1 = hin[(size_t)e1.x * 64 + lane];
        unsigned v2 = hin[(size_t)e2.x * 64 + lane];
        unsigned v3 = hin[(size_t)e3.x * 64 + lane];
        float w0 = __int_as_float(e0.y), w1 = __int_as_float(e1.y);
        float w2 = __int_as_float(e2.y), w3 = __int_as_float(e3.y);
        ax = fmaf(w0, ubx(v0), ax); ay = fmaf(w0, uby(v0), ay);
        ax = fmaf(w1, ubx(v1), ax); ay = fmaf(w1, uby(v1), ay);
        ax = fmaf(w2, ubx(v2), ax); ay = fmaf(w2, uby(v2), ay);
        ax = fmaf(w3, ubx(v3), ax); ay = fmaf(w3, uby(v3), ay);
    }
    for (; j < s1; j++) {
        int2 e = esw[j];
        unsigned v = hin[(size_t)e.x * 64 + lane];
        float w = __int_as_float(e.y);
        ax = fmaf(w, ubx(v), ax); ay = fmaf(w, uby(v), ay);
    }
    float2 anc = anchor[idx];
    float ox = 0.9f * ax + 0.1f * anc.x;
    float oy = 0.9f * ay + 0.1f * anc.y;
    if (LAST) {
        float2 o; o.x = ox; o.y = oy;
        houtf[idx] = o;
    } else {
        hout[idx] = pack_bf2(ox, oy);
    }
}

// ---------------- Attentional pooling ----------------

__global__ void seg_begin(const int* __restrict__ batch, int* __restrict__ gbeg) {
    int b = threadIdx.x;
    if (b > N_B) return;
    if (b == N_B) { gbeg[N_B] = N_NODES; return; }
    int lo = 0, hi = N_NODES;
    while (lo < hi) {
        int mid = (lo + hi) >> 1;
        if (batch[mid] < b) lo = mid + 1; else hi = mid;
    }
    gbeg[b] = lo;
}

__global__ __launch_bounds__(256) void seg_max(const float* __restrict__ gate, const int* __restrict__ gbeg,
                                               float* __restrict__ gmax) {
    int b = blockIdx.x;
    int s = gbeg[b], e = gbeg[b + 1];
    float m = -INFINITY;
    for (int i = s + threadIdx.x; i < e; i += 256) m = fmaxf(m, gate[i]);
    for (int o = 32; o > 0; o >>= 1) m = fmaxf(m, __shfl_xor(m, o, 64));
    __shared__ float red[4];
    if ((threadIdx.x & 63) == 0) red[threadIdx.x >> 6] = m;
    __syncthreads();
    if (threadIdx.x == 0) gmax[b] = fmaxf(fmaxf(red[0], red[1]), fmaxf(red[2], red[3]));
}

__global__ __launch_bounds__(256) void seg_sum(const float* __restrict__ gate, const int* __restrict__ gbeg,
                                               const float* __restrict__ gmax, float* __restrict__ gsum) {
    int b = blockIdx.x;
    int s = gbeg[b], e = gbeg[b + 1];
    float m = gmax[b];
    float acc = 0.0f;
    for (int i = s + threadIdx.x; i < e; i += 256) acc += expf(gate[i] - m);
    for (int o = 32; o > 0; o >>= 1) acc += __shfl_xor(acc, o, 64);
    __shared__ float red[4];
    if ((threadIdx.x & 63) == 0) red[threadIdx.x >> 6] = acc;
    __syncthreads();
    if (threadIdx.x == 0) gsum[b] = red[0] + red[1] + red[2] + red[3];
}

// 8 slices per graph; atomicAdd into zero-initialized gout.
__global__ __launch_bounds__(512) void seg_pool(const float* __restrict__ h, const float* __restrict__ gate,
                                                const int* __restrict__ gbeg, const float* __restrict__ gmax,
                                                const float* __restrict__ gsum, float* __restrict__ gout) {
    int b = blockIdx.x >> 3, slice = blockIdx.x & 7;
    int team = threadIdx.x >> 7;
    int f = threadIdx.x & 127;
    int s = gbeg[b], e = gbeg[b + 1];
    float m = gmax[b];
    float inv = (e > s) ? 1.0f / gsum[b] : 0.0f;
    float acc = 0.0f;
    for (int i = s + slice * 4 + team; i < e; i += 32) {
        float a = expf(gate[i] - m) * inv;
        acc = fmaf(a, h[(size_t)i * 128 + f], acc);
    }
    __shared__ float red[4][128];
    red[team][f] = acc;
    __syncthreads();
    if (team == 0) {
        float v = red[0][f] + red[1][f] + red[2][f] + red[3][f];
        atomicAdd(&gout[b * 128 + f], v);
    }
}

// ---------------- host launch ----------------

extern "C" void kernel_launch(void* const* d_in, const int* in_sizes, int n_in,
                              void* d_out, int out_size, void* d_ws, size_t ws_size,
                              hipStream_t stream) {
    const float* x     = (const float*)d_in[0];
    const int*   ei    = (const int*)d_in[1];
    const int*   batch = (const int*)d_in[2];
    const float* ea    = (const float*)d_in[3];
    const float* We1 = (const float*)d_in[4];
    const float* be1 = (const float*)d_in[5];
    const float* W1a = (const float*)d_in[6];
    const float* b1a = (const float*)d_in[7];
    const float* W1b = (const float*)d_in[8];
    const float* b1b = (const float*)d_in[9];
    const float* g1  = (const float*)d_in[10];
    const float* bn1 = (const float*)d_in[11];
    const float* We2 = (const float*)d_in[12];
    const float* be2 = (const float*)d_in[13];
    const float* W2a = (const float*)d_in[14];
    const float* b2a = (const float*)d_in[15];
    const float* W2b = (const float*)d_in[16];
    const float* b2b = (const float*)d_in[17];
    const float* g2  = (const float*)d_in[18];
    const float* bn2 = (const float*)d_in[19];
    const float* Wg1 = (const float*)d_in[20];
    const float* bg1 = (const float*)d_in[21];
    const float* Wg2 = (const float*)d_in[22];
    const float* bg2 = (const float*)d_in[23];

    float* outH = (float*)d_out;                 // [N,128] final h
    float* outG = outH + (size_t)N_NODES * 128;  // [B,128] pooled

    char* w = (char*)d_ws;
    auto carve = [&](size_t bytes) {
        void* p = (void*)w;
        w += ((bytes + 255) / 256) * 256;
        return p;
    };
    float*  bufB   = (float*)carve((size_t)N_NODES * 128 * 4);
    float*  bufC   = (float*)carve((size_t)N_NODES * 128 * 4);
    int2*   esw    = (int2*)carve((size_t)N_EDGES * 8);
    float2* eea    = (float2*)carve((size_t)N_EDGES * 8);
    int*    counts = (int*)carve((size_t)N_NODES * 4);
    int*    rp     = (int*)carve((size_t)(N_NODES + 1) * 4);
    int*    cursor = (int*)carve((size_t)N_NODES * 4);
    float*  dis    = (float*)carve((size_t)N_NODES * 4);
    float*  selfw  = (float*)carve((size_t)N_NODES * 4);
    float*  gate   = (float*)carve((size_t)N_NODES * 4);
    int*    bsum   = (int*)carve(128 * 4);
    float*  gmax   = (float*)carve(N_B * 4);
    float*  gsum   = (float*)carve(N_B * 4);
    int*    gbeg   = (int*)carve((N_B + 1) * 4);

    const int* src = ei;
    const int* dst = ei + N_EDGES;

    const int NB_SCAN = (N_NODES + 1023) / 1024;  // 98
    const int EB = (N_EDGES + 255) / 256;
    const int NBLK = (N_NODES + 255) / 256;
    const int WBLK = (N_NODES + 3) / 4;    // one wave per node, 4 waves/block
    const int MBLK = (N_NODES + 63) / 64;  // 1563 blocks for mfma kernels

    // CSR build
    hipMemsetAsync(counts, 0, (size_t)N_NODES * 4, stream);
    hist_kernel<<<EB, 256, 0, stream>>>(dst, counts);
    deg_kernel<<<NBLK, 256, 0, stream>>>(counts, dis, selfw);
    scan1<<<NB_SCAN, 1024, 0, stream>>>(counts, rp, bsum);
    scan2<<<1, 64, 0, stream>>>(bsum, NB_SCAN);
    scan3<<<NB_SCAN, 1024, 0, stream>>>(rp, bsum, cursor);
    scatter_kernel<<<EB, 256, 0, stream>>>(src, dst, ea, dis, cursor, esw, eea);

    // conv1
    conv1_gather<<<WBLK, 256, 0, stream>>>(x, rp, esw, eea, We1, be1, bufB);
    mlp_mfma<64, true, false><<<MBLK, 256, 0, stream>>>(bufB, W1a, b1a, nullptr, nullptr, outH);
    mlp_mfma<128, true, true><<<MBLK, 256, 0, stream>>>(outH, W1b, b1b, g1, bn1, bufB);

    // conv2
    conv2_gather<<<WBLK, 256, 0, stream>>>(bufB, rp, esw, eea, We2, be2, bufC);
    mlp_mfma<128, true, false><<<MBLK, 256, 0, stream>>>(bufC, W2a, b2a, nullptr, nullptr, outH);
    mlp_mfma<128, false, true><<<MBLK, 256, 0, stream>>>(outH, W2b, b2b, g2, bn2, bufB);

    // APPNP: anchor = bufB (f32). bf16 ping-pong inside bufC.
    unsigned* bfA = (unsigned*)bufC;
    unsigned* bfB2 = bfA + (size_t)N_NODES * 64;
    const float2* anchor2 = (const float2*)bufB;
    f32_to_bf2<<<(N_NODES * 64 + 255) / 256, 256, 0, stream>>>(anchor2, bfA);
    const unsigned* cur = bfA;
    for (int k = 1; k <= K_ITER - 1; k++) {
        unsigned* dstbuf = (k & 1) ? bfB2 : bfA;
        appnp_step_bf<false><<<WBLK, 256, 0, stream>>>(cur, anchor2, dstbuf, nullptr, rp, esw, selfw);
        cur = dstbuf;
    }
    appnp_step_bf<true><<<WBLK, 256, 0, stream>>>(cur, anchor2, nullptr, (float2*)outH, rp, esw, selfw);

    // pooling on outH
    gate_mfma<<<MBLK, 256, 0, stream>>>(outH, Wg1, bg1, Wg2, bg2, gate);
    seg_begin<<<1, 128, 0, stream>>>(batch, gbeg);
    seg_max<<<N_B, 256, 0, stream>>>(gate, gbeg, gmax);
    seg_sum<<<N_B, 256, 0, stream>>>(gate, gbeg, gmax, gsum);
    hipMemsetAsync(outG, 0, (size_t)N_B * 128 * 4, stream);
    seg_pool<<<N_B * 8, 512, 0, stream>>>(outH, gate, gbeg, gmax, gsum, outG);
}

// Round 7
// 1834.336 us; speedup vs baseline: 2.5401x; 1.0802x over previous
//
#include <hip/hip_runtime.h>
#include <math.h>

#define N_NODES 100000
#define N_EDGES 1600000
#define N_B 64
#define D_IN 64
#define D_HID 128
#define D_OUT 128
#define K_ITER 16
#define LN_EPS 1e-5f

typedef short s8v __attribute__((ext_vector_type(8)));
typedef float f4v __attribute__((ext_vector_type(4)));

__device__ __forceinline__ float gelu_f(float x) {
    return 0.5f * x * (1.0f + erff(0.70710678118654752440f * x));
}

__device__ __forceinline__ float ubx(unsigned u) { return __uint_as_float(u << 16); }
__device__ __forceinline__ float uby(unsigned u) { return __uint_as_float(u & 0xffff0000u); }

__device__ __forceinline__ unsigned short bf_rne(float x) {
    unsigned u = __float_as_uint(x);
    u += 0x7fffu + ((u >> 16) & 1u);
    return (unsigned short)(u >> 16);
}
__device__ __forceinline__ float bf_f(unsigned short s) {
    return __uint_as_float(((unsigned)s) << 16);
}
__device__ __forceinline__ unsigned pack_bf2(float a, float b) {
    return (unsigned)bf_rne(a) | (((unsigned)bf_rne(b)) << 16);
}

// ---------------- CSR build ----------------

__global__ __launch_bounds__(256) void hist_kernel(const int* __restrict__ dst, int* __restrict__ counts) {
    int e = blockIdx.x * 256 + threadIdx.x;
    if (e < N_EDGES) atomicAdd(&counts[dst[e]], 1);
}

__global__ __launch_bounds__(256) void deg_kernel(const int* __restrict__ counts,
                                                  float* __restrict__ dis, float* __restrict__ selfw) {
    int i = blockIdx.x * 256 + threadIdx.x;
    if (i < N_NODES) {
        float d = (float)(counts[i] + 1);
        dis[i] = 1.0f / sqrtf(d);
        selfw[i] = 1.0f / d;
    }
}

__global__ __launch_bounds__(1024) void scan1(const int* __restrict__ counts, int* __restrict__ rp,
                                              int* __restrict__ bsum) {
    __shared__ int tmp[1024];
    int t = threadIdx.x;
    int idx = blockIdx.x * 1024 + t;
    int v = (idx < N_NODES) ? counts[idx] : 0;
    tmp[t] = v;
    __syncthreads();
    for (int o = 1; o < 1024; o <<= 1) {
        int add = (t >= o) ? tmp[t - o] : 0;
        __syncthreads();
        tmp[t] += add;
        __syncthreads();
    }
    if (idx < N_NODES) rp[idx] = tmp[t] - v;   // exclusive
    if (t == 1023) bsum[blockIdx.x] = tmp[t];
}

__global__ void scan2(int* bsum, int nb) {
    if (threadIdx.x == 0 && blockIdx.x == 0) {
        int acc = 0;
        for (int i = 0; i < nb; i++) { int v = bsum[i]; bsum[i] = acc; acc += v; }
    }
}

__global__ __launch_bounds__(1024) void scan3(int* __restrict__ rp, const int* __restrict__ bsum,
                                              int* __restrict__ cursor) {
    int t = threadIdx.x;
    int idx = blockIdx.x * 1024 + t;
    if (idx < N_NODES) {
        int v = rp[idx] + bsum[blockIdx.x];
        rp[idx] = v;
        cursor[idx] = v;
    }
    if (idx == 0) rp[N_NODES] = N_EDGES;
}

__global__ __launch_bounds__(256) void scatter_kernel(const int* __restrict__ src, const int* __restrict__ dst,
                                                      const float* __restrict__ ea, const float* __restrict__ dis,
                                                      int* __restrict__ cursor, int2* __restrict__ esw,
                                                      float2* __restrict__ eea) {
    int e = blockIdx.x * 256 + threadIdx.x;
    if (e >= N_EDGES) return;
    int s = src[e], d = dst[e];
    int pos = atomicAdd(&cursor[d], 1);
    int2 sw;
    sw.x = s;
    sw.y = __float_as_int(dis[s] * dis[d]);
    esw[pos] = sw;
    float2 e2;
    e2.x = ea[e * 2];
    e2.y = ea[e * 2 + 1];
    eea[pos] = e2;
}

// ---------------- GINE gathers ----------------

__global__ __launch_bounds__(256) void conv1_gather(const float* __restrict__ x, const int* __restrict__ rp,
                                                    const int2* __restrict__ esw, const float2* __restrict__ eea,
                                                    const float* __restrict__ We1, const float* __restrict__ be1,
                                                    float* __restrict__ out) {
    int gw = (blockIdx.x * 256 + threadIdx.x) >> 6;
    if (gw >= N_NODES) return;
    int lane = threadIdx.x & 63;
    float w0 = We1[lane], w1 = We1[64 + lane], bb = be1[lane];
    float acc = x[(size_t)gw * 64 + lane];
    int j = rp[gw], s1 = rp[gw + 1];
    for (; j + 4 <= s1; j += 4) {
        int2 e0 = esw[j], e1 = esw[j + 1], e2 = esw[j + 2], e3 = esw[j + 3];
        float2 a0 = eea[j], a1 = eea[j + 1], a2 = eea[j + 2], a3 = eea[j + 3];
        float v0 = x[(size_t)e0.x * 64 + lane];
        float v1 = x[(size_t)e1.x * 64 + lane];
        float v2 = x[(size_t)e2.x * 64 + lane];
        float v3 = x[(size_t)e3.x * 64 + lane];
        acc += fmaxf(v0 + a0.x * w0 + a0.y * w1 + bb, 0.0f);
        acc += fmaxf(v1 + a1.x * w0 + a1.y * w1 + bb, 0.0f);
        acc += fmaxf(v2 + a2.x * w0 + a2.y * w1 + bb, 0.0f);
        acc += fmaxf(v3 + a3.x * w0 + a3.y * w1 + bb, 0.0f);
    }
    for (; j < s1; j++) {
        int2 e = esw[j];
        float2 a = eea[j];
        float v = x[(size_t)e.x * 64 + lane];
        acc += fmaxf(v + a.x * w0 + a.y * w1 + bb, 0.0f);
    }
    out[(size_t)gw * 64 + lane] = acc;
}

// conv2: self term from f32 h1, gathered messages from bf16 h1 copy.
__global__ __launch_bounds__(256) void conv2_gather(const float* __restrict__ h1f, const unsigned* __restrict__ h1b,
                                                    const int* __restrict__ rp,
                                                    const int2* __restrict__ esw, const float2* __restrict__ eea,
                                                    const float* __restrict__ We2, const float* __restrict__ be2,
                                                    float* __restrict__ out) {
    int gw = (blockIdx.x * 256 + threadIdx.x) >> 6;
    if (gw >= N_NODES) return;
    int lane = threadIdx.x & 63;
    int f0 = lane * 2;
    float w00 = We2[f0], w01 = We2[f0 + 1];
    float w10 = We2[128 + f0], w11 = We2[128 + f0 + 1];
    float b0 = be2[f0], b1 = be2[f0 + 1];
    float2 hc = ((const float2*)h1f)[(size_t)gw * 64 + lane];
    float a0 = hc.x, a1 = hc.y;
    int j = rp[gw], s1 = rp[gw + 1];
    for (; j + 8 <= s1; j += 8) {
        int2 e0 = esw[j], e1 = esw[j + 1], e2 = esw[j + 2], e3 = esw[j + 3];
        int2 e4 = esw[j + 4], e5 = esw[j + 5], e6 = esw[j + 6], e7 = esw[j + 7];
        float2 q0 = eea[j], q1 = eea[j + 1], q2 = eea[j + 2], q3 = eea[j + 3];
        float2 q4 = eea[j + 4], q5 = eea[j + 5], q6 = eea[j + 6], q7 = eea[j + 7];
        unsigned v0 = h1b[(size_t)e0.x * 64 + lane];
        unsigned v1 = h1b[(size_t)e1.x * 64 + lane];
        unsigned v2 = h1b[(size_t)e2.x * 64 + lane];
        unsigned v3 = h1b[(size_t)e3.x * 64 + lane];
        unsigned v4 = h1b[(size_t)e4.x * 64 + lane];
        unsigned v5 = h1b[(size_t)e5.x * 64 + lane];
        unsigned v6 = h1b[(size_t)e6.x * 64 + lane];
        unsigned v7 = h1b[(size_t)e7.x * 64 + lane];
        a0 += fmaxf(ubx(v0) + q0.x * w00 + q0.y * w10 + b0, 0.0f);
        a1 += fmaxf(uby(v0) + q0.x * w01 + q0.y * w11 + b1, 0.0f);
        a0 += fmaxf(ubx(v1) + q1.x * w00 + q1.y * w10 + b0, 0.0f);
        a1 += fmaxf(uby(v1) + q1.x * w01 + q1.y * w11 + b1, 0.0f);
        a0 += fmaxf(ubx(v2) + q2.x * w00 + q2.y * w10 + b0, 0.0f);
        a1 += fmaxf(uby(v2) + q2.x * w01 + q2.y * w11 + b1, 0.0f);
        a0 += fmaxf(ubx(v3) + q3.x * w00 + q3.y * w10 + b0, 0.0f);
        a1 += fmaxf(uby(v3) + q3.x * w01 + q3.y * w11 + b1, 0.0f);
        a0 += fmaxf(ubx(v4) + q4.x * w00 + q4.y * w10 + b0, 0.0f);
        a1 += fmaxf(uby(v4) + q4.x * w01 + q4.y * w11 + b1, 0.0f);
        a0 += fmaxf(ubx(v5) + q5.x * w00 + q5.y * w10 + b0, 0.0f);
        a1 += fmaxf(uby(v5) + q5.x * w01 + q5.y * w11 + b1, 0.0f);
        a0 += fmaxf(ubx(v6) + q6.x * w00 + q6.y * w10 + b0, 0.0f);
        a1 += fmaxf(uby(v6) + q6.x * w01 + q6.y * w11 + b1, 0.0f);
        a0 += fmaxf(ubx(v7) + q7.x * w00 + q7.y * w10 + b0, 0.0f);
        a1 += fmaxf(uby(v7) + q7.x * w01 + q7.y * w11 + b1, 0.0f);
    }
    for (; j < s1; j++) {
        int2 e = esw[j];
        float2 q = eea[j];
        unsigned v = h1b[(size_t)e.x * 64 + lane];
        a0 += fmaxf(ubx(v) + q.x * w00 + q.y * w10 + b0, 0.0f);
        a1 += fmaxf(uby(v) + q.x * w01 + q.y * w11 + b1, 0.0f);
    }
    out[(size_t)gw * 128 + f0] = a0;
    out[(size_t)gw * 128 + f0 + 1] = a1;
}

// ---------------- MLP layers via MFMA (split-bf16: Ahi*Whi + Ahi*Wlo + Alo*Whi) ----------------
// OMODE: 0 = f32 out only, 1 = f32 + bf16 copy, 2 = bf16 only.

template <int Kd, bool GELU, bool LN, int OMODE>
__global__ __launch_bounds__(256) void mlp_mfma(const float* __restrict__ A, const float* __restrict__ W,
                                                const float* __restrict__ bias, const float* __restrict__ g,
                                                const float* __restrict__ bn, float* __restrict__ outf,
                                                unsigned short* __restrict__ outb) {
    __shared__ unsigned short sHi[8192];   // 64 k-rows x 128 cols, swizzled
    __shared__ unsigned short sLo[8192];
    int wave = threadIdx.x >> 6, lane = threadIdx.x & 63;
    int quad = lane >> 4, n = lane & 15;
    int rowA = blockIdx.x * 64 + wave * 16 + n;
    int rowAc = (rowA < N_NODES) ? rowA : 0;

    f4v acc[8];
    #pragma unroll
    for (int t = 0; t < 8; t++) acc[t] = (f4v){0.f, 0.f, 0.f, 0.f};

    for (int ph = 0; ph < Kd / 64; ph++) {
        __syncthreads();
        for (int idx = threadIdx.x; idx < 8192; idx += 256) {
            int k = idx >> 7, c = idx & 127;
            float v = W[(size_t)(ph * 64 + k) * 128 + c];
            unsigned short hi = bf_rne(v);
            unsigned short lo = bf_rne(v - bf_f(hi));
            int kk = k >> 5, q = (k >> 3) & 3, j = k & 7, t = c >> 4, nn = c & 15;
            int lidx = ((((kk * 4 + q) * 8 + t) * 16 + nn) << 3) + j;
            sHi[lidx] = hi;
            sLo[lidx] = lo;
        }
        __syncthreads();
        #pragma unroll
        for (int kk = 0; kk < 2; kk++) {
            int k0 = ph * 64 + kk * 32 + quad * 8;
            const float4* ap = (const float4*)(A + (size_t)rowAc * Kd + k0);
            float4 a0 = ap[0], a1 = ap[1];
            float av[8] = {a0.x, a0.y, a0.z, a0.w, a1.x, a1.y, a1.z, a1.w};
            s8v ahi, alo;
            #pragma unroll
            for (int j = 0; j < 8; j++) {
                unsigned short h = bf_rne(av[j]);
                ahi[j] = (short)h;
                alo[j] = (short)bf_rne(av[j] - bf_f(h));
            }
            int base = ((kk * 4 + quad) * 8) * 128;
            #pragma unroll
            for (int t = 0; t < 8; t++) {
                s8v bhi = *(const s8v*)&sHi[base + ((t * 16 + n) << 3)];
                s8v blo = *(const s8v*)&sLo[base + ((t * 16 + n) << 3)];
                acc[t] = __builtin_amdgcn_mfma_f32_16x16x32_bf16(ahi, bhi, acc[t], 0, 0, 0);
                acc[t] = __builtin_amdgcn_mfma_f32_16x16x32_bf16(ahi, blo, acc[t], 0, 0, 0);
                acc[t] = __builtin_amdgcn_mfma_f32_16x16x32_bf16(alo, bhi, acc[t], 0, 0, 0);
            }
        }
    }

    float bcol[8], gcol[8], bncol[8];
    #pragma unroll
    for (int t = 0; t < 8; t++) {
        bcol[t] = bias[t * 16 + n];
        if (LN) { gcol[t] = g[t * 16 + n]; bncol[t] = bn[t * 16 + n]; }
    }
    #pragma unroll
    for (int r = 0; r < 4; r++) {
        int row = blockIdx.x * 64 + wave * 16 + quad * 4 + r;
        float v[8];
        #pragma unroll
        for (int t = 0; t < 8; t++) {
            float x = acc[t][r] + bcol[t];
            v[t] = GELU ? gelu_f(x) : x;
        }
        if (LN) {
            float s = 0.f, q2 = 0.f;
            #pragma unroll
            for (int t = 0; t < 8; t++) { s += v[t]; q2 += v[t] * v[t]; }
            #pragma unroll
            for (int m = 1; m <= 8; m <<= 1) {
                s += __shfl_xor(s, m, 64);
                q2 += __shfl_xor(q2, m, 64);
            }
            float mu = s * (1.0f / 128.0f);
            float rs = rsqrtf(q2 * (1.0f / 128.0f) - mu * mu + LN_EPS);
            #pragma unroll
            for (int t = 0; t < 8; t++) v[t] = (v[t] - mu) * rs * gcol[t] + bncol[t];
        }
        if (row < N_NODES) {
            #pragma unroll
            for (int t = 0; t < 8; t++) {
                if (OMODE != 2) outf[(size_t)row * 128 + t * 16 + n] = v[t];
                if (OMODE >= 1) outb[(size_t)row * 128 + t * 16 + n] = bf_rne(v[t]);
            }
        }
    }
}

// ---------------- Gate via MFMA: gate = gelu(h@Wg1+bg1)@Wg2 + bg2 ----------------

__global__ __launch_bounds__(256) void gate_mfma(const float* __restrict__ h, const float* __restrict__ Wg1,
                                                 const float* __restrict__ bg1, const float* __restrict__ Wg2,
                                                 const float* __restrict__ bg2, float* __restrict__ gate) {
    __shared__ unsigned short sHi[8192];  // 128 k x 64 cols, swizzled
    __shared__ unsigned short sLo[8192];
    int wave = threadIdx.x >> 6, lane = threadIdx.x & 63;
    int quad = lane >> 4, n = lane & 15;
    for (int idx = threadIdx.x; idx < 8192; idx += 256) {
        int k = idx >> 6, c = idx & 63;
        float v = Wg1[k * 64 + c];
        unsigned short hi = bf_rne(v);
        unsigned short lo = bf_rne(v - bf_f(hi));
        int kk = k >> 5, q = (k >> 3) & 3, j = k & 7, t = c >> 4, nn = c & 15;
        int lidx = ((((kk * 4 + q) * 4 + t) * 16 + nn) << 3) + j;
        sHi[lidx] = hi;
        sLo[lidx] = lo;
    }
    __syncthreads();
    int rowA = blockIdx.x * 64 + wave * 16 + n;
    int rowAc = (rowA < N_NODES) ? rowA : 0;
    f4v acc[4];
    #pragma unroll
    for (int t = 0; t < 4; t++) acc[t] = (f4v){0.f, 0.f, 0.f, 0.f};
    #pragma unroll
    for (int kk = 0; kk < 4; kk++) {
        const float4* ap = (const float4*)(h + (size_t)rowAc * 128 + kk * 32 + quad * 8);
        float4 a0 = ap[0], a1 = ap[1];
        float av[8] = {a0.x, a0.y, a0.z, a0.w, a1.x, a1.y, a1.z, a1.w};
        s8v ahi, alo;
        #pragma unroll
        for (int j = 0; j < 8; j++) {
            unsigned short hh = bf_rne(av[j]);
            ahi[j] = (short)hh;
            alo[j] = (short)bf_rne(av[j] - bf_f(hh));
        }
        int base = ((kk * 4 + quad) * 4) * 128;
        #pragma unroll
        for (int t = 0; t < 4; t++) {
            s8v bhi = *(const s8v*)&sHi[base + ((t * 16 + n) << 3)];
            s8v blo = *(const s8v*)&sLo[base + ((t * 16 + n) << 3)];
            acc[t] = __builtin_amdgcn_mfma_f32_16x16x32_bf16(ahi, bhi, acc[t], 0, 0, 0);
            acc[t] = __builtin_amdgcn_mfma_f32_16x16x32_bf16(ahi, blo, acc[t], 0, 0, 0);
            acc[t] = __builtin_amdgcn_mfma_f32_16x16x32_bf16(alo, bhi, acc[t], 0, 0, 0);
        }
    }
    float b2 = bg2[0];
    float bb[4], vv[4];
    #pragma unroll
    for (int t = 0; t < 4; t++) { bb[t] = bg1[t * 16 + n]; vv[t] = Wg2[t * 16 + n]; }
    #pragma unroll
    for (int r = 0; r < 4; r++) {
        int row = blockIdx.x * 64 + wave * 16 + quad * 4 + r;
        float val = 0.f;
        #pragma unroll
        for (int t = 0; t < 4; t++) val += gelu_f(acc[t][r] + bb[t]) * vv[t];
        #pragma unroll
        for (int m = 1; m <= 8; m <<= 1) val += __shfl_xor(val, m, 64);
        if (n == 0 && row < N_NODES) gate[row] = val + b2;
    }
}

// ---------------- APPNP (bf16 state + bf16 anchor, f32 accumulation, 8x unroll) ----------------

template <bool LAST>
__global__ __launch_bounds__(256) void appnp_step_bf(const unsigned* __restrict__ hin,
                                                     const unsigned* __restrict__ anchor,
                                                     unsigned* __restrict__ hout, float2* __restrict__ houtf,
                                                     const int* __restrict__ rp, const int2* __restrict__ esw,
                                                     const float* __restrict__ selfw) {
    int gw = (blockIdx.x * 256 + threadIdx.x) >> 6;
    if (gw >= N_NODES) return;
    int lane = threadIdx.x & 63;
    size_t idx = (size_t)gw * 64 + lane;
    float swi = selfw[gw];
    unsigned hcp = hin[idx];
    float ax = swi * ubx(hcp), ay = swi * uby(hcp);
    int j = rp[gw], s1 = rp[gw + 1];
    for (; j + 8 <= s1; j += 8) {
        int2 e0 = esw[j], e1 = esw[j + 1], e2 = esw[j + 2], e3 = esw[j + 3];
        int2 e4 = esw[j + 4], e5 = esw[j + 5], e6 = esw[j + 6], e7 = esw[j + 7];
        unsigned v0 = hin[(size_t)e0.x * 64 + lane];
        unsigned v1 = hin[(size_t)e1.x * 64 + lane];
        unsigned v2 = hin[(size_t)e2.x * 64 + lane];
        unsigned v3 = hin[(size_t)e3.x * 64 + lane];
        unsigned v4 = hin[(size_t)e4.x * 64 + lane];
        unsigned v5 = hin[(size_t)e5.x * 64 + lane];
        unsigned v6 = hin[(size_t)e6.x * 64 + lane];
        unsigned v7 = hin[(size_t)e7.x * 64 + lane];
        float w0 = __int_as_float(e0.y), w1 = __int_as_float(e1.y);
        float w2 = __int_as_float(e2.y), w3 = __int_as_float(e3.y);
        float w4 = __int_as_float(e4.y), w5 = __int_as_float(e5.y);
        float w6 = __int_as_float(e6.y), w7 = __int_as_float(e7.y);
        ax = fmaf(w0, ubx(v0), ax); ay = fmaf(w0, uby(v0), ay);
        ax = fmaf(w1, ubx(v1), ax); ay = fmaf(w1, uby(v1), ay);
        ax = fmaf(w2, ubx(v2), ax); ay = fmaf(w2, uby(v2), ay);
        ax = fmaf(w3, ubx(v3), ax); ay = fmaf(w3, uby(v3), ay);
        ax = fmaf(w4, ubx(v4), ax); ay = fmaf(w4, uby(v4), ay);
        ax = fmaf(w5, ubx(v5), ax); ay = fmaf(w5, uby(v5), ay);
        ax = fmaf(w6, ubx(v6), ax); ay = fmaf(w6, uby(v6), ay);
        ax = fmaf(w7, ubx(v7), ax); ay = fmaf(w7, uby(v7), ay);
    }
    for (; j + 4 <= s1; j += 4) {
        int2 e0 = esw[j], e1 = esw[j + 1], e2 = esw[j + 2], e3 = esw[j + 3];
        unsigned v0 = hin[(size_t)e0.x * 64 + lane];
        unsigned v1 = hin[(size_t)e1.x * 64 + lane];
        unsigned v2 = hin[(size_t)e2.x * 64 + lane];
        unsigned v3 = hin[(size_t)e3.x * 64 + lane];
        float w0 = __int_as_float(e0.y), w1 = __int_as_float(e1.y);
        float w2 = __int_as_float(e2.y), w3 = __int_as_float(e3.y);
        ax = fmaf(w0, ubx(v0), ax); ay = fmaf(w0, uby(v0), ay);
        ax = fmaf(w1, ubx(v1), ax); ay = fmaf(w1, uby(v1), ay);
        ax = fmaf(w2, ubx(v2), ax); ay = fmaf(w2, uby(v2), ay);
        ax = fmaf(w3, ubx(v3), ax); ay = fmaf(w3, uby(v3), ay);
    }
    for (; j < s1; j++) {
        int2 e = esw[j];
        unsigned v = hin[(size_t)e.x * 64 + lane];
        float w = __int_as_float(e.y);
        ax = fmaf(w, ubx(v), ax); ay = fmaf(w, uby(v), ay);
    }
    unsigned ancp = anchor[idx];
    float ox = 0.9f * ax + 0.1f * ubx(ancp);
    float oy = 0.9f * ay + 0.1f * uby(ancp);
    if (LAST) {
        float2 o; o.x = ox; o.y = oy;
        houtf[idx] = o;
    } else {
        hout[idx] = pack_bf2(ox, oy);
    }
}

// ---------------- Attentional pooling ----------------

__global__ void seg_begin(const int* __restrict__ batch, int* __restrict__ gbeg) {
    int b = threadIdx.x;
    if (b > N_B) return;
    if (b == N_B) { gbeg[N_B] = N_NODES; return; }
    int lo = 0, hi = N_NODES;
    while (lo < hi) {
        int mid = (lo + hi) >> 1;
        if (batch[mid] < b) lo = mid + 1; else hi = mid;
    }
    gbeg[b] = lo;
}

__global__ __launch_bounds__(256) void seg_max(const float* __restrict__ gate, const int* __restrict__ gbeg,
                                               float* __restrict__ gmax) {
    int b = blockIdx.x;
    int s = gbeg[b], e = gbeg[b + 1];
    float m = -INFINITY;
    for (int i = s + threadIdx.x; i < e; i += 256) m = fmaxf(m, gate[i]);
    for (int o = 32; o > 0; o >>= 1) m = fmaxf(m, __shfl_xor(m, o, 64));
    __shared__ float red[4];
    if ((threadIdx.x & 63) == 0) red[threadIdx.x >> 6] = m;
    __syncthreads();
    if (threadIdx.x == 0) gmax[b] = fmaxf(fmaxf(red[0], red[1]), fmaxf(red[2], red[3]));
}

__global__ __launch_bounds__(256) void seg_sum(const float* __restrict__ gate, const int* __restrict__ gbeg,
                                               const float* __restrict__ gmax, float* __restrict__ gsum) {
    int b = blockIdx.x;
    int s = gbeg[b], e = gbeg[b + 1];
    float m = gmax[b];
    float acc = 0.0f;
    for (int i = s + threadIdx.x; i < e; i += 256) acc += expf(gate[i] - m);
    for (int o = 32; o > 0; o >>= 1) acc += __shfl_xor(acc, o, 64);
    __shared__ float red[4];
    if ((threadIdx.x & 63) == 0) red[threadIdx.x >> 6] = acc;
    __syncthreads();
    if (threadIdx.x == 0) gsum[b] = red[0] + red[1] + red[2] + red[3];
}

// 8 slices per graph; atomicAdd into zero-initialized gout.
__global__ __launch_bounds__(512) void seg_pool(const float* __restrict__ h, const float* __restrict__ gate,
                                                const int* __restrict__ gbeg, const float* __restrict__ gmax,
                                                const float* __restrict__ gsum, float* __restrict__ gout) {
    int b = blockIdx.x >> 3, slice = blockIdx.x & 7;
    int team = threadIdx.x >> 7;
    int f = threadIdx.x & 127;
    int s = gbeg[b], e = gbeg[b + 1];
    float m = gmax[b];
    float inv = (e > s) ? 1.0f / gsum[b] : 0.0f;
    float acc = 0.0f;
    for (int i = s + slice * 4 + team; i < e; i += 32) {
        float a = expf(gate[i] - m) * inv;
        acc = fmaf(a, h[(size_t)i * 128 + f], acc);
    }
    __shared__ float red[4][128];
    red[team][f] = acc;
    __syncthreads();
    if (team == 0) {
        float v = red[0][f] + red[1][f] + red[2][f] + red[3][f];
        atomicAdd(&gout[b * 128 + f], v);
    }
}

// ---------------- host launch ----------------

extern "C" void kernel_launch(void* const* d_in, const int* in_sizes, int n_in,
                              void* d_out, int out_size, void* d_ws, size_t ws_size,
                              hipStream_t stream) {
    const float* x     = (const float*)d_in[0];
    const int*   ei    = (const int*)d_in[1];
    const int*   batch = (const int*)d_in[2];
    const float* ea    = (const float*)d_in[3];
    const float* We1 = (const float*)d_in[4];
    const float* be1 = (const float*)d_in[5];
    const float* W1a = (const float*)d_in[6];
    const float* b1a = (const float*)d_in[7];
    const float* W1b = (const float*)d_in[8];
    const float* b1b = (const float*)d_in[9];
    const float* g1  = (const float*)d_in[10];
    const float* bn1 = (const float*)d_in[11];
    const float* We2 = (const float*)d_in[12];
    const float* be2 = (const float*)d_in[13];
    const float* W2a = (const float*)d_in[14];
    const float* b2a = (const float*)d_in[15];
    const float* W2b = (const float*)d_in[16];
    const float* b2b = (const float*)d_in[17];
    const float* g2  = (const float*)d_in[18];
    const float* bn2 = (const float*)d_in[19];
    const float* Wg1 = (const float*)d_in[20];
    const float* bg1 = (const float*)d_in[21];
    const float* Wg2 = (const float*)d_in[22];
    const float* bg2 = (const float*)d_in[23];

    float* outH = (float*)d_out;                 // [N,128] final h (also used as scratch)
    float* outG = outH + (size_t)N_NODES * 128;  // [B,128] pooled

    char* w = (char*)d_ws;
    auto carve = [&](size_t bytes) {
        void* p = (void*)w;
        w += ((bytes + 255) / 256) * 256;
        return p;
    };
    float*  bufB   = (float*)carve((size_t)N_NODES * 128 * 4);  // 51.2 MB
    float*  bufC   = (float*)carve((size_t)N_NODES * 128 * 4);  // 51.2 MB
    int2*   esw    = (int2*)carve((size_t)N_EDGES * 8);
    float2* eea    = (float2*)carve((size_t)N_EDGES * 8);
    int*    counts = (int*)carve((size_t)N_NODES * 4);
    int*    rp     = (int*)carve((size_t)(N_NODES + 1) * 4);
    int*    cursor = (int*)carve((size_t)N_NODES * 4);
    float*  dis    = (float*)carve((size_t)N_NODES * 4);
    float*  selfw  = (float*)carve((size_t)N_NODES * 4);
    float*  gate   = (float*)carve((size_t)N_NODES * 4);
    int*    bsum   = (int*)carve(128 * 4);
    float*  gmax   = (float*)carve(N_B * 4);
    float*  gsum   = (float*)carve(N_B * 4);
    int*    gbeg   = (int*)carve((N_B + 1) * 4);

    const int* src = ei;
    const int* dst = ei + N_EDGES;

    const int NB_SCAN = (N_NODES + 1023) / 1024;  // 98
    const int EB = (N_EDGES + 255) / 256;
    const int NBLK = (N_NODES + 255) / 256;
    const int WBLK = (N_NODES + 3) / 4;    // one wave per node, 4 waves/block
    const int MBLK = (N_NODES + 63) / 64;  // 1563 blocks for mfma kernels

    // CSR build
    hipMemsetAsync(counts, 0, (size_t)N_NODES * 4, stream);
    hist_kernel<<<EB, 256, 0, stream>>>(dst, counts);
    deg_kernel<<<NBLK, 256, 0, stream>>>(counts, dis, selfw);
    scan1<<<NB_SCAN, 1024, 0, stream>>>(counts, rp, bsum);
    scan2<<<1, 64, 0, stream>>>(bsum, NB_SCAN);
    scan3<<<NB_SCAN, 1024, 0, stream>>>(rp, bsum, cursor);
    scatter_kernel<<<EB, 256, 0, stream>>>(src, dst, ea, dis, cursor, esw, eea);

    // Buffer plan (liveness):
    //   agg1 = bufB ; t1 = outH ; h1f = bufB (overwrites agg1), h1bf = bufC[0:25.6MB]
    //   agg2 = outH (overwrites t1) ; t2 = bufB (overwrites h1f)
    //   anchor_bf = bufC[0:25.6] (overwrites h1bf) ; pingA = bufC[25.6:51.2] ; pingB = bufB[0:25.6]
    unsigned short* h1bf  = (unsigned short*)bufC;
    unsigned* ancU  = (unsigned*)bufC;
    unsigned* pingA = ancU + (size_t)N_NODES * 64;
    unsigned* pingB = (unsigned*)bufB;

    // conv1
    conv1_gather<<<WBLK, 256, 0, stream>>>(x, rp, esw, eea, We1, be1, bufB);
    mlp_mfma<64, true, false, 0><<<MBLK, 256, 0, stream>>>(bufB, W1a, b1a, nullptr, nullptr, outH, nullptr);
    mlp_mfma<128, true, true, 1><<<MBLK, 256, 0, stream>>>(outH, W1b, b1b, g1, bn1, bufB, h1bf);

    // conv2
    conv2_gather<<<WBLK, 256, 0, stream>>>(bufB, (const unsigned*)h1bf, rp, esw, eea, We2, be2, outH);
    mlp_mfma<128, true, false, 0><<<MBLK, 256, 0, stream>>>(outH, W2a, b2a, nullptr, nullptr, bufB, nullptr);
    mlp_mfma<128, false, true, 2><<<MBLK, 256, 0, stream>>>(bufB, W2b, b2b, g2, bn2, nullptr, (unsigned short*)ancU);

    // APPNP: h0 = anchor (bf16). Steps 1..15 bf16 ping-pong; step 16 writes f32 outH.
    const unsigned* cur = ancU;
    for (int k = 1; k <= K_ITER - 1; k++) {
        unsigned* dstbuf = (k & 1) ? pingA : pingB;
        appnp_step_bf<false><<<WBLK, 256, 0, stream>>>(cur, ancU, dstbuf, nullptr, rp, esw, selfw);
        cur = dstbuf;
    }
    appnp_step_bf<true><<<WBLK, 256, 0, stream>>>(cur, ancU, nullptr, (float2*)outH, rp, esw, selfw);

    // pooling on outH
    gate_mfma<<<MBLK, 256, 0, stream>>>(outH, Wg1, bg1, Wg2, bg2, gate);
    seg_begin<<<1, 128, 0, stream>>>(batch, gbeg);
    seg_max<<<N_B, 256, 0, stream>>>(gate, gbeg, gmax);
    seg_sum<<<N_B, 256, 0, stream>>>(gate, gbeg, gmax, gsum);
    hipMemsetAsync(outG, 0, (size_t)N_B * 128 * 4, stream);
    seg_pool<<<N_B * 8, 512, 0, stream>>>(outH, gate, gbeg, gmax, gsum, outG);
}